// Round 1
// baseline (5010.646 us; speedup 1.0000x reference)
//
#include <hip/hip_runtime.h>
#include <math.h>

// Problem constants
#define NB   8
#define NROI 400
#define DF   512
#define GG   25
#define EMBD 360
#define NHD  4
#define HDD  90
#define FFD  2048
#define TBM  1728   // max tokens (12*12*12)

__device__ __forceinline__ float gelu_f(float x) {
    return 0.5f * x * (1.0f + erff(x * 0.7071067811865475f));
}

// ---------------------------------------------------------------------------
// Generic fp32 GEMM: C[M,N] = act(A[M,K] @ B[K,N] + bias[N] (+ res[M,N]))
// 128x128 tile, 256 threads, 8x8 per-thread register blocking, K-step 16.
// ---------------------------------------------------------------------------
#define TILE_M 128
#define TILE_N 128
#define KSTEP  16

template <int ACT, bool RES>   // ACT: 0 none, 1 gelu, 2 relu
__global__ __launch_bounds__(256) void k_gemm(
    const float* __restrict__ A, const float* __restrict__ B,
    const float* __restrict__ bias, const float* __restrict__ res,
    float* __restrict__ C, int M, int N, int K)
{
    __shared__ float As[KSTEP][TILE_M + 4];   // transposed (k-major)
    __shared__ float Bs[KSTEP][TILE_N + 4];

    const int t  = threadIdx.x;
    const int m0 = blockIdx.y * TILE_M;
    const int n0 = blockIdx.x * TILE_N;
    const int tm = (t >> 4) * 8;
    const int tn = (t & 15) * 8;

    float acc[8][8] = {};
    const int nk = (K + KSTEP - 1) / KSTEP;

    for (int ks = 0; ks < nk; ++ks) {
        const int k0 = ks * KSTEP;
        __syncthreads();   // protect LDS from previous iteration's readers
        #pragma unroll
        for (int g = 0; g < 2; ++g) {
            int f = t + g * 256;
            // A tile: 128 rows x 16 cols
            int arow = f >> 2, ac = (f & 3) * 4;
            int gm = m0 + arow;
            #pragma unroll
            for (int i = 0; i < 4; ++i) {
                int gk = k0 + ac + i;
                As[ac + i][arow] = (gm < M && gk < K) ? A[(size_t)gm * K + gk] : 0.0f;
            }
            // B tile: 16 rows x 128 cols
            int brow = f >> 5, bc = (f & 31) * 4;
            int gk2 = k0 + brow;
            #pragma unroll
            for (int i = 0; i < 4; ++i) {
                int gn = n0 + bc + i;
                Bs[brow][bc + i] = (gk2 < K && gn < N) ? B[(size_t)gk2 * N + gn] : 0.0f;
            }
        }
        __syncthreads();
        #pragma unroll
        for (int k = 0; k < KSTEP; ++k) {
            float a[8], bv[8];
            #pragma unroll
            for (int i = 0; i < 8; ++i) a[i] = As[k][tm + i];
            #pragma unroll
            for (int j = 0; j < 8; ++j) bv[j] = Bs[k][tn + j];
            #pragma unroll
            for (int i = 0; i < 8; ++i)
                #pragma unroll
                for (int j = 0; j < 8; ++j)
                    acc[i][j] = fmaf(a[i], bv[j], acc[i][j]);
        }
    }

    #pragma unroll
    for (int i = 0; i < 8; ++i) {
        int gm = m0 + tm + i;
        if (gm >= M) break;
        #pragma unroll
        for (int j = 0; j < 8; ++j) {
            int gn = n0 + tn + j;
            if (gn < N) {
                float v = acc[i][j] + bias[gn];
                if (RES) v += res[(size_t)gm * N + gn];
                if (ACT == 1) v = gelu_f(v);
                else if (ACT == 2) v = fmaxf(v, 0.0f);
                C[(size_t)gm * N + gn] = v;
            }
        }
    }
}

// ---------------------------------------------------------------------------
// Gather + 3^3 sum-pool (stride 2, VALID): nodes[b,t,e] = sum_27 F_pad[b,C,e]
// ---------------------------------------------------------------------------
__global__ __launch_bounds__(128) void k_pool(
    const float* __restrict__ F_emb, const int* __restrict__ C,
    float* __restrict__ nodes)
{
    const int tkn = blockIdx.x;           // 0..1727
    const int b   = blockIdx.y;
    const int oz = tkn % 12, oy = (tkn / 12) % 12, ox = tkn / 144;
    __shared__ int idx[27];
    const int tid = threadIdx.x;
    if (tid < 27) {
        int dx = tid / 9, dy = (tid / 3) % 3, dz = tid % 3;
        int ix = ox * 2 + dx, iy = oy * 2 + dy, iz = oz * 2 + dz;
        idx[tid] = C[((b * GG + ix) * GG + iy) * GG + iz];
    }
    __syncthreads();
    float acc0 = 0.f, acc1 = 0.f, acc2 = 0.f;
    for (int n = 0; n < 27; ++n) {
        int c = idx[n];
        if (c == 0) continue;             // padding row (zeros)
        const float* src = F_emb + (size_t)(b * NROI + (c - 1)) * EMBD;
        acc0 += src[tid];
        acc1 += src[tid + 128];
        if (tid < 104) acc2 += src[tid + 256];
    }
    float* dst = nodes + ((size_t)b * TBM + tkn) * EMBD;
    dst[tid] = acc0;
    dst[tid + 128] = acc1;
    if (tid < 104) dst[tid + 256] = acc2;
}

// ---------------------------------------------------------------------------
// Token mask: valid[t] = (sum_{b,e} |nodes[b,t,e]| > 0)
// ---------------------------------------------------------------------------
__global__ __launch_bounds__(256) void k_mask(
    const float* __restrict__ nodes, int* __restrict__ valid)
{
    const int tkn = blockIdx.x;
    float s = 0.f;
    for (int i = threadIdx.x; i < NB * EMBD; i += 256) {
        int b = i / EMBD, e = i - b * EMBD;
        s += fabsf(nodes[((size_t)b * TBM + tkn) * EMBD + e]);
    }
    #pragma unroll
    for (int o = 32; o >= 1; o >>= 1) s += __shfl_xor(s, o);
    __shared__ float red[4];
    if ((threadIdx.x & 63) == 0) red[threadIdx.x >> 6] = s;
    __syncthreads();
    if (threadIdx.x == 0)
        valid[tkn] = ((red[0] + red[1] + red[2] + red[3]) > 0.f) ? 1 : 0;
}

// ---------------------------------------------------------------------------
// Compaction scan (single block): cidx[j] = j-th valid token, *tcp = count
// ---------------------------------------------------------------------------
__global__ __launch_bounds__(256) void k_scan(
    const int* __restrict__ valid, int* __restrict__ cidx, int* __restrict__ tcp)
{
    __shared__ int csum[256];
    __shared__ int coff[256];
    const int t = threadIdx.x;
    const int base = t * 7;
    int loc[7]; int s = 0;
    #pragma unroll
    for (int i = 0; i < 7; ++i) {
        int g = base + i;
        int v = (g < TBM) ? valid[g] : 0;
        loc[i] = v; s += v;
    }
    csum[t] = s;
    __syncthreads();
    if (t == 0) {
        int a = 0;
        for (int i = 0; i < 256; ++i) { coff[i] = a; a += csum[i]; }
        *tcp = a;
    }
    __syncthreads();
    int off = coff[t];
    #pragma unroll
    for (int i = 0; i < 7; ++i) {
        int g = base + i;
        if (g < TBM && loc[i]) cidx[off++] = g;
    }
}

__global__ __launch_bounds__(128) void k_compact(
    const float* __restrict__ nodes, const int* __restrict__ cidx,
    const int* __restrict__ tcp, float* __restrict__ x)
{
    const int j = blockIdx.x, b = blockIdx.y;
    const int Tc = *tcp;
    float* dst = x + ((size_t)b * TBM + j) * EMBD;
    if (j >= Tc) {
        for (int e = threadIdx.x; e < EMBD; e += 128) dst[e] = 0.f;
        return;
    }
    const float* src = nodes + ((size_t)b * TBM + cidx[j]) * EMBD;
    for (int e = threadIdx.x; e < EMBD; e += 128) dst[e] = src[e];
}

// ---------------------------------------------------------------------------
// Flash attention, fp32. Block = (qtile of 64 rows, head, batch), 256 thr.
// qkv rows: [b*1728 + t][1080]; q = cols h*90.., k = 360+h*90.., v = 720+h*90..
// ---------------------------------------------------------------------------
__global__ __launch_bounds__(256) void k_attn(
    const float* __restrict__ qkv, float* __restrict__ ao,
    const int* __restrict__ tcp)
{
    const int t = threadIdx.x;
    const int qt = blockIdx.x, h = blockIdx.y, b = blockIdx.z;
    const int Tc = *tcp;
    const int q0 = qt * 64;
    const float scale = 0.105409255338945984f;   // 1/sqrt(90)

    __shared__ float Qs[HDD][64];        // d-major
    __shared__ float KV[96 * 64];        // K as [d][64] then V as [kk][96]
    __shared__ float Ss[64][65];
    __shared__ float mrow[64], lrow[64], frow[64];

    const size_t qb = (size_t)b * (TBM * 1080);
    for (int idx = t; idx < 64 * HDD; idx += 256) {
        int qq = idx / HDD, d = idx - qq * HDD;
        Qs[d][qq] = qkv[qb + (size_t)(q0 + qq) * 1080 + h * HDD + d];
    }
    if (t < 64) { mrow[t] = -INFINITY; lrow[t] = 0.0f; }

    float o[4][6] = {};
    const int sq = (t >> 4) * 4, sk = (t & 15) * 4;
    const int softr = t >> 2, softc = (t & 3) * 16;
    const int c6 = (t & 15) * 6;
    int nkt = (Tc + 63) >> 6; if (nkt > 27) nkt = 27;
    __syncthreads();

    for (int kt = 0; kt < nkt; ++kt) {
        const int k0 = kt * 64;
        // stage K tile (d-major)
        for (int idx = t; idx < 64 * HDD; idx += 256) {
            int kk = idx / HDD, d = idx - kk * HDD;
            KV[d * 64 + kk] = qkv[qb + (size_t)(k0 + kk) * 1080 + 360 + h * HDD + d];
        }
        __syncthreads();
        // S = scale * Q K^T  (4x4 per thread)
        float s[4][4] = {};
        for (int d = 0; d < HDD; ++d) {
            float qa[4], ka[4];
            #pragma unroll
            for (int i = 0; i < 4; ++i) qa[i] = Qs[d][sq + i];
            #pragma unroll
            for (int j = 0; j < 4; ++j) ka[j] = KV[d * 64 + sk + j];
            #pragma unroll
            for (int i = 0; i < 4; ++i)
                #pragma unroll
                for (int j = 0; j < 4; ++j)
                    s[i][j] = fmaf(qa[i], ka[j], s[i][j]);
        }
        #pragma unroll
        for (int i = 0; i < 4; ++i)
            #pragma unroll
            for (int j = 0; j < 4; ++j)
                Ss[sq + i][sk + j] = s[i][j] * scale;
        __syncthreads();   // Ks reads done, Ss written
        // stage V tile over K (kk-major, padded to 96)
        for (int idx = t; idx < 64 * HDD; idx += 256) {
            int kk = idx / HDD, d = idx - kk * HDD;
            KV[kk * 96 + d] = qkv[qb + (size_t)(k0 + kk) * 1080 + 720 + h * HDD + d];
        }
        // online softmax: 4 threads per row, 16 cols each
        float pm = -INFINITY;
        #pragma unroll
        for (int c = 0; c < 16; ++c) {
            int kg = k0 + softc + c;
            float v = (kg < Tc) ? Ss[softr][softc + c] : -INFINITY;
            pm = fmaxf(pm, v);
        }
        pm = fmaxf(pm, __shfl_xor(pm, 1));
        pm = fmaxf(pm, __shfl_xor(pm, 2));
        float mo = mrow[softr];
        float mn = fmaxf(mo, pm);
        float ps = 0.0f;
        if (mn == -INFINITY) {
            #pragma unroll
            for (int c = 0; c < 16; ++c) Ss[softr][softc + c] = 0.0f;
        } else {
            #pragma unroll
            for (int c = 0; c < 16; ++c) {
                int kg = k0 + softc + c;
                float v = (kg < Tc) ? expf(Ss[softr][softc + c] - mn) : 0.0f;
                Ss[softr][softc + c] = v;
                ps += v;
            }
        }
        ps += __shfl_xor(ps, 1);
        ps += __shfl_xor(ps, 2);
        if ((t & 3) == 0) {
            float f = (mo == -INFINITY) ? 0.0f : expf(mo - mn);
            mrow[softr] = mn;
            lrow[softr] = lrow[softr] * f + ps;
            frow[softr] = f;
        }
        __syncthreads();   // V staged + softmax/factors done
        // rescale O and accumulate P @ V  (4 rows x 6 dims per thread)
        float fr[4];
        #pragma unroll
        for (int i = 0; i < 4; ++i) fr[i] = frow[sq + i];
        #pragma unroll
        for (int i = 0; i < 4; ++i)
            #pragma unroll
            for (int j = 0; j < 6; ++j)
                o[i][j] *= fr[i];
        for (int kk = 0; kk < 64; ++kk) {
            float p[4], vv[6];
            #pragma unroll
            for (int i = 0; i < 4; ++i) p[i] = Ss[sq + i][kk];
            #pragma unroll
            for (int j = 0; j < 6; ++j) vv[j] = KV[kk * 96 + c6 + j];
            #pragma unroll
            for (int i = 0; i < 4; ++i)
                #pragma unroll
                for (int j = 0; j < 6; ++j)
                    o[i][j] = fmaf(p[i], vv[j], o[i][j]);
        }
        __syncthreads();   // Ss/KV consumed before next tile
    }

    const size_t ab = (size_t)b * (TBM * EMBD);
    #pragma unroll
    for (int i = 0; i < 4; ++i) {
        int gq = q0 + sq + i;
        if (gq >= Tc) continue;
        float l = lrow[sq + i];
        float inv = (l > 0.0f) ? (1.0f / l) : 0.0f;
        #pragma unroll
        for (int j = 0; j < 6; ++j) {
            int c = c6 + j;
            if (c < HDD) ao[ab + (size_t)gq * EMBD + h * HDD + c] = o[i][j] * inv;
        }
    }
}

// ---------------------------------------------------------------------------
// LayerNorm over 360 dims, one block (128 thr) per row. Input already has
// residual+bias folded in by the GEMM epilogue.
// ---------------------------------------------------------------------------
__global__ __launch_bounds__(128) void k_ln(
    const float* __restrict__ y, const float* __restrict__ sc,
    const float* __restrict__ bc, float* __restrict__ outp)
{
    const int row = blockIdx.x;
    const int t = threadIdx.x;
    const float* yr = y + (size_t)row * EMBD;
    float x0 = yr[t];
    float x1 = yr[t + 128];
    float x2 = (t < 104) ? yr[t + 256] : 0.0f;
    float sum = x0 + x1 + x2;
    __shared__ float red[2];
    #pragma unroll
    for (int o = 32; o >= 1; o >>= 1) sum += __shfl_xor(sum, o);
    if ((t & 63) == 0) red[t >> 6] = sum;
    __syncthreads();
    float mean = (red[0] + red[1]) * (1.0f / 360.0f);
    float d0 = x0 - mean, d1 = x1 - mean, d2 = (t < 104) ? (x2 - mean) : 0.0f;
    float vs = d0 * d0 + d1 * d1 + d2 * d2;
    __syncthreads();
    #pragma unroll
    for (int o = 32; o >= 1; o >>= 1) vs += __shfl_xor(vs, o);
    if ((t & 63) == 0) red[t >> 6] = vs;
    __syncthreads();
    float var = (red[0] + red[1]) * (1.0f / 360.0f);
    float rs = rsqrtf(var + 1e-5f);
    float* orow = outp + (size_t)row * EMBD;
    orow[t]       = d0 * rs * sc[t]       + bc[t];
    orow[t + 128] = d1 * rs * sc[t + 128] + bc[t + 128];
    if (t < 104) orow[t + 256] = d2 * rs * sc[t + 256] + bc[t + 256];
}

// ---------------------------------------------------------------------------
// Mean over valid tokens: h[b,e] = (1/Tc) * sum_{j<Tc} x[b,j,e]
// ---------------------------------------------------------------------------
__global__ __launch_bounds__(256) void k_mean(
    const float* __restrict__ x, float* __restrict__ h,
    const int* __restrict__ tcp)
{
    const int e = blockIdx.x * 256 + threadIdx.x;
    const int b = blockIdx.y;
    if (e >= EMBD) return;
    int Tc = *tcp; if (Tc < 1) Tc = 1;
    const float* xp = x + (size_t)b * TBM * EMBD + e;
    float s0 = 0.f, s1 = 0.f, s2 = 0.f, s3 = 0.f;
    int j = 0;
    for (; j + 4 <= Tc; j += 4) {
        s0 += xp[(size_t)(j + 0) * EMBD];
        s1 += xp[(size_t)(j + 1) * EMBD];
        s2 += xp[(size_t)(j + 2) * EMBD];
        s3 += xp[(size_t)(j + 3) * EMBD];
    }
    for (; j < Tc; ++j) s0 += xp[(size_t)j * EMBD];
    h[b * EMBD + e] = (s0 + s1 + s2 + s3) / (float)Tc;
}

// ---------------------------------------------------------------------------
// Classification head: gelu(h@cw1+cb1) -> relu(@cw2+cb2) -> @cw3+cb3. 1 block.
// ---------------------------------------------------------------------------
__global__ __launch_bounds__(256) void k_head(
    const float* __restrict__ h,
    const float* __restrict__ cw1, const float* __restrict__ cb1,
    const float* __restrict__ cw2, const float* __restrict__ cb2,
    const float* __restrict__ cw3, const float* __restrict__ cb3,
    float* __restrict__ outp)
{
    __shared__ float hs[NB * EMBD];
    __shared__ float h1[NB * 256];
    __shared__ float h2[NB * 128];
    const int t = threadIdx.x;
    for (int i = t; i < NB * EMBD; i += 256) hs[i] = h[i];
    __syncthreads();
    for (int i = t; i < NB * 256; i += 256) {
        int b = i >> 8, o = i & 255;
        float s = cb1[o];
        for (int k = 0; k < EMBD; ++k) s = fmaf(hs[b * EMBD + k], cw1[k * 256 + o], s);
        h1[i] = gelu_f(s);
    }
    __syncthreads();
    for (int i = t; i < NB * 128; i += 256) {
        int b = i >> 7, o = i & 127;
        float s = cb2[o];
        for (int k = 0; k < 256; ++k) s = fmaf(h1[b * 256 + k], cw2[k * 128 + o], s);
        h2[i] = fmaxf(s, 0.0f);
    }
    __syncthreads();
    if (t < 16) {
        int b = t >> 1, o = t & 1;
        float s = cb3[o];
        for (int k = 0; k < 128; ++k) s = fmaf(h2[b * 128 + k], cw3[k * 2 + o], s);
        outp[t] = s;
    }
}

// ---------------------------------------------------------------------------
// kernel_launch
// Workspace layout (floats), ~233 MB total with aliasing:
//   big0: 28,311,552  (mid 13824x2048; aliases tmp450@0, F_emb@1,440,000, ao@0)
//   big1: 14,929,920  (qkv 13824x1080; aliases nodes@0)
//   xa, xb, t360: 4,976,640 each
//   hb: 2944; ints: valid[1728], cidx[1728], tcp
// ---------------------------------------------------------------------------
extern "C" void kernel_launch(void* const* d_in, const int* in_sizes, int n_in,
                              void* d_out, int out_size, void* d_ws, size_t ws_size,
                              hipStream_t stream)
{
    const float* F_roi  = (const float*)d_in[0];
    const int*   C      = (const int*)d_in[1];
    const float* ffn_w1 = (const float*)d_in[2];
    const float* ffn_b1 = (const float*)d_in[3];
    const float* ffn_w2 = (const float*)d_in[4];
    const float* ffn_b2 = (const float*)d_in[5];
    const float* wqkv   = (const float*)d_in[6];
    const float* bqkv   = (const float*)d_in[7];
    const float* wo     = (const float*)d_in[8];
    const float* bo     = (const float*)d_in[9];
    const float* ln1s   = (const float*)d_in[10];
    const float* ln1b   = (const float*)d_in[11];
    const float* wf1    = (const float*)d_in[12];
    const float* bf1    = (const float*)d_in[13];
    const float* wf2    = (const float*)d_in[14];
    const float* bf2    = (const float*)d_in[15];
    const float* ln2s   = (const float*)d_in[16];
    const float* ln2b   = (const float*)d_in[17];
    const float* cw1    = (const float*)d_in[18];
    const float* cb1    = (const float*)d_in[19];
    const float* cw2    = (const float*)d_in[20];
    const float* cb2    = (const float*)d_in[21];
    const float* cw3    = (const float*)d_in[22];
    const float* cb3    = (const float*)d_in[23];
    float* out = (float*)d_out;

    float* ws   = (float*)d_ws;
    float* big0 = ws;                               // 28,311,552
    float* big1 = big0 + 28311552;                  // 14,929,920
    float* xa   = big1 + 14929920;                  //  4,976,640
    float* xb   = xa + 4976640;
    float* t360 = xb + 4976640;
    float* hb   = t360 + 4976640;                   //  2944 (h buffer)
    int*   ints = (int*)(hb + 2944);
    int* valid = ints;
    int* cidx  = ints + 1728;
    int* tcp   = ints + 3456;

    float* tmp450 = big0;                 // 3200x450
    float* F_emb  = big0 + 1440000;       // 3200x360
    float* nodes  = big1;                 // 8x1728x360  (dead before qkv)
    float* aob    = big0;                 // 8x1728x360  (dead before mid)
    float* midb   = big0;                 // 13824x2048
    float* qkvb   = big1;                 // 13824x1080

    dim3 blk(256);

    // Node featurization
    k_gemm<1, false><<<dim3(4, 25), blk, 0, stream>>>(F_roi, ffn_w1, ffn_b1, nullptr, tmp450, 3200, 450, 512);
    k_gemm<0, false><<<dim3(3, 25), blk, 0, stream>>>(tmp450, ffn_w2, ffn_b2, nullptr, F_emb, 3200, 360, 450);
    k_pool<<<dim3(1728, 8), dim3(128), 0, stream>>>(F_emb, C, nodes);
    k_mask<<<dim3(1728), blk, 0, stream>>>(nodes, valid);
    k_scan<<<dim3(1), blk, 0, stream>>>(valid, cidx, tcp);
    k_compact<<<dim3(1728, 8), dim3(128), 0, stream>>>(nodes, cidx, tcp, xa);

    // Transformer layers
    for (int l = 0; l < 2; ++l) {
        const float* wq  = wqkv + (size_t)l * 360 * 1080;
        const float* bq  = bqkv + (size_t)l * 1080;
        const float* wol = wo   + (size_t)l * 360 * 360;
        const float* bol = bo   + (size_t)l * 360;
        const float* w1l = wf1  + (size_t)l * 360 * 2048;
        const float* b1l = bf1  + (size_t)l * 2048;
        const float* w2l = wf2  + (size_t)l * 2048 * 360;
        const float* b2l = bf2  + (size_t)l * 360;

        k_gemm<0, false><<<dim3(9, 108), blk, 0, stream>>>(xa, wq, bq, nullptr, qkvb, 13824, 1080, 360);
        k_attn<<<dim3(27, 4, 8), blk, 0, stream>>>(qkvb, aob, tcp);
        k_gemm<0, true><<<dim3(3, 108), blk, 0, stream>>>(aob, wol, bol, xa, t360, 13824, 360, 360);
        k_ln<<<dim3(13824), dim3(128), 0, stream>>>(t360, ln1s + l * 360, ln1b + l * 360, xb);
        k_gemm<1, false><<<dim3(16, 108), blk, 0, stream>>>(xb, w1l, b1l, nullptr, midb, 13824, 2048, 360);
        k_gemm<0, true><<<dim3(3, 108), blk, 0, stream>>>(midb, w2l, b2l, xb, t360, 13824, 360, 2048);
        k_ln<<<dim3(13824), dim3(128), 0, stream>>>(t360, ln2s + l * 360, ln2b + l * 360, xa);
    }

    // Head
    k_mean<<<dim3(2, 8), blk, 0, stream>>>(xa, hb, tcp);
    k_head<<<dim3(1), blk, 0, stream>>>(hb, cw1, cb1, cw2, cb2, cw3, cb3, out);
}

// Round 2
// 1853.712 us; speedup vs baseline: 2.7030x; 2.7030x over previous
//
#include <hip/hip_runtime.h>
#include <math.h>

#define NB   8
#define NROI 400
#define GG   25
#define EMBD 360
#define HDD  90
#define TBM  1728

typedef __attribute__((ext_vector_type(8)))  short bh8;    // 8 bf16 (4 VGPR)
typedef __attribute__((ext_vector_type(4)))  short bh4;
typedef __attribute__((ext_vector_type(16))) float f32x16;

#define MFMA(a,b,c) __builtin_amdgcn_mfma_f32_32x32x16_bf16(a,b,c,0,0,0)

__device__ __forceinline__ float gelu_f(float x) {
    return 0.5f * x * (1.0f + erff(x * 0.7071067811865475f));
}
// round-to-nearest-even fp32 -> bf16 bits
__device__ __forceinline__ short f2bf(float f) {
    unsigned u = __float_as_uint(f);
    unsigned r = (u + 0x7FFFu + ((u >> 16) & 1u)) >> 16;
    return (short)r;
}
__device__ __forceinline__ float bf2f(short h) {
    return __uint_as_float(((unsigned)(unsigned short)h) << 16);
}

// ---------------------------------------------------------------------------
// Weight split+transpose: W[K][N] fp32 -> Wt_hi/Wt_lo [Np][Kp] bf16 (zero pad)
// ---------------------------------------------------------------------------
__global__ __launch_bounds__(256) void k_wsplit(
    const float* __restrict__ W, int K, int N,
    short* __restrict__ Wh, short* __restrict__ Wl, int Kp, int Np)
{
    __shared__ float tile[32][33];
    const int k0 = blockIdx.x * 32, n0 = blockIdx.y * 32;
    const int t = threadIdx.x;
    #pragma unroll
    for (int it = 0; it < 4; ++it) {
        int e = t + it * 256;
        int i = e >> 5, j = e & 31;          // i = k-local, j = n-local
        float v = (k0 + i < K && n0 + j < N) ? W[(size_t)(k0 + i) * N + n0 + j] : 0.0f;
        tile[j][i] = v;
    }
    __syncthreads();
    #pragma unroll
    for (int it = 0; it < 4; ++it) {
        int e = t + it * 256;
        int n = e >> 5, kk = e & 31;
        float v = tile[n][kk];
        short hi = f2bf(v);
        short lo = f2bf(v - bf2f(hi));
        size_t off = (size_t)(n0 + n) * Kp + k0 + kk;
        Wh[off] = hi; Wl[off] = lo;
    }
}

// ---------------------------------------------------------------------------
// MFMA GEMM (split-bf16 x3): C = act(A@B + bias (+res))
// A fp32 [M][K]; B pre-split bf16 [Np][Kp] (transposed). 128x128 tile, BK=32,
// 4 waves of 64x64, 32x32x16 fragments. LDS in 16B-chunk layout [chunk][row].
// ---------------------------------------------------------------------------
template <int ACT, bool RES>   // ACT: 0 none, 1 gelu
__global__ __launch_bounds__(256, 2) void k_mgemm(
    const float* __restrict__ A, const short* __restrict__ Bth,
    const short* __restrict__ Btl, const float* __restrict__ bias,
    const float* res, float* Cc, int M, int N, int K, int Kp)
{
    __shared__ __align__(16) short Ah[4096], Al[4096], Bh[4096], Bl[4096];
    const int t = threadIdx.x;
    const int lane = t & 63, wid = t >> 6;
    const int half = lane >> 5, l31 = lane & 31;
    const int m0 = blockIdx.y * 128, n0 = blockIdx.x * 128;
    const int wm = (wid >> 1) * 64, wn = (wid & 1) * 64;

    f32x16 acc00 = {}, acc01 = {}, acc10 = {}, acc11 = {};
    const int nk = Kp >> 5;
    const bool k4 = (K & 3) == 0;

    for (int ks = 0; ks < nk; ++ks) {
        const int k0 = ks << 5;
        __syncthreads();
        // ---- stage A (fp32 -> hi/lo bf16), 128 rows x 32 k
        #pragma unroll
        for (int i = 0; i < 4; ++i) {
            int e = t + i * 256;
            int row = e >> 3, c4 = e & 7;
            int gm = m0 + row, kb = k0 + c4 * 4;
            float v0 = 0.f, v1 = 0.f, v2 = 0.f, v3 = 0.f;
            if (gm < M) {
                const float* ap = A + (size_t)gm * K + kb;
                if (k4 && kb + 3 < K) {
                    float4 fv = *(const float4*)ap;
                    v0 = fv.x; v1 = fv.y; v2 = fv.z; v3 = fv.w;
                } else {
                    if (kb + 0 < K) v0 = ap[0];
                    if (kb + 1 < K) v1 = ap[1];
                    if (kb + 2 < K) v2 = ap[2];
                    if (kb + 3 < K) v3 = ap[3];
                }
            }
            short h0 = f2bf(v0), h1 = f2bf(v1), h2 = f2bf(v2), h3 = f2bf(v3);
            bh4 hv = { h0, h1, h2, h3 };
            bh4 lv = { f2bf(v0 - bf2f(h0)), f2bf(v1 - bf2f(h1)),
                       f2bf(v2 - bf2f(h2)), f2bf(v3 - bf2f(h3)) };
            int c = c4 >> 1, sub = c4 & 1;
            *(bh4*)&Ah[(c * 128 + row) * 8 + sub * 4] = hv;
            *(bh4*)&Al[(c * 128 + row) * 8 + sub * 4] = lv;
        }
        // ---- stage B (bf16 copy, coalesced 64B groups)
        #pragma unroll
        for (int i = 0; i < 2; ++i) {
            int e = t + i * 256;
            int col = e >> 2, c = e & 3;
            size_t src = (size_t)(n0 + col) * Kp + k0 + c * 8;
            *(bh8*)&Bh[(c * 128 + col) * 8] = *(const bh8*)(Bth + src);
            *(bh8*)&Bl[(c * 128 + col) * 8] = *(const bh8*)(Btl + src);
        }
        __syncthreads();
        // ---- fragments
        bh8 ahf[2][2], alf[2][2], bhf[2][2], blf[2][2];
        #pragma unroll
        for (int m2 = 0; m2 < 2; ++m2)
            #pragma unroll
            for (int ku = 0; ku < 2; ++ku) {
                int c = ku * 2 + half;
                int arow = wm + m2 * 32 + l31;
                int bcol = wn + m2 * 32 + l31;
                ahf[m2][ku] = *(const bh8*)&Ah[(c * 128 + arow) * 8];
                alf[m2][ku] = *(const bh8*)&Al[(c * 128 + arow) * 8];
                bhf[m2][ku] = *(const bh8*)&Bh[(c * 128 + bcol) * 8];
                blf[m2][ku] = *(const bh8*)&Bl[(c * 128 + bcol) * 8];
            }
        #define TRIP(ACCV, AHI, ALO, BHI, BLO) \
            ACCV = MFMA(AHI, BHI, ACCV); ACCV = MFMA(AHI, BLO, ACCV); ACCV = MFMA(ALO, BHI, ACCV);
        #pragma unroll
        for (int ku = 0; ku < 2; ++ku) {
            TRIP(acc00, ahf[0][ku], alf[0][ku], bhf[0][ku], blf[0][ku])
            TRIP(acc01, ahf[0][ku], alf[0][ku], bhf[1][ku], blf[1][ku])
            TRIP(acc10, ahf[1][ku], alf[1][ku], bhf[0][ku], blf[0][ku])
            TRIP(acc11, ahf[1][ku], alf[1][ku], bhf[1][ku], blf[1][ku])
        }
        #undef TRIP
    }
    // ---- epilogue
    #define EPILOG(ACCV, M2, N2) { \
        int gn = n0 + wn + (N2) * 32 + l31; \
        if (gn < N) { \
            float bv = bias[gn]; \
            _Pragma("unroll") \
            for (int r = 0; r < 16; ++r) { \
                int gm = m0 + wm + (M2) * 32 + (r & 3) + 8 * (r >> 2) + 4 * half; \
                if (gm < M) { \
                    float v = ACCV[r] + bv; \
                    if (RES) v += res[(size_t)gm * N + gn]; \
                    if (ACT == 1) v = gelu_f(v); \
                    Cc[(size_t)gm * N + gn] = v; \
                } } } }
    EPILOG(acc00, 0, 0) EPILOG(acc01, 0, 1) EPILOG(acc10, 1, 0) EPILOG(acc11, 1, 1)
    #undef EPILOG
}

// ---------------------------------------------------------------------------
// Flash attention, bf16 MFMA. Block: 256 thr = 4 waves; wave owns 32 q-rows.
// No max-tracking (scores bounded); softmax denom via ones-column at d=90.
// ---------------------------------------------------------------------------
__global__ __launch_bounds__(256, 2) void k_mattn(
    const float* __restrict__ qkv, float* __restrict__ ao,
    const int* __restrict__ tcp)
{
    __shared__ __align__(16) short Kl[64 * 128];   // [kk][16 chunks], XOR-swz
    __shared__ __align__(16) short Vl[64 * 128];
    __shared__ __align__(16) short Pl[4][32 * 64]; // per wave [q][8 chunks]

    const int t = threadIdx.x;
    const int lane = t & 63, wid = t >> 6;
    const int half = lane >> 5, l31 = lane & 31;
    const int qt = blockIdx.x, h = blockIdx.y, b = blockIdx.z;
    const int Tc = *tcp;
    const int q0w = qt * 128 + wid * 32;
    const float scale = 0.105409255338945984f;  // 1/sqrt(90)
    const size_t base = (size_t)b * TBM * 1080 + h * HDD;

    // Q fragments in registers (scaled, bf16)
    bh8 qf[3];
    #pragma unroll
    for (int ku = 0; ku < 3; ++ku) {
        bh8 qv;
        int row = q0w + l31;
        #pragma unroll
        for (int j = 0; j < 8; ++j) {
            int d = ku * 32 + half * 8 + j;
            float v = (row < TBM && d < HDD) ? qkv[base + (size_t)row * 1080 + d] * scale : 0.0f;
            qv[j] = f2bf(v);
        }
        qf[ku] = qv;
    }

    f32x16 o0 = {}, o1 = {}, o2 = {};
    int nkt = (Tc + 63) >> 6; if (nkt > 27) nkt = 27;

    for (int kt = 0; kt < nkt; ++kt) {
        const int k0 = kt * 64;
        __syncthreads();
        // ---- stage K and V (+ ones column at d=90), 64 rows x 12 chunks each
        #pragma unroll
        for (int i = 0; i < 3; ++i) {
            int cid = t + i * 256;
            int kk = cid / 12, c = cid - kk * 12;
            int cp = c ^ (kk & 7);
            const float* srck = qkv + base + (size_t)(k0 + kk) * 1080 + 360 + c * 8;
            const float* srcv = qkv + base + (size_t)(k0 + kk) * 1080 + 720 + c * 8;
            bh8 kv, vv;
            #pragma unroll
            for (int j = 0; j < 8; ++j) {
                int d = c * 8 + j;
                kv[j] = f2bf(d < HDD ? srck[j] : 0.0f);
                vv[j] = f2bf(d < HDD ? srcv[j] : (d == HDD ? 1.0f : 0.0f));
            }
            *(bh8*)&Kl[kk * 128 + cp * 8] = kv;
            *(bh8*)&Vl[kk * 128 + cp * 8] = vv;
        }
        __syncthreads();
        // ---- S = Q K^T  (two 32-key fragments)
        f32x16 s0 = {}, s1 = {};
        #pragma unroll
        for (int ku = 0; ku < 3; ++ku) {
            int c = ku * 4 + half;
            int cp = c ^ (l31 & 7);
            bh8 kb0 = *(const bh8*)&Kl[(l31) * 128 + cp * 8];
            bh8 kb1 = *(const bh8*)&Kl[(32 + l31) * 128 + cp * 8];
            s0 = MFMA(qf[ku], kb0, s0);
            s1 = MFMA(qf[ku], kb1, s1);
        }
        // ---- P = exp(S) (no shift; scores bounded), masked, write to Pl
        const bool ok0 = (k0 + l31) < Tc;
        const bool ok1 = (k0 + 32 + l31) < Tc;
        const int c0 = l31 >> 3, c1 = 4 + (l31 >> 3), j0 = l31 & 7;
        #pragma unroll
        for (int r = 0; r < 16; ++r) {
            int ql = (r & 3) + 8 * (r >> 2) + 4 * half;
            float p0 = ok0 ? __expf(s0[r]) : 0.0f;
            float p1 = ok1 ? __expf(s1[r]) : 0.0f;
            Pl[wid][ql * 64 + (c0 ^ (ql & 7)) * 8 + j0] = f2bf(p0);
            Pl[wid][ql * 64 + (c1 ^ (ql & 7)) * 8 + j0] = f2bf(p1);
        }
        asm volatile("s_waitcnt lgkmcnt(0)" ::: "memory");
        __builtin_amdgcn_sched_barrier(0);
        // ---- PA fragments
        bh8 pa[2];
        #pragma unroll
        for (int ku = 0; ku < 2; ++ku) {
            int c = ku * 4 + half;
            int cp = c ^ (l31 & 7);
            pa[ku] = *(const bh8*)&Pl[wid][l31 * 64 + cp * 8];
        }
        // ---- V fragments (strided u16 reads) + PV MFMA
        #pragma unroll
        for (int n = 0; n < 3; ++n) {
            f32x16* op = n == 0 ? &o0 : (n == 1 ? &o1 : &o2);
            #pragma unroll
            for (int ku = 0; ku < 2; ++ku) {
                bh8 vb;
                int d = n * 32 + l31;
                int cd = d >> 3, jd = d & 7;
                #pragma unroll
                for (int j = 0; j < 8; ++j) {
                    int kk = ku * 32 + half * 8 + j;
                    vb[j] = Vl[kk * 128 + (cd ^ (kk & 7)) * 8 + jd];
                }
                *op = MFMA(pa[ku], vb, *op);
            }
        }
    }

    // ---- normalize by denominator (col d=90 of o2, lane half*32+26) and store
    #pragma unroll
    for (int r = 0; r < 16; ++r) {
        float den = __shfl(o2[r], (lane & 32) | 26);
        float inv = (den > 0.0f) ? 1.0f / den : 0.0f;
        int qg = q0w + (r & 3) + 8 * (r >> 2) + 4 * half;
        if (qg < Tc) {
            size_t orow = ((size_t)b * TBM + qg) * EMBD + h * HDD;
            int d0 = l31, d1 = 32 + l31, d2 = 64 + l31;
            ao[orow + d0] = o0[r] * inv;
            ao[orow + d1] = o1[r] * inv;
            if (d2 < HDD) ao[orow + d2] = o2[r] * inv;
        }
    }
}

// ---------------------------------------------------------------------------
// Gather + 3^3 sum-pool
// ---------------------------------------------------------------------------
__global__ __launch_bounds__(128) void k_pool(
    const float* __restrict__ F_emb, const int* __restrict__ C,
    float* __restrict__ nodes)
{
    const int tkn = blockIdx.x, b = blockIdx.y;
    const int oz = tkn % 12, oy = (tkn / 12) % 12, ox = tkn / 144;
    __shared__ int idx[27];
    const int tid = threadIdx.x;
    if (tid < 27) {
        int dx = tid / 9, dy = (tid / 3) % 3, dz = tid % 3;
        idx[tid] = C[(((b * GG) + ox * 2 + dx) * GG + oy * 2 + dy) * GG + oz * 2 + dz];
    }
    __syncthreads();
    float a0 = 0.f, a1 = 0.f, a2 = 0.f;
    for (int n = 0; n < 27; ++n) {
        int c = idx[n];
        if (c == 0) continue;
        const float* src = F_emb + (size_t)(b * NROI + (c - 1)) * EMBD;
        a0 += src[tid]; a1 += src[tid + 128];
        if (tid < 104) a2 += src[tid + 256];
    }
    float* dst = nodes + ((size_t)b * TBM + tkn) * EMBD;
    dst[tid] = a0; dst[tid + 128] = a1;
    if (tid < 104) dst[tid + 256] = a2;
}

__global__ __launch_bounds__(256) void k_mask(
    const float* __restrict__ nodes, int* __restrict__ valid)
{
    const int tkn = blockIdx.x;
    float s = 0.f;
    for (int i = threadIdx.x; i < NB * EMBD; i += 256) {
        int b = i / EMBD, e = i - b * EMBD;
        s += fabsf(nodes[((size_t)b * TBM + tkn) * EMBD + e]);
    }
    #pragma unroll
    for (int o = 32; o >= 1; o >>= 1) s += __shfl_xor(s, o);
    __shared__ float red[4];
    if ((threadIdx.x & 63) == 0) red[threadIdx.x >> 6] = s;
    __syncthreads();
    if (threadIdx.x == 0)
        valid[tkn] = ((red[0] + red[1] + red[2] + red[3]) > 0.f) ? 1 : 0;
}

__global__ __launch_bounds__(256) void k_scan(
    const int* __restrict__ valid, int* __restrict__ cidx, int* __restrict__ tcp)
{
    __shared__ int csum[256];
    __shared__ int coff[256];
    const int t = threadIdx.x;
    const int base = t * 7;
    int loc[7]; int s = 0;
    #pragma unroll
    for (int i = 0; i < 7; ++i) {
        int g = base + i;
        int v = (g < TBM) ? valid[g] : 0;
        loc[i] = v; s += v;
    }
    csum[t] = s;
    __syncthreads();
    if (t == 0) {
        int a = 0;
        for (int i = 0; i < 256; ++i) { coff[i] = a; a += csum[i]; }
        *tcp = a;
    }
    __syncthreads();
    int off = coff[t];
    #pragma unroll
    for (int i = 0; i < 7; ++i) {
        int g = base + i;
        if (g < TBM && loc[i]) cidx[off++] = g;
    }
}

__global__ __launch_bounds__(128) void k_compact(
    const float* __restrict__ nodes, const int* __restrict__ cidx,
    const int* __restrict__ tcp, float* __restrict__ x)
{
    const int j = blockIdx.x, b = blockIdx.y;
    const int Tc = *tcp;
    float* dst = x + ((size_t)b * TBM + j) * EMBD;
    if (j >= Tc) {
        for (int e = threadIdx.x; e < EMBD; e += 128) dst[e] = 0.f;
        return;
    }
    const float* src = nodes + ((size_t)b * TBM + cidx[j]) * EMBD;
    for (int e = threadIdx.x; e < EMBD; e += 128) dst[e] = src[e];
}

// LayerNorm (in-place safe: y and outp may alias)
__global__ __launch_bounds__(128) void k_ln(
    const float* y, const float* __restrict__ sc,
    const float* __restrict__ bc, float* outp)
{
    const int row = blockIdx.x;
    const int t = threadIdx.x;
    const float* yr = y + (size_t)row * EMBD;
    float x0 = yr[t], x1 = yr[t + 128];
    float x2 = (t < 104) ? yr[t + 256] : 0.0f;
    float sum = x0 + x1 + x2;
    __shared__ float red[2];
    #pragma unroll
    for (int o = 32; o >= 1; o >>= 1) sum += __shfl_xor(sum, o);
    if ((t & 63) == 0) red[t >> 6] = sum;
    __syncthreads();
    float mean = (red[0] + red[1]) * (1.0f / 360.0f);
    float d0 = x0 - mean, d1 = x1 - mean, d2 = (t < 104) ? (x2 - mean) : 0.0f;
    float vs = d0 * d0 + d1 * d1 + d2 * d2;
    __syncthreads();
    #pragma unroll
    for (int o = 32; o >= 1; o >>= 1) vs += __shfl_xor(vs, o);
    if ((t & 63) == 0) red[t >> 6] = vs;
    __syncthreads();
    float var = (red[0] + red[1]) * (1.0f / 360.0f);
    float rs = rsqrtf(var + 1e-5f);
    float* orow = outp + (size_t)row * EMBD;
    orow[t]       = d0 * rs * sc[t]       + bc[t];
    orow[t + 128] = d1 * rs * sc[t + 128] + bc[t + 128];
    if (t < 104) orow[t + 256] = d2 * rs * sc[t + 256] + bc[t + 256];
}

__global__ __launch_bounds__(256) void k_mean(
    const float* __restrict__ x, float* __restrict__ h,
    const int* __restrict__ tcp)
{
    const int e = blockIdx.x * 256 + threadIdx.x;
    const int b = blockIdx.y;
    if (e >= EMBD) return;
    int Tc = *tcp; if (Tc < 1) Tc = 1;
    const float* xp = x + (size_t)b * TBM * EMBD + e;
    float s0 = 0.f, s1 = 0.f, s2 = 0.f, s3 = 0.f;
    int j = 0;
    for (; j + 4 <= Tc; j += 4) {
        s0 += xp[(size_t)(j + 0) * EMBD]; s1 += xp[(size_t)(j + 1) * EMBD];
        s2 += xp[(size_t)(j + 2) * EMBD]; s3 += xp[(size_t)(j + 3) * EMBD];
    }
    for (; j < Tc; ++j) s0 += xp[(size_t)j * EMBD];
    h[b * EMBD + e] = (s0 + s1 + s2 + s3) / (float)Tc;
}

__global__ __launch_bounds__(256) void k_head(
    const float* __restrict__ h,
    const float* __restrict__ cw1, const float* __restrict__ cb1,
    const float* __restrict__ cw2, const float* __restrict__ cb2,
    const float* __restrict__ cw3, const float* __restrict__ cb3,
    float* __restrict__ outp)
{
    __shared__ float hs[NB * EMBD];
    __shared__ float h1[NB * 256];
    __shared__ float h2[NB * 128];
    const int t = threadIdx.x;
    for (int i = t; i < NB * EMBD; i += 256) hs[i] = h[i];
    __syncthreads();
    for (int i = t; i < NB * 256; i += 256) {
        int b = i >> 8, o = i & 255;
        float s = cb1[o];
        for (int k = 0; k < EMBD; ++k) s = fmaf(hs[b * EMBD + k], cw1[k * 256 + o], s);
        h1[i] = gelu_f(s);
    }
    __syncthreads();
    for (int i = t; i < NB * 128; i += 256) {
        int b = i >> 7, o = i & 127;
        float s = cb2[o];
        for (int k = 0; k < 256; ++k) s = fmaf(h1[b * 256 + k], cw2[k * 128 + o], s);
        h2[i] = fmaxf(s, 0.0f);
    }
    __syncthreads();
    if (t < 16) {
        int b = t >> 1, o = t & 1;
        float s = cb3[o];
        for (int k = 0; k < 128; ++k) s = fmaf(h2[b * 128 + k], cw3[k * 2 + o], s);
        outp[t] = s;
    }
}

// ---------------------------------------------------------------------------
extern "C" void kernel_launch(void* const* d_in, const int* in_sizes, int n_in,
                              void* d_out, int out_size, void* d_ws, size_t ws_size,
                              hipStream_t stream)
{
    const float* F_roi  = (const float*)d_in[0];
    const int*   C      = (const int*)d_in[1];
    const float* ffn_w1 = (const float*)d_in[2];
    const float* ffn_b1 = (const float*)d_in[3];
    const float* ffn_w2 = (const float*)d_in[4];
    const float* ffn_b2 = (const float*)d_in[5];
    const float* wqkv   = (const float*)d_in[6];
    const float* bqkv   = (const float*)d_in[7];
    const float* wo     = (const float*)d_in[8];
    const float* bo     = (const float*)d_in[9];
    const float* ln1s   = (const float*)d_in[10];
    const float* ln1b   = (const float*)d_in[11];
    const float* wf1    = (const float*)d_in[12];
    const float* bf1    = (const float*)d_in[13];
    const float* wf2    = (const float*)d_in[14];
    const float* bf2    = (const float*)d_in[15];
    const float* ln2s   = (const float*)d_in[16];
    const float* ln2b   = (const float*)d_in[17];
    const float* cw1    = (const float*)d_in[18];
    const float* cb1    = (const float*)d_in[19];
    const float* cw2    = (const float*)d_in[20];
    const float* cb2    = (const float*)d_in[21];
    const float* cw3    = (const float*)d_in[22];
    const float* cb3    = (const float*)d_in[23];
    float* out = (float*)d_out;

    float* ws   = (float*)d_ws;
    float* big0 = ws;                        // 28,311,552 f (midb / tmp450+F_emb / aob)
    float* big1 = ws + 28311552;             // 14,929,920 f (qkvb / nodes)
    float* t360 = ws + 43241472;             //  4,976,640 f (x, in-place stream)
    short* sw   = (short*)(ws + 48218112);   //  bf16 split-weight area

    size_t so = 0;
    auto salloc = [&](size_t n) { short* p = sw + so; so += n; return p; };
    short* w1h = salloc(262144); short* w1l = salloc(262144);
    short* w2h = salloc(184320); short* w2l = salloc(184320);
    short *qkvh[2], *qkvl[2], *woh[2], *wol[2], *f1h[2], *f1l[2], *f2h[2], *f2l[2];
    for (int l = 0; l < 2; ++l) {
        qkvh[l] = salloc(442368); qkvl[l] = salloc(442368);
        woh[l]  = salloc(147456); wol[l]  = salloc(147456);
        f1h[l]  = salloc(786432); f1l[l]  = salloc(786432);
        f2h[l]  = salloc(786432); f2l[l]  = salloc(786432);
    }
    float* hb  = ws + 48218112 + 4771840;
    int* ints  = (int*)(hb + 2944);
    int* valid = ints, *cidx = ints + 1728, *tcp = ints + 3456;

    float* tmp450 = big0;
    float* F_emb  = big0 + 1440000;
    float* nodes  = big1;
    float* aob    = big0;
    float* midb   = big0;
    float* qkvb   = big1;

    dim3 blk(256);

    // Weight split/transposes (once per launch)
    k_wsplit<<<dim3(16, 16), blk, 0, stream>>>(ffn_w1, 512, 450, w1h, w1l, 512, 512);
    k_wsplit<<<dim3(15, 12), blk, 0, stream>>>(ffn_w2, 450, 360, w2h, w2l, 480, 384);
    for (int l = 0; l < 2; ++l) {
        k_wsplit<<<dim3(12, 36), blk, 0, stream>>>(wqkv + (size_t)l * 360 * 1080, 360, 1080, qkvh[l], qkvl[l], 384, 1152);
        k_wsplit<<<dim3(12, 12), blk, 0, stream>>>(wo   + (size_t)l * 360 * 360,  360, 360,  woh[l],  wol[l],  384, 384);
        k_wsplit<<<dim3(12, 64), blk, 0, stream>>>(wf1  + (size_t)l * 360 * 2048, 360, 2048, f1h[l],  f1l[l],  384, 2048);
        k_wsplit<<<dim3(64, 12), blk, 0, stream>>>(wf2  + (size_t)l * 2048 * 360, 2048, 360, f2h[l],  f2l[l],  2048, 384);
    }

    // Node featurization
    k_mgemm<1, false><<<dim3(4, 25), blk, 0, stream>>>(F_roi, w1h, w1l, ffn_b1, nullptr, tmp450, 3200, 450, 512, 512);
    k_mgemm<0, false><<<dim3(3, 25), blk, 0, stream>>>(tmp450, w2h, w2l, ffn_b2, nullptr, F_emb, 3200, 360, 450, 480);
    k_pool<<<dim3(1728, 8), dim3(128), 0, stream>>>(F_emb, C, nodes);
    k_mask<<<dim3(1728), blk, 0, stream>>>(nodes, valid);
    k_scan<<<dim3(1), blk, 0, stream>>>(valid, cidx, tcp);
    k_compact<<<dim3(1728, 8), dim3(128), 0, stream>>>(nodes, cidx, tcp, t360);

    // Transformer layers (x stream lives in t360, in-place)
    for (int l = 0; l < 2; ++l) {
        k_mgemm<0, false><<<dim3(9, 108), blk, 0, stream>>>(t360, qkvh[l], qkvl[l], bqkv + l * 1080, nullptr, qkvb, 13824, 1080, 360, 384);
        k_mattn<<<dim3(14, 4, 8), blk, 0, stream>>>(qkvb, aob, tcp);
        k_mgemm<0, true><<<dim3(3, 108), blk, 0, stream>>>(aob, woh[l], wol[l], bo + l * 360, t360, t360, 13824, 360, 360, 384);
        k_ln<<<dim3(13824), dim3(128), 0, stream>>>(t360, ln1s + l * 360, ln1b + l * 360, t360);
        k_mgemm<1, false><<<dim3(16, 108), blk, 0, stream>>>(t360, f1h[l], f1l[l], bf1 + l * 2048, nullptr, midb, 13824, 2048, 360, 384);
        k_mgemm<0, true><<<dim3(3, 108), blk, 0, stream>>>(midb, f2h[l], f2l[l], bf2 + l * 360, t360, t360, 13824, 360, 2048, 2048);
        k_ln<<<dim3(13824), dim3(128), 0, stream>>>(t360, ln2s + l * 360, ln2b + l * 360, t360);
    }

    // Head
    k_mean<<<dim3(2, 8), blk, 0, stream>>>(t360, hb, tcp);
    k_head<<<dim3(1), blk, 0, stream>>>(hb, cw1, cb1, cw2, cb2, cw3, cb3, out);
}

// Round 3
// 1358.885 us; speedup vs baseline: 3.6873x; 1.3641x over previous
//
#include <hip/hip_runtime.h>
#include <math.h>

#define NB   8
#define NROI 400
#define GG   25
#define EMBD 360
#define HDD  90
#define TBM  1728

typedef __attribute__((ext_vector_type(8)))  _Float16 h8;   // 8 f16 (4 VGPR)
typedef __attribute__((ext_vector_type(4)))  _Float16 h4;
typedef __attribute__((ext_vector_type(16))) float f32x16;

#define MFMA16(a,b,c) __builtin_amdgcn_mfma_f32_32x32x16_f16(a,b,c,0,0,0)
#define QSCALE 0.105409255338945984f   /* 1/sqrt(90) */

__device__ __forceinline__ float gelu_f(float x) {
    return 0.5f * x * (1.0f + erff(x * 0.7071067811865475f));
}

// ---------------------------------------------------------------------------
// Weight convert+transpose: W[K][N] fp32 -> Wt[Np][Kp] f16 (zero-padded)
// ---------------------------------------------------------------------------
__global__ __launch_bounds__(256) void k_wconv(
    const float* __restrict__ W, int K, int N,
    _Float16* __restrict__ Wt, int Kp, int Np)
{
    int id = blockIdx.x * 256 + threadIdx.x;
    if (id >= Np * Kp) return;
    int n = id / Kp, kk = id - n * Kp;
    float v = (n < N && kk < K) ? W[(size_t)kk * N + n] : 0.0f;
    Wt[id] = (_Float16)v;
}

// qkv weight: W[360][1080] -> Wt[1152][384], col map n' = sec*384+96h+d,
// Q section scaled by 1/sqrt(90), pads zero.
__global__ __launch_bounds__(256) void k_wconv_qkv(
    const float* __restrict__ W, _Float16* __restrict__ Wt)
{
    int id = blockIdx.x * 256 + threadIdx.x;
    if (id >= 1152 * 384) return;
    int np = id / 384, kk = id - np * 384;
    int sec = np / 384 == 0 ? np / 384 : np / 384;   // np<1152
    sec = np / 384;
    int r = np - sec * 384, h = r / 96, d = r - h * 96;
    float v = 0.0f;
    if (d < HDD && kk < 360) v = W[(size_t)kk * 1080 + sec * 360 + h * HDD + d];
    if (sec == 0) v *= QSCALE;
    Wt[id] = (_Float16)v;
}

// padded qkv bias [1152]: Q scaled, V-pad d==90 -> 1.0 (softmax denom column)
__global__ __launch_bounds__(256) void k_bias_qkv(
    const float* __restrict__ bq, float* __restrict__ bp)
{
    int id = blockIdx.x * 256 + threadIdx.x;
    if (id >= 1152) return;
    int sec = id / 384, r = id - sec * 384, h = r / 96, d = r - h * 96;
    float v = 0.0f;
    if (d < HDD) v = bq[sec * 360 + h * HDD + d];
    if (sec == 0) v *= QSCALE;
    if (sec == 2 && d == HDD) v = 1.0f;
    bp[id] = v;
}

// ---------------------------------------------------------------------------
// MFMA GEMM (f16 single-pass): C = act(A@B + bias (+res))
// A fp32 [M][K]; B f16 [Np][Kp] transposed. 128x128 tile, BK=32, 4 waves,
// 32x32x16 fragments. OUTH: write _Float16 instead of fp32.
// ---------------------------------------------------------------------------
template <int ACT, bool RES, bool OUTH>   // ACT: 0 none, 1 gelu
__global__ __launch_bounds__(256, 2) void k_mgemm(
    const float* __restrict__ A, const _Float16* __restrict__ Bt,
    const float* __restrict__ bias, const float* res, void* Cp,
    int M, int N, int K, int Kp)
{
    __shared__ __align__(16) _Float16 Ah[4096], Bh[4096];
    const int t = threadIdx.x;
    const int lane = t & 63, wid = t >> 6;
    const int half = lane >> 5, l31 = lane & 31;
    const int m0 = blockIdx.y * 128, n0 = blockIdx.x * 128;
    const int wm = (wid >> 1) * 64, wn = (wid & 1) * 64;

    f32x16 acc00 = {}, acc01 = {}, acc10 = {}, acc11 = {};
    const int nk = Kp >> 5;
    const bool k4 = (K & 3) == 0;

    for (int ks = 0; ks < nk; ++ks) {
        const int k0 = ks << 5;
        __syncthreads();
        // ---- stage A (fp32 -> f16), 128 rows x 32 k
        #pragma unroll
        for (int i = 0; i < 4; ++i) {
            int e = t + i * 256;
            int row = e >> 3, c4 = e & 7;
            int gm = m0 + row, kb = k0 + c4 * 4;
            float v0 = 0.f, v1 = 0.f, v2 = 0.f, v3 = 0.f;
            if (gm < M) {
                const float* ap = A + (size_t)gm * K + kb;
                if (k4 && kb + 3 < K) {
                    float4 fv = *(const float4*)ap;
                    v0 = fv.x; v1 = fv.y; v2 = fv.z; v3 = fv.w;
                } else {
                    if (kb + 0 < K) v0 = ap[0];
                    if (kb + 1 < K) v1 = ap[1];
                    if (kb + 2 < K) v2 = ap[2];
                    if (kb + 3 < K) v3 = ap[3];
                }
            }
            h4 hv = { (_Float16)v0, (_Float16)v1, (_Float16)v2, (_Float16)v3 };
            int c = c4 >> 1, sub = c4 & 1;
            *(h4*)&Ah[(c * 128 + row) * 8 + sub * 4] = hv;
        }
        // ---- stage B (f16 copy)
        #pragma unroll
        for (int i = 0; i < 2; ++i) {
            int e = t + i * 256;
            int col = e >> 2, c = e & 3;
            *(h8*)&Bh[(c * 128 + col) * 8] =
                *(const h8*)(Bt + (size_t)(n0 + col) * Kp + k0 + c * 8);
        }
        __syncthreads();
        // ---- fragments + 8 MFMA
        h8 af[2][2], bf[2][2];
        #pragma unroll
        for (int m2 = 0; m2 < 2; ++m2)
            #pragma unroll
            for (int ku = 0; ku < 2; ++ku) {
                int c = ku * 2 + half;
                af[m2][ku] = *(const h8*)&Ah[(c * 128 + wm + m2 * 32 + l31) * 8];
                bf[m2][ku] = *(const h8*)&Bh[(c * 128 + wn + m2 * 32 + l31) * 8];
            }
        #pragma unroll
        for (int ku = 0; ku < 2; ++ku) {
            acc00 = MFMA16(af[0][ku], bf[0][ku], acc00);
            acc01 = MFMA16(af[0][ku], bf[1][ku], acc01);
            acc10 = MFMA16(af[1][ku], bf[0][ku], acc10);
            acc11 = MFMA16(af[1][ku], bf[1][ku], acc11);
        }
    }
    // ---- epilogue
    float* Cf = (float*)Cp;
    _Float16* Ch = (_Float16*)Cp;
    #define EPILOG(ACCV, M2, N2) { \
        int gn = n0 + wn + (N2) * 32 + l31; \
        if (gn < N) { \
            float bv = bias[gn]; \
            _Pragma("unroll") \
            for (int r = 0; r < 16; ++r) { \
                int gm = m0 + wm + (M2) * 32 + (r & 3) + 8 * (r >> 2) + 4 * half; \
                if (gm < M) { \
                    float v = ACCV[r] + bv; \
                    if (RES) v += res[(size_t)gm * N + gn]; \
                    if (ACT == 1) v = gelu_f(v); \
                    if (OUTH) Ch[(size_t)gm * N + gn] = (_Float16)v; \
                    else      Cf[(size_t)gm * N + gn] = v; \
                } } } }
    EPILOG(acc00, 0, 0) EPILOG(acc01, 0, 1) EPILOG(acc10, 1, 0) EPILOG(acc11, 1, 1)
    #undef EPILOG
}

// ---------------------------------------------------------------------------
// Flash attention, f16 MFMA, FULL d/key coverage. qkv f16 [13824][1152]:
// sec*384 + h*96 + d; Q pre-scaled; V has 1.0 at d==90 (denominator column).
// Block = 256 thr (4 waves x 32 q-rows). Grid 448 linear, bh-major for L2.
// ---------------------------------------------------------------------------
__global__ __launch_bounds__(256, 2) void k_mattn(
    const _Float16* __restrict__ qkv, float* __restrict__ ao,
    const int* __restrict__ tcp)
{
    __shared__ __align__(16) _Float16 Kl[64 * 128];   // [kk][12 chunks] XOR-swz
    __shared__ __align__(16) _Float16 Vl[64 * 128];
    __shared__ __align__(16) _Float16 Pl[4][32 * 64]; // per-wave [q][8 chunks]

    const int t = threadIdx.x;
    const int lane = t & 63, wid = t >> 6;
    const int half = lane >> 5, l31 = lane & 31;
    const int bid = blockIdx.x;
    const int bh = bid & 31, qt = bid >> 5;     // same (b,h) -> same XCD
    const int h = bh & 3, b = bh >> 2;
    const int Tc = *tcp;
    const int q0w = qt * 128 + wid * 32;
    const size_t base = (size_t)b * TBM * 1152;

    // Q fragments (6 x 16 d = 96, pads are zero)
    h8 qf[6];
    {
        int rl = q0w + l31; if (rl > TBM - 1) rl = TBM - 1;
        const _Float16* qrow = qkv + base + (size_t)rl * 1152 + 96 * h;
        #pragma unroll
        for (int ku = 0; ku < 6; ++ku)
            qf[ku] = *(const h8*)(qrow + ku * 16 + half * 8);
    }

    f32x16 o0 = {}, o1 = {}, o2 = {};
    int nkt = (Tc + 63) >> 6; if (nkt > 27) nkt = 27;

    for (int kt = 0; kt < nkt; ++kt) {
        const int k0 = kt * 64;
        __syncthreads();
        // ---- stage K and V: 64 rows x 12 chunks, direct 16B copies
        #pragma unroll
        for (int i = 0; i < 3; ++i) {
            int cid = t + i * 256;
            int kk = cid / 12, c = cid - kk * 12;
            int cp = c ^ (kk & 7);
            const _Float16* src = qkv + base + (size_t)(k0 + kk) * 1152 + 96 * h;
            *(h8*)&Kl[kk * 128 + cp * 8] = *(const h8*)(src + 384 + c * 8);
            *(h8*)&Vl[kk * 128 + cp * 8] = *(const h8*)(src + 768 + c * 8);
        }
        __syncthreads();
        // ---- S = Q K^T (full 96 d, 12 MFMAs)
        f32x16 s0 = {}, s1 = {};
        #pragma unroll
        for (int ku = 0; ku < 6; ++ku) {
            int c = ku * 2 + half;
            int cp = c ^ (l31 & 7);
            h8 kb0 = *(const h8*)&Kl[l31 * 128 + cp * 8];
            h8 kb1 = *(const h8*)&Kl[(32 + l31) * 128 + cp * 8];
            s0 = MFMA16(qf[ku], kb0, s0);
            s1 = MFMA16(qf[ku], kb1, s1);
        }
        // ---- P = exp(S) (scores bounded, no shift), masked, store f16
        const bool ok0 = (k0 + l31) < Tc;
        const bool ok1 = (k0 + 32 + l31) < Tc;
        const int c0 = l31 >> 3, c1 = 4 + (l31 >> 3), j0 = l31 & 7;
        #pragma unroll
        for (int r = 0; r < 16; ++r) {
            int ql = (r & 3) + 8 * (r >> 2) + 4 * half;
            float p0 = ok0 ? __expf(s0[r]) : 0.0f;
            float p1 = ok1 ? __expf(s1[r]) : 0.0f;
            Pl[wid][ql * 64 + (c0 ^ (ql & 7)) * 8 + j0] = (_Float16)p0;
            Pl[wid][ql * 64 + (c1 ^ (ql & 7)) * 8 + j0] = (_Float16)p1;
        }
        asm volatile("s_waitcnt lgkmcnt(0)" ::: "memory");
        __builtin_amdgcn_sched_barrier(0);
        // ---- PA fragments (full kk 0..63)
        h8 pa[4];
        #pragma unroll
        for (int ku = 0; ku < 4; ++ku) {
            int c = ku * 2 + half;
            pa[ku] = *(const h8*)&Pl[wid][l31 * 64 + (c ^ (l31 & 7)) * 8];
        }
        // ---- PV (12 MFMAs over 3 d-groups x 4 kk-groups)
        #pragma unroll
        for (int n = 0; n < 3; ++n) {
            f32x16* op = n == 0 ? &o0 : (n == 1 ? &o1 : &o2);
            int d = n * 32 + l31;
            int cd = d >> 3, jd = d & 7;
            #pragma unroll
            for (int ku = 0; ku < 4; ++ku) {
                h8 vb;
                #pragma unroll
                for (int j = 0; j < 8; ++j) {
                    int kk = ku * 16 + half * 8 + j;
                    vb[j] = Vl[kk * 128 + (cd ^ (kk & 7)) * 8 + jd];
                }
                *op = MFMA16(pa[ku], vb, *op);
            }
        }
        __syncthreads();
    }

    // ---- normalize by denominator (d=90 column of o2 -> lane (half,26))
    #pragma unroll
    for (int r = 0; r < 16; ++r) {
        float den = __shfl(o2[r], (lane & 32) | 26);
        float inv = (den > 0.0f) ? 1.0f / den : 0.0f;
        int qg = q0w + (r & 3) + 8 * (r >> 2) + 4 * half;
        if (qg < Tc) {
            size_t orow = ((size_t)b * TBM + qg) * EMBD + h * HDD;
            ao[orow + l31]      = o0[r] * inv;
            ao[orow + 32 + l31] = o1[r] * inv;
            if (64 + l31 < HDD) ao[orow + 64 + l31] = o2[r] * inv;
        }
    }
}

// ---------------------------------------------------------------------------
// Gather + 3^3 sum-pool
// ---------------------------------------------------------------------------
__global__ __launch_bounds__(128) void k_pool(
    const float* __restrict__ F_emb, const int* __restrict__ C,
    float* __restrict__ nodes)
{
    const int tkn = blockIdx.x, b = blockIdx.y;
    const int oz = tkn % 12, oy = (tkn / 12) % 12, ox = tkn / 144;
    __shared__ int idx[27];
    const int tid = threadIdx.x;
    if (tid < 27) {
        int dx = tid / 9, dy = (tid / 3) % 3, dz = tid % 3;
        idx[tid] = C[(((b * GG) + ox * 2 + dx) * GG + oy * 2 + dy) * GG + oz * 2 + dz];
    }
    __syncthreads();
    float a0 = 0.f, a1 = 0.f, a2 = 0.f;
    for (int n = 0; n < 27; ++n) {
        int c = idx[n];
        if (c == 0) continue;
        const float* src = F_emb + (size_t)(b * NROI + (c - 1)) * EMBD;
        a0 += src[tid]; a1 += src[tid + 128];
        if (tid < 104) a2 += src[tid + 256];
    }
    float* dst = nodes + ((size_t)b * TBM + tkn) * EMBD;
    dst[tid] = a0; dst[tid + 128] = a1;
    if (tid < 104) dst[tid + 256] = a2;
}

__global__ __launch_bounds__(256) void k_mask(
    const float* __restrict__ nodes, int* __restrict__ valid)
{
    const int tkn = blockIdx.x;
    float s = 0.f;
    for (int i = threadIdx.x; i < NB * EMBD; i += 256) {
        int b = i / EMBD, e = i - b * EMBD;
        s += fabsf(nodes[((size_t)b * TBM + tkn) * EMBD + e]);
    }
    #pragma unroll
    for (int o = 32; o >= 1; o >>= 1) s += __shfl_xor(s, o);
    __shared__ float red[4];
    if ((threadIdx.x & 63) == 0) red[threadIdx.x >> 6] = s;
    __syncthreads();
    if (threadIdx.x == 0)
        valid[tkn] = ((red[0] + red[1] + red[2] + red[3]) > 0.f) ? 1 : 0;
}

__global__ __launch_bounds__(256) void k_scan(
    const int* __restrict__ valid, int* __restrict__ cidx, int* __restrict__ tcp)
{
    __shared__ int csum[256];
    __shared__ int coff[256];
    const int t = threadIdx.x;
    const int base = t * 7;
    int loc[7]; int s = 0;
    #pragma unroll
    for (int i = 0; i < 7; ++i) {
        int g = base + i;
        int v = (g < TBM) ? valid[g] : 0;
        loc[i] = v; s += v;
    }
    csum[t] = s;
    __syncthreads();
    if (t == 0) {
        int a = 0;
        for (int i = 0; i < 256; ++i) { coff[i] = a; a += csum[i]; }
        *tcp = a;
    }
    __syncthreads();
    int off = coff[t];
    #pragma unroll
    for (int i = 0; i < 7; ++i) {
        int g = base + i;
        if (g < TBM && loc[i]) cidx[off++] = g;
    }
}

__global__ __launch_bounds__(128) void k_compact(
    const float* __restrict__ nodes, const int* __restrict__ cidx,
    const int* __restrict__ tcp, float* __restrict__ x)
{
    const int j = blockIdx.x, b = blockIdx.y;
    const int Tc = *tcp;
    float* dst = x + ((size_t)b * TBM + j) * EMBD;
    if (j >= Tc) {
        for (int e = threadIdx.x; e < EMBD; e += 128) dst[e] = 0.f;
        return;
    }
    const float* src = nodes + ((size_t)b * TBM + cidx[j]) * EMBD;
    for (int e = threadIdx.x; e < EMBD; e += 128) dst[e] = src[e];
}

// LayerNorm (in-place safe)
__global__ __launch_bounds__(128) void k_ln(
    const float* y, const float* __restrict__ sc,
    const float* __restrict__ bc, float* outp)
{
    const int row = blockIdx.x;
    const int t = threadIdx.x;
    const float* yr = y + (size_t)row * EMBD;
    float x0 = yr[t], x1 = yr[t + 128];
    float x2 = (t < 104) ? yr[t + 256] : 0.0f;
    float sum = x0 + x1 + x2;
    __shared__ float red[2];
    #pragma unroll
    for (int o = 32; o >= 1; o >>= 1) sum += __shfl_xor(sum, o);
    if ((t & 63) == 0) red[t >> 6] = sum;
    __syncthreads();
    float mean = (red[0] + red[1]) * (1.0f / 360.0f);
    float d0 = x0 - mean, d1 = x1 - mean, d2 = (t < 104) ? (x2 - mean) : 0.0f;
    float vs = d0 * d0 + d1 * d1 + d2 * d2;
    __syncthreads();
    #pragma unroll
    for (int o = 32; o >= 1; o >>= 1) vs += __shfl_xor(vs, o);
    if ((t & 63) == 0) red[t >> 6] = vs;
    __syncthreads();
    float var = (red[0] + red[1]) * (1.0f / 360.0f);
    float rs = rsqrtf(var + 1e-5f);
    float* orow = outp + (size_t)row * EMBD;
    orow[t]       = d0 * rs * sc[t]       + bc[t];
    orow[t + 128] = d1 * rs * sc[t + 128] + bc[t + 128];
    if (t < 104) orow[t + 256] = d2 * rs * sc[t + 256] + bc[t + 256];
}

__global__ __launch_bounds__(256) void k_mean(
    const float* __restrict__ x, float* __restrict__ h,
    const int* __restrict__ tcp)
{
    const int e = blockIdx.x * 256 + threadIdx.x;
    const int b = blockIdx.y;
    if (e >= EMBD) return;
    int Tc = *tcp; if (Tc < 1) Tc = 1;
    const float* xp = x + (size_t)b * TBM * EMBD + e;
    float s0 = 0.f, s1 = 0.f, s2 = 0.f, s3 = 0.f;
    int j = 0;
    for (; j + 4 <= Tc; j += 4) {
        s0 += xp[(size_t)(j + 0) * EMBD]; s1 += xp[(size_t)(j + 1) * EMBD];
        s2 += xp[(size_t)(j + 2) * EMBD]; s3 += xp[(size_t)(j + 3) * EMBD];
    }
    for (; j < Tc; ++j) s0 += xp[(size_t)j * EMBD];
    h[b * EMBD + e] = (s0 + s1 + s2 + s3) / (float)Tc;
}

__global__ __launch_bounds__(256) void k_head(
    const float* __restrict__ h,
    const float* __restrict__ cw1, const float* __restrict__ cb1,
    const float* __restrict__ cw2, const float* __restrict__ cb2,
    const float* __restrict__ cw3, const float* __restrict__ cb3,
    float* __restrict__ outp)
{
    __shared__ float hs[NB * EMBD];
    __shared__ float h1[NB * 256];
    __shared__ float h2[NB * 128];
    const int t = threadIdx.x;
    for (int i = t; i < NB * EMBD; i += 256) hs[i] = h[i];
    __syncthreads();
    for (int i = t; i < NB * 256; i += 256) {
        int b = i >> 8, o = i & 255;
        float s = cb1[o];
        for (int k = 0; k < EMBD; ++k) s = fmaf(hs[b * EMBD + k], cw1[k * 256 + o], s);
        h1[i] = gelu_f(s);
    }
    __syncthreads();
    for (int i = t; i < NB * 128; i += 256) {
        int b = i >> 7, o = i & 127;
        float s = cb2[o];
        for (int k = 0; k < 256; ++k) s = fmaf(h1[b * 256 + k], cw2[k * 128 + o], s);
        h2[i] = fmaxf(s, 0.0f);
    }
    __syncthreads();
    if (t < 16) {
        int b = t >> 1, o = t & 1;
        float s = cb3[o];
        for (int k = 0; k < 128; ++k) s = fmaf(h2[b * 128 + k], cw3[k * 2 + o], s);
        outp[t] = s;
    }
}

// ---------------------------------------------------------------------------
extern "C" void kernel_launch(void* const* d_in, const int* in_sizes, int n_in,
                              void* d_out, int out_size, void* d_ws, size_t ws_size,
                              hipStream_t stream)
{
    const float* F_roi  = (const float*)d_in[0];
    const int*   C      = (const int*)d_in[1];
    const float* ffn_w1 = (const float*)d_in[2];
    const float* ffn_b1 = (const float*)d_in[3];
    const float* ffn_w2 = (const float*)d_in[4];
    const float* ffn_b2 = (const float*)d_in[5];
    const float* wqkv   = (const float*)d_in[6];
    const float* bqkv   = (const float*)d_in[7];
    const float* wo     = (const float*)d_in[8];
    const float* bo     = (const float*)d_in[9];
    const float* ln1s   = (const float*)d_in[10];
    const float* ln1b   = (const float*)d_in[11];
    const float* wf1    = (const float*)d_in[12];
    const float* bf1    = (const float*)d_in[13];
    const float* wf2    = (const float*)d_in[14];
    const float* bf2    = (const float*)d_in[15];
    const float* ln2s   = (const float*)d_in[16];
    const float* ln2b   = (const float*)d_in[17];
    const float* cw1    = (const float*)d_in[18];
    const float* cb1    = (const float*)d_in[19];
    const float* cw2    = (const float*)d_in[20];
    const float* cb2    = (const float*)d_in[21];
    const float* cw3    = (const float*)d_in[22];
    const float* cb3    = (const float*)d_in[23];
    float* out = (float*)d_out;

    float* ws   = (float*)d_ws;
    float* big0 = ws;                        // 28,311,552 f (tmp450+F_emb / aob / midb)
    float* big1 = ws + 28311552;             // 14,929,920 f (nodes f32 / qkv f16)
    float* t360 = ws + 43241472;             //  4,976,640 f (x stream, in-place)
    _Float16* sw = (_Float16*)(ws + 48218112); // f16 weights

    size_t so = 0;
    auto salloc = [&](size_t n) { _Float16* p = sw + so; so += n; return p; };
    _Float16* w1c = salloc(262144);          // [512][512]
    _Float16* w2c = salloc(184320);          // [384][480]
    _Float16 *qkvc[2], *woc[2], *f1c[2], *f2c[2];
    for (int l = 0; l < 2; ++l) {
        qkvc[l] = salloc(442368);            // [1152][384]
        woc[l]  = salloc(147456);            // [384][384]
        f1c[l]  = salloc(786432);            // [2048][384]
        f2c[l]  = salloc(786432);            // [384][2048]
    }
    float* hb  = ws + 48218112 + 4771840;
    int* ints  = (int*)(hb + 2944);
    int* valid = ints, *cidx = ints + 1728, *tcp = ints + 3456;
    float* bqp = (float*)(ints + 3460);      // 2 x 1152 padded qkv bias

    float* tmp450 = big0;
    float* F_emb  = big0 + 1440000;
    float* nodes  = big1;
    float* aob    = big0;
    float* midb   = big0;
    _Float16* qkvh = (_Float16*)big1;        // [13824][1152] f16

    dim3 blk(256);

    // Weight conversions (once per launch)
    k_wconv<<<dim3(1024), blk, 0, stream>>>(ffn_w1, 512, 450, w1c, 512, 512);
    k_wconv<<<dim3(720),  blk, 0, stream>>>(ffn_w2, 450, 360, w2c, 480, 384);
    for (int l = 0; l < 2; ++l) {
        k_wconv_qkv<<<dim3(1728), blk, 0, stream>>>(wqkv + (size_t)l * 360 * 1080, qkvc[l]);
        k_bias_qkv<<<dim3(5), blk, 0, stream>>>(bqkv + l * 1080, bqp + l * 1152);
        k_wconv<<<dim3(576),  blk, 0, stream>>>(wo  + (size_t)l * 360 * 360,  360, 360,  woc[l], 384, 384);
        k_wconv<<<dim3(3072), blk, 0, stream>>>(wf1 + (size_t)l * 360 * 2048, 360, 2048, f1c[l], 384, 2048);
        k_wconv<<<dim3(3072), blk, 0, stream>>>(wf2 + (size_t)l * 2048 * 360, 2048, 360, f2c[l], 2048, 384);
    }

    // Node featurization
    k_mgemm<1, false, false><<<dim3(4, 25), blk, 0, stream>>>(F_roi, w1c, ffn_b1, nullptr, tmp450, 3200, 450, 512, 512);
    k_mgemm<0, false, false><<<dim3(3, 25), blk, 0, stream>>>(tmp450, w2c, ffn_b2, nullptr, F_emb, 3200, 360, 450, 480);
    k_pool<<<dim3(1728, 8), dim3(128), 0, stream>>>(F_emb, C, nodes);
    k_mask<<<dim3(1728), blk, 0, stream>>>(nodes, valid);
    k_scan<<<dim3(1), blk, 0, stream>>>(valid, cidx, tcp);
    k_compact<<<dim3(1728, 8), dim3(128), 0, stream>>>(nodes, cidx, tcp, t360);

    // Transformer layers
    for (int l = 0; l < 2; ++l) {
        k_mgemm<0, false, true><<<dim3(9, 108), blk, 0, stream>>>(t360, qkvc[l], bqp + l * 1152, nullptr, qkvh, 13824, 1152, 360, 384);
        k_mattn<<<dim3(448), blk, 0, stream>>>(qkvh, aob, tcp);
        k_mgemm<0, true, false><<<dim3(3, 108), blk, 0, stream>>>(aob, woc[l], bo + l * 360, t360, t360, 13824, 360, 360, 384);
        k_ln<<<dim3(13824), dim3(128), 0, stream>>>(t360, ln1s + l * 360, ln1b + l * 360, t360);
        k_mgemm<1, false, false><<<dim3(16, 108), blk, 0, stream>>>(t360, f1c[l], bf1 + l * 2048, nullptr, midb, 13824, 2048, 360, 384);
        k_mgemm<0, true, false><<<dim3(3, 108), blk, 0, stream>>>(midb, f2c[l], bf2 + l * 360, t360, t360, 13824, 360, 2048, 2048);
        k_ln<<<dim3(13824), dim3(128), 0, stream>>>(t360, ln2s + l * 360, ln2b + l * 360, t360);
    }

    // Head
    k_mean<<<dim3(2, 8), blk, 0, stream>>>(t360, hb, tcp);
    k_head<<<dim3(1), blk, 0, stream>>>(hb, cw1, cb1, cw2, cb2, cw3, cb3, out);
}

// Round 5
// 915.948 us; speedup vs baseline: 5.4704x; 1.4836x over previous
//
#include <hip/hip_runtime.h>
#include <math.h>

#define NB   8
#define NROI 400
#define GG   25
#define EMBD 360
#define HDD  90
#define TBM  1728
#define MTOK 13824      // NB*TBM

typedef __attribute__((ext_vector_type(8)))  _Float16 h8;   // 8 f16 (4 VGPR)
typedef __attribute__((ext_vector_type(4)))  _Float16 h4;
typedef __attribute__((ext_vector_type(16))) float f32x16;

#define MFMA16(a,b,c) __builtin_amdgcn_mfma_f32_32x32x16_f16(a,b,c,0,0,0)
#define QSCALE 0.105409255338945984f   /* 1/sqrt(90) */

__device__ __forceinline__ float gelu_f(float x) {
    return 0.5f * x * (1.0f + erff(x * 0.7071067811865475f));
}

// ---------------------------------------------------------------------------
// Tiled weight convert+transpose: W[K][N] fp32 -> Wt[Np][Kp] f16 (zero-pad).
// ---------------------------------------------------------------------------
__global__ __launch_bounds__(256) void k_wconv(
    const float* __restrict__ W, int K, int N,
    _Float16* __restrict__ Wt, int Kp, int Np)
{
    __shared__ float tile[32][33];
    const int k0 = blockIdx.x * 32, n0 = blockIdx.y * 32;
    const int t = threadIdx.x;
    #pragma unroll
    for (int it = 0; it < 4; ++it) {
        int e = t + it * 256;
        int i = e >> 5, j = e & 31;
        tile[j][i] = (k0 + i < K && n0 + j < N) ? W[(size_t)(k0 + i) * N + n0 + j] : 0.0f;
    }
    __syncthreads();
    #pragma unroll
    for (int it = 0; it < 4; ++it) {
        int e = t + it * 256;
        int n = e >> 5, kk = e & 31;
        if (n0 + n < Np && k0 + kk < Kp)
            Wt[(size_t)(n0 + n) * Kp + k0 + kk] = (_Float16)tile[n][kk];
    }
}

// qkv weight: W[360][1080] -> Wt[1152][384], col map n' = sec*384+96h+d,
// Q section scaled by 1/sqrt(90), pads zero.
__global__ __launch_bounds__(256) void k_wconv_qkv(
    const float* __restrict__ W, _Float16* __restrict__ Wt)
{
    int id = blockIdx.x * 256 + threadIdx.x;
    if (id >= 1152 * 384) return;
    int np = id / 384, kk = id - np * 384;
    int sec = np / 384, r = np - sec * 384, h = r / 96, d = r - h * 96;
    float v = 0.0f;
    if (d < HDD && kk < 360) v = W[(size_t)kk * 1080 + sec * 360 + h * HDD + d];
    if (sec == 0) v *= QSCALE;
    Wt[id] = (_Float16)v;
}

// wo weight: W[360][360] -> Wt[384][384] with k' = 96h+d (matches the PADDED
// attention-output layout); Wt[n'][k'] = W[90h+d][n'], pads zero.
__global__ __launch_bounds__(256) void k_wconv_wo(
    const float* __restrict__ W, _Float16* __restrict__ Wt)
{
    int id = blockIdx.x * 256 + threadIdx.x;
    if (id >= 384 * 384) return;
    int n = id / 384, kp = id - n * 384;
    int h = kp / 96, d = kp - h * 96;
    float v = 0.0f;
    if (d < HDD && n < 360) v = W[(size_t)(h * HDD + d) * 360 + n];
    Wt[id] = (_Float16)v;
}

// padded qkv bias [1152]: Q scaled, V-pad d==90 -> 1.0 (softmax denom column)
__global__ __launch_bounds__(256) void k_bias_qkv(
    const float* __restrict__ bq, float* __restrict__ bp)
{
    int id = blockIdx.x * 256 + threadIdx.x;
    if (id >= 1152) return;
    int sec = id / 384, r = id - sec * 384, h = r / 96, d = r - h * 96;
    float v = 0.0f;
    if (d < HDD) v = bq[sec * 360 + h * HDD + d];
    if (sec == 0) v *= QSCALE;
    if (sec == 2 && d == HDD) v = 1.0f;
    bp[id] = v;
}

// ---------------------------------------------------------------------------
// MFMA GEMM (f16): C = act(A@B + bias (+res)). 128x128 tile, BK=32, 4 waves.
// AH: A is f16 [M][Kp] (pre-padded); else fp32 [M][K]. OUTH: write f16.
// ---------------------------------------------------------------------------
template <int ACT, bool RES, bool OUTH, bool AH>
__global__ __launch_bounds__(256, 2) void k_mgemm(
    const void* __restrict__ Ap, const _Float16* __restrict__ Bt,
    const float* __restrict__ bias, const float* res, void* Cp,
    int M, int N, int K, int Kp)
{
    __shared__ __align__(16) _Float16 Ah[4096], Bh[4096];
    const int t = threadIdx.x;
    const int lane = t & 63, wid = t >> 6;
    const int half = lane >> 5, l31 = lane & 31;
    const int m0 = blockIdx.y * 128, n0 = blockIdx.x * 128;
    const int wm = (wid >> 1) * 64, wn = (wid & 1) * 64;

    f32x16 acc00 = {}, acc01 = {}, acc10 = {}, acc11 = {};
    const int nk = Kp >> 5;
    const bool k4 = (K & 3) == 0;

    for (int ks = 0; ks < nk; ++ks) {
        const int k0 = ks << 5;
        __syncthreads();
        if (AH) {
            const _Float16* Af = (const _Float16*)Ap;
            #pragma unroll
            for (int i = 0; i < 2; ++i) {
                int e = t + i * 256;
                int row = e >> 2, c = e & 3;
                int gm = m0 + row; if (gm > M - 1) gm = M - 1;
                *(h8*)&Ah[(c * 128 + row) * 8] =
                    *(const h8*)(Af + (size_t)gm * Kp + k0 + c * 8);
            }
        } else {
            const float* A = (const float*)Ap;
            #pragma unroll
            for (int i = 0; i < 4; ++i) {
                int e = t + i * 256;
                int row = e >> 3, c4 = e & 7;
                int gm = m0 + row, kb = k0 + c4 * 4;
                float v0 = 0.f, v1 = 0.f, v2 = 0.f, v3 = 0.f;
                if (gm < M) {
                    const float* ap = A + (size_t)gm * K + kb;
                    if (k4 && kb + 3 < K) {
                        float4 fv = *(const float4*)ap;
                        v0 = fv.x; v1 = fv.y; v2 = fv.z; v3 = fv.w;
                    } else {
                        if (kb + 0 < K) v0 = ap[0];
                        if (kb + 1 < K) v1 = ap[1];
                        if (kb + 2 < K) v2 = ap[2];
                        if (kb + 3 < K) v3 = ap[3];
                    }
                }
                h4 hv = { (_Float16)v0, (_Float16)v1, (_Float16)v2, (_Float16)v3 };
                int c = c4 >> 1, sub = c4 & 1;
                *(h4*)&Ah[(c * 128 + row) * 8 + sub * 4] = hv;
            }
        }
        #pragma unroll
        for (int i = 0; i < 2; ++i) {
            int e = t + i * 256;
            int col = e >> 2, c = e & 3;
            *(h8*)&Bh[(c * 128 + col) * 8] =
                *(const h8*)(Bt + (size_t)(n0 + col) * Kp + k0 + c * 8);
        }
        __syncthreads();
        h8 af[2][2], bf[2][2];
        #pragma unroll
        for (int m2 = 0; m2 < 2; ++m2)
            #pragma unroll
            for (int ku = 0; ku < 2; ++ku) {
                int c = ku * 2 + half;
                af[m2][ku] = *(const h8*)&Ah[(c * 128 + wm + m2 * 32 + l31) * 8];
                bf[m2][ku] = *(const h8*)&Bh[(c * 128 + wn + m2 * 32 + l31) * 8];
            }
        #pragma unroll
        for (int ku = 0; ku < 2; ++ku) {
            acc00 = MFMA16(af[0][ku], bf[0][ku], acc00);
            acc01 = MFMA16(af[0][ku], bf[1][ku], acc01);
            acc10 = MFMA16(af[1][ku], bf[0][ku], acc10);
            acc11 = MFMA16(af[1][ku], bf[1][ku], acc11);
        }
    }
    float* Cf = (float*)Cp;
    _Float16* Ch = (_Float16*)Cp;
    #define EPILOG(ACCV, M2, N2) { \
        int gn = n0 + wn + (N2) * 32 + l31; \
        if (gn < N) { \
            float bv = bias[gn]; \
            _Pragma("unroll") \
            for (int r = 0; r < 16; ++r) { \
                int gm = m0 + wm + (M2) * 32 + (r & 3) + 8 * (r >> 2) + 4 * half; \
                if (gm < M) { \
                    float v = ACCV[r] + bv; \
                    if (RES) v += res[(size_t)gm * N + gn]; \
                    if (ACT == 1) v = gelu_f(v); \
                    if (OUTH) Ch[(size_t)gm * N + gn] = (_Float16)v; \
                    else      Cf[(size_t)gm * N + gn] = v; \
                } } } }
    EPILOG(acc00, 0, 0) EPILOG(acc01, 0, 1) EPILOG(acc10, 1, 0) EPILOG(acc11, 1, 1)
    #undef EPILOG
}

// ---------------------------------------------------------------------------
// Split-K GEMM for wf2: A f16 [13824][2048], B f16 [384][2048],
// partial[z] fp32 [13824][360], z = blockIdx.z in {0,1}, K-chunk 1024.
// ---------------------------------------------------------------------------
__global__ __launch_bounds__(256, 2) void k_skgemm(
    const _Float16* __restrict__ A, const _Float16* __restrict__ Bt,
    float* __restrict__ P)
{
    __shared__ __align__(16) _Float16 Ah[4096], Bh[4096];
    const int t = threadIdx.x;
    const int lane = t & 63, wid = t >> 6;
    const int half = lane >> 5, l31 = lane & 31;
    const int m0 = blockIdx.y * 128, n0 = blockIdx.x * 128;
    const int wm = (wid >> 1) * 64, wn = (wid & 1) * 64;
    const int zb = blockIdx.z * 1024;
    P += (size_t)blockIdx.z * MTOK * EMBD;

    f32x16 acc00 = {}, acc01 = {}, acc10 = {}, acc11 = {};
    for (int ks = 0; ks < 32; ++ks) {
        const int k0 = zb + (ks << 5);
        __syncthreads();
        #pragma unroll
        for (int i = 0; i < 2; ++i) {
            int e = t + i * 256;
            int row = e >> 2, c = e & 3;
            *(h8*)&Ah[(c * 128 + row) * 8] =
                *(const h8*)(A + (size_t)(m0 + row) * 2048 + k0 + c * 8);
        }
        #pragma unroll
        for (int i = 0; i < 2; ++i) {
            int e = t + i * 256;
            int col = e >> 2, c = e & 3;
            *(h8*)&Bh[(c * 128 + col) * 8] =
                *(const h8*)(Bt + (size_t)(n0 + col) * 2048 + k0 + c * 8);
        }
        __syncthreads();
        h8 af[2][2], bf[2][2];
        #pragma unroll
        for (int m2 = 0; m2 < 2; ++m2)
            #pragma unroll
            for (int ku = 0; ku < 2; ++ku) {
                int c = ku * 2 + half;
                af[m2][ku] = *(const h8*)&Ah[(c * 128 + wm + m2 * 32 + l31) * 8];
                bf[m2][ku] = *(const h8*)&Bh[(c * 128 + wn + m2 * 32 + l31) * 8];
            }
        #pragma unroll
        for (int ku = 0; ku < 2; ++ku) {
            acc00 = MFMA16(af[0][ku], bf[0][ku], acc00);
            acc01 = MFMA16(af[0][ku], bf[1][ku], acc01);
            acc10 = MFMA16(af[1][ku], bf[0][ku], acc10);
            acc11 = MFMA16(af[1][ku], bf[1][ku], acc11);
        }
    }
    #define EPILOGP(ACCV, M2, N2) { \
        int gn = n0 + wn + (N2) * 32 + l31; \
        if (gn < EMBD) { \
            _Pragma("unroll") \
            for (int r = 0; r < 16; ++r) { \
                int gm = m0 + wm + (M2) * 32 + (r & 3) + 8 * (r >> 2) + 4 * half; \
                P[(size_t)gm * EMBD + gn] = ACCV[r]; \
            } } }
    EPILOGP(acc00, 0, 0) EPILOGP(acc01, 0, 1) EPILOGP(acc10, 1, 0) EPILOGP(acc11, 1, 1)
    #undef EPILOGP
}

// ---------------------------------------------------------------------------
// Flash attention, f16 MFMA. qkv f16 [13824][1152]: sec*384 + 96h + d;
// Q pre-scaled; V has 1.0 at d==90 (denominator). Writes aob f16 [13824][384]
// in the PADDED layout col = 96h + d (wo weights permuted to match).
// ---------------------------------------------------------------------------
__global__ __launch_bounds__(256, 2) void k_mattn(
    const _Float16* __restrict__ qkv, _Float16* __restrict__ aob,
    const int* __restrict__ tcp)
{
    __shared__ __align__(16) _Float16 Kl[64 * 128];
    __shared__ __align__(16) _Float16 Vl[64 * 128];
    __shared__ __align__(16) _Float16 Pl[4][32 * 64];

    const int t = threadIdx.x;
    const int lane = t & 63, wid = t >> 6;
    const int half = lane >> 5, l31 = lane & 31;
    const int bid = blockIdx.x;
    const int bh = bid & 31, qt = bid >> 5;
    const int h = bh & 3, b = bh >> 2;
    const int Tc = *tcp;
    const int q0w = qt * 128 + wid * 32;
    const size_t base = (size_t)b * TBM * 1152;

    h8 qf[6];
    {
        int rl = q0w + l31; if (rl > TBM - 1) rl = TBM - 1;
        const _Float16* qrow = qkv + base + (size_t)rl * 1152 + 96 * h;
        #pragma unroll
        for (int ku = 0; ku < 6; ++ku)
            qf[ku] = *(const h8*)(qrow + ku * 16 + half * 8);
    }

    f32x16 o0 = {}, o1 = {}, o2 = {};
    int nkt = (Tc + 63) >> 6; if (nkt > 27) nkt = 27;

    for (int kt = 0; kt < nkt; ++kt) {
        const int k0 = kt * 64;
        __syncthreads();
        #pragma unroll
        for (int i = 0; i < 3; ++i) {
            int cid = t + i * 256;
            int kk = cid / 12, c = cid - kk * 12;
            int cp = c ^ (kk & 7);
            const _Float16* src = qkv + base + (size_t)(k0 + kk) * 1152 + 96 * h;
            *(h8*)&Kl[kk * 128 + cp * 8] = *(const h8*)(src + 384 + c * 8);
            *(h8*)&Vl[kk * 128 + cp * 8] = *(const h8*)(src + 768 + c * 8);
        }
        __syncthreads();
        f32x16 s0 = {}, s1 = {};
        #pragma unroll
        for (int ku = 0; ku < 6; ++ku) {
            int c = ku * 2 + half;
            int cp = c ^ (l31 & 7);
            h8 kb0 = *(const h8*)&Kl[l31 * 128 + cp * 8];
            h8 kb1 = *(const h8*)&Kl[(32 + l31) * 128 + cp * 8];
            s0 = MFMA16(qf[ku], kb0, s0);
            s1 = MFMA16(qf[ku], kb1, s1);
        }
        const bool ok0 = (k0 + l31) < Tc;
        const bool ok1 = (k0 + 32 + l31) < Tc;
        const int c0 = l31 >> 3, c1 = 4 + (l31 >> 3), j0 = l31 & 7;
        #pragma unroll
        for (int r = 0; r < 16; ++r) {
            int ql = (r & 3) + 8 * (r >> 2) + 4 * half;
            float p0 = ok0 ? __expf(s0[r]) : 0.0f;
            float p1 = ok1 ? __expf(s1[r]) : 0.0f;
            Pl[wid][ql * 64 + (c0 ^ (ql & 7)) * 8 + j0] = (_Float16)p0;
            Pl[wid][ql * 64 + (c1 ^ (ql & 7)) * 8 + j0] = (_Float16)p1;
        }
        asm volatile("s_waitcnt lgkmcnt(0)" ::: "memory");
        __builtin_amdgcn_sched_barrier(0);
        h8 pa[4];
        #pragma unroll
        for (int ku = 0; ku < 4; ++ku) {
            int c = ku * 2 + half;
            pa[ku] = *(const h8*)&Pl[wid][l31 * 64 + (c ^ (l31 & 7)) * 8];
        }
        #pragma unroll
        for (int n = 0; n < 3; ++n) {
            f32x16* op = n == 0 ? &o0 : (n == 1 ? &o1 : &o2);
            int d = n * 32 + l31;
            int cd = d >> 3, jd = d & 7;
            #pragma unroll
            for (int ku = 0; ku < 4; ++ku) {
                h8 vb;
                #pragma unroll
                for (int j = 0; j < 8; ++j) {
                    int kk = ku * 16 + half * 8 + j;
                    vb[j] = Vl[kk * 128 + (cd ^ (kk & 7)) * 8 + jd];
                }
                *op = MFMA16(pa[ku], vb, *op);
            }
        }
        __syncthreads();
    }

    #pragma unroll
    for (int r = 0; r < 16; ++r) {
        float den = __shfl(o2[r], (lane & 32) | 26);
        float inv = (den > 0.0f) ? 1.0f / den : 0.0f;
        int qg = q0w + (r & 3) + 8 * (r >> 2) + 4 * half;
        if (qg < Tc) {
            _Float16* orow = aob + ((size_t)b * TBM + qg) * 384 + 96 * h;
            orow[l31]      = (_Float16)(o0[r] * inv);
            orow[32 + l31] = (_Float16)(o1[r] * inv);
            orow[64 + l31] = (64 + l31 < HDD) ? (_Float16)(o2[r] * inv) : (_Float16)0.0f;
        }
    }
}

// ---------------------------------------------------------------------------
__global__ __launch_bounds__(128) void k_pool(
    const float* __restrict__ F_emb, const int* __restrict__ C,
    float* __restrict__ nodes)
{
    const int tkn = blockIdx.x, b = blockIdx.y;
    const int oz = tkn % 12, oy = (tkn / 12) % 12, ox = tkn / 144;
    __shared__ int idx[27];
    const int tid = threadIdx.x;
    if (tid < 27) {
        int dx = tid / 9, dy = (tid / 3) % 3, dz = tid % 3;
        idx[tid] = C[(((b * GG) + ox * 2 + dx) * GG + oy * 2 + dy) * GG + oz * 2 + dz];
    }
    __syncthreads();
    float a0 = 0.f, a1 = 0.f, a2 = 0.f;
    for (int n = 0; n < 27; ++n) {
        int c = idx[n];
        if (c == 0) continue;
        const float* src = F_emb + (size_t)(b * NROI + (c - 1)) * EMBD;
        a0 += src[tid]; a1 += src[tid + 128];
        if (tid < 104) a2 += src[tid + 256];
    }
    float* dst = nodes + ((size_t)b * TBM + tkn) * EMBD;
    dst[tid] = a0; dst[tid + 128] = a1;
    if (tid < 104) dst[tid + 256] = a2;
}

__global__ __launch_bounds__(256) void k_mask(
    const float* __restrict__ nodes, int* __restrict__ valid)
{
    const int tkn = blockIdx.x;
    float s = 0.f;
    for (int i = threadIdx.x; i < NB * EMBD; i += 256) {
        int b = i / EMBD, e = i - b * EMBD;
        s += fabsf(nodes[((size_t)b * TBM + tkn) * EMBD + e]);
    }
    #pragma unroll
    for (int o = 32; o >= 1; o >>= 1) s += __shfl_xor(s, o);
    __shared__ float red[4];
    if ((threadIdx.x & 63) == 0) red[threadIdx.x >> 6] = s;
    __syncthreads();
    if (threadIdx.x == 0)
        valid[tkn] = ((red[0] + red[1] + red[2] + red[3]) > 0.f) ? 1 : 0;
}

__global__ __launch_bounds__(256) void k_scan(
    const int* __restrict__ valid, int* __restrict__ cidx, int* __restrict__ tcp)
{
    __shared__ int csum[256];
    __shared__ int coff[256];
    const int t = threadIdx.x;
    const int base = t * 7;
    int loc[7]; int s = 0;
    #pragma unroll
    for (int i = 0; i < 7; ++i) {
        int g = base + i;
        int v = (g < TBM) ? valid[g] : 0;
        loc[i] = v; s += v;
    }
    csum[t] = s;
    __syncthreads();
    if (t == 0) {
        int a = 0;
        for (int i = 0; i < 256; ++i) { coff[i] = a; a += csum[i]; }
        *tcp = a;
    }
    __syncthreads();
    int off = coff[t];
    #pragma unroll
    for (int i = 0; i < 7; ++i) {
        int g = base + i;
        if (g < TBM && loc[i]) cidx[off++] = g;
    }
}

// compact -> t360 fp32 [.][360] and xh f16 [.][384] (pads zero)
__global__ __launch_bounds__(128) void k_compact(
    const float* __restrict__ nodes, const int* __restrict__ cidx,
    const int* __restrict__ tcp, float* __restrict__ xf, _Float16* __restrict__ xh)
{
    const int j = blockIdx.x, b = blockIdx.y;
    const int Tc = *tcp;
    const size_t row = (size_t)b * TBM + j;
    const float* src = (j < Tc) ? nodes + ((size_t)b * TBM + cidx[j]) * EMBD : nullptr;
    for (int e = threadIdx.x; e < 384; e += 128) {
        float v = (e < EMBD && src) ? src[e] : 0.0f;
        if (e < EMBD) xf[row * EMBD + e] = v;
        xh[row * 384 + e] = (_Float16)v;
    }
}

// LayerNorm: y fp32[.][360] -> outf fp32 + outh f16 [.][384] (pads zero)
__global__ __launch_bounds__(128) void k_ln(
    const float* y, const float* __restrict__ sc,
    const float* __restrict__ bc, float* outf, _Float16* __restrict__ outh)
{
    const int row = blockIdx.x;
    const int t = threadIdx.x;
    const float* yr = y + (size_t)row * EMBD;
    float x0 = yr[t], x1 = yr[t + 128];
    float x2 = (t < 104) ? yr[t + 256] : 0.0f;
    float sum = x0 + x1 + x2;
    __shared__ float red[2];
    #pragma unroll
    for (int o = 32; o >= 1; o >>= 1) sum += __shfl_xor(sum, o);
    if ((t & 63) == 0) red[t >> 6] = sum;
    __syncthreads();
    float mean = (red[0] + red[1]) * (1.0f / 360.0f);
    float d0 = x0 - mean, d1 = x1 - mean, d2 = (t < 104) ? (x2 - mean) : 0.0f;
    float vs = d0 * d0 + d1 * d1 + d2 * d2;
    __syncthreads();
    #pragma unroll
    for (int o = 32; o >= 1; o >>= 1) vs += __shfl_xor(vs, o);
    if ((t & 63) == 0) red[t >> 6] = vs;
    __syncthreads();
    float var = (red[0] + red[1]) * (1.0f / 360.0f);
    float rs = rsqrtf(var + 1e-5f);
    float* orow = outf + (size_t)row * EMBD;
    _Float16* hrow = outh + (size_t)row * 384;
    float v0 = d0 * rs * sc[t] + bc[t];
    float v1 = d1 * rs * sc[t + 128] + bc[t + 128];
    orow[t] = v0;       hrow[t] = (_Float16)v0;
    orow[t + 128] = v1; hrow[t + 128] = (_Float16)v1;
    if (t < 104) {
        float v2 = d2 * rs * sc[t + 256] + bc[t + 256];
        orow[t + 256] = v2; hrow[t + 256] = (_Float16)v2;
    } else {
        hrow[t + 256] = (_Float16)0.0f;   // cols 360..383
    }
}

// Split-K reduce + bias + residual + LayerNorm
__global__ __launch_bounds__(128) void k_ln2(
    const float* __restrict__ p0, const float* __restrict__ p1,
    const float* __restrict__ bias, const float* res,
    const float* __restrict__ sc, const float* __restrict__ bc,
    float* outf, _Float16* __restrict__ outh)
{
    const int row = blockIdx.x;
    const int t = threadIdx.x;
    const size_t ro = (size_t)row * EMBD;
    float x0 = p0[ro + t]       + p1[ro + t]       + bias[t]       + res[ro + t];
    float x1 = p0[ro + t + 128] + p1[ro + t + 128] + bias[t + 128] + res[ro + t + 128];
    float x2 = (t < 104) ? (p0[ro + t + 256] + p1[ro + t + 256] + bias[t + 256] + res[ro + t + 256]) : 0.0f;
    float sum = x0 + x1 + x2;
    __shared__ float red[2];
    #pragma unroll
    for (int o = 32; o >= 1; o >>= 1) sum += __shfl_xor(sum, o);
    if ((t & 63) == 0) red[t >> 6] = sum;
    __syncthreads();
    float mean = (red[0] + red[1]) * (1.0f / 360.0f);
    float d0 = x0 - mean, d1 = x1 - mean, d2 = (t < 104) ? (x2 - mean) : 0.0f;
    float vs = d0 * d0 + d1 * d1 + d2 * d2;
    __syncthreads();
    #pragma unroll
    for (int o = 32; o >= 1; o >>= 1) vs += __shfl_xor(vs, o);
    if ((t & 63) == 0) red[t >> 6] = vs;
    __syncthreads();
    float var = (red[0] + red[1]) * (1.0f / 360.0f);
    float rs = rsqrtf(var + 1e-5f);
    float* orow = outf + ro;
    _Float16* hrow = outh + (size_t)row * 384;
    float v0 = d0 * rs * sc[t] + bc[t];
    float v1 = d1 * rs * sc[t + 128] + bc[t + 128];
    orow[t] = v0;       hrow[t] = (_Float16)v0;
    orow[t + 128] = v1; hrow[t + 128] = (_Float16)v1;
    if (t < 104) {
        float v2 = d2 * rs * sc[t + 256] + bc[t + 256];
        orow[t + 256] = v2; hrow[t + 256] = (_Float16)v2;
    } else {
        hrow[t + 256] = (_Float16)0.0f;
    }
}

__global__ __launch_bounds__(256) void k_mean(
    const float* __restrict__ x, float* __restrict__ h,
    const int* __restrict__ tcp)
{
    const int e = blockIdx.x * 256 + threadIdx.x;
    const int b = blockIdx.y;
    if (e >= EMBD) return;
    int Tc = *tcp; if (Tc < 1) Tc = 1;
    const float* xp = x + (size_t)b * TBM * EMBD + e;
    float s0 = 0.f, s1 = 0.f, s2 = 0.f, s3 = 0.f;
    int j = 0;
    for (; j + 4 <= Tc; j += 4) {
        s0 += xp[(size_t)(j + 0) * EMBD]; s1 += xp[(size_t)(j + 1) * EMBD];
        s2 += xp[(size_t)(j + 2) * EMBD]; s3 += xp[(size_t)(j + 3) * EMBD];
    }
    for (; j < Tc; ++j) s0 += xp[(size_t)j * EMBD];
    h[b * EMBD + e] = (s0 + s1 + s2 + s3) / (float)Tc;
}

__global__ __launch_bounds__(256) void k_head(
    const float* __restrict__ h,
    const float* __restrict__ cw1, const float* __restrict__ cb1,
    const float* __restrict__ cw2, const float* __restrict__ cb2,
    const float* __restrict__ cw3, const float* __restrict__ cb3,
    float* __restrict__ outp)
{
    __shared__ float hs[NB * EMBD];
    __shared__ float h1[NB * 256];
    __shared__ float h2[NB * 128];
    const int t = threadIdx.x;
    for (int i = t; i < NB * EMBD; i += 256) hs[i] = h[i];
    __syncthreads();
    for (int i = t; i < NB * 256; i += 256) {
        int b = i >> 8, o = i & 255;
        float s = cb1[o];
        for (int k = 0; k < EMBD; ++k) s = fmaf(hs[b * EMBD + k], cw1[k * 256 + o], s);
        h1[i] = gelu_f(s);
    }
    __syncthreads();
    for (int i = t; i < NB * 128; i += 256) {
        int b = i >> 7, o = i & 127;
        float s = cb2[o];
        for (int k = 0; k < 256; ++k) s = fmaf(h1[b * 256 + k], cw2[k * 128 + o], s);
        h2[i] = fmaxf(s, 0.0f);
    }
    __syncthreads();
    if (t < 16) {
        int b = t >> 1, o = t & 1;
        float s = cb3[o];
        for (int k = 0; k < 128; ++k) s = fmaf(h2[b * 128 + k], cw3[k * 2 + o], s);
        outp[t] = s;
    }
}

// ---------------------------------------------------------------------------
extern "C" void kernel_launch(void* const* d_in, const int* in_sizes, int n_in,
                              void* d_out, int out_size, void* d_ws, size_t ws_size,
                              hipStream_t stream)
{
    const float* F_roi  = (const float*)d_in[0];
    const int*   C      = (const int*)d_in[1];
    const float* ffn_w1 = (const float*)d_in[2];
    const float* ffn_b1 = (const float*)d_in[3];
    const float* ffn_w2 = (const float*)d_in[4];
    const float* ffn_b2 = (const float*)d_in[5];
    const float* wqkv   = (const float*)d_in[6];
    const float* bqkv   = (const float*)d_in[7];
    const float* wo     = (const float*)d_in[8];
    const float* bo     = (const float*)d_in[9];
    const float* ln1s   = (const float*)d_in[10];
    const float* ln1b   = (const float*)d_in[11];
    const float* wf1    = (const float*)d_in[12];
    const float* bf1    = (const float*)d_in[13];
    const float* wf2    = (const float*)d_in[14];
    const float* bf2    = (const float*)d_in[15];
    const float* ln2s   = (const float*)d_in[16];
    const float* ln2b   = (const float*)d_in[17];
    const float* cw1    = (const float*)d_in[18];
    const float* cb1    = (const float*)d_in[19];
    const float* cw2    = (const float*)d_in[20];
    const float* cb2    = (const float*)d_in[21];
    const float* cw3    = (const float*)d_in[22];
    const float* cb3    = (const float*)d_in[23];
    float* out = (float*)d_out;

    float* ws = (float*)d_ws;
    // layout (float offsets)
    _Float16* qkvh = (_Float16*)ws;                   // [13824][1152] f16 (7,962,624 f)
    float*    tmp450 = ws;                            // alias (1,440,000 f)
    float*    F_emb  = ws + 1440000;                  // alias (1,152,000 f)
    float*    midf   = ws + 7962624;                  // midb f16 area (14,155,776 f)
    _Float16* midb   = (_Float16*)midf;               // [13824][2048] f16
    float*    nodes  = midf;                          // alias fp32 (4,976,640 f)
    _Float16* aob    = (_Float16*)(ws + 22118400);    // [13824][384] f16 (2,654,208 f)
    float*    p0     = ws + 24772608;                 // (4,976,640 f)
    float*    p1     = ws + 29749248;                 // (4,976,640 f)
    float*    t360   = ws + 34725888;                 // (4,976,640 f)
    _Float16* xh     = (_Float16*)(ws + 39702528);    // [13824][384] f16 (2,654,208 f)
    _Float16* sw     = (_Float16*)(ws + 42356736);    // weights (2,385,920 f as shorts)

    size_t so = 0;
    auto salloc = [&](size_t n) { _Float16* p = sw + so; so += n; return p; };
    _Float16* w1c = salloc(262144);          // [512][512]
    _Float16* w2c = salloc(184320);          // [384][480]
    _Float16 *qkvc[2], *woc[2], *f1c[2], *f2c[2];
    for (int l = 0; l < 2; ++l) {
        qkvc[l] = salloc(442368);            // [1152][384]
        woc[l]  = salloc(147456);            // [384][384]
        f1c[l]  = salloc(786432);            // [2048][384]
        f2c[l]  = salloc(786432);            // [384][2048]
    }
    float* hb  = ws + 44742656;              // (2,944 f)
    int* ints  = (int*)(hb + 2944);
    int* valid = ints, *cidx = ints + 1728, *tcp = ints + 3456;
    float* bqp = (float*)(ints + 3460);      // 2 x 1152

    dim3 blk(256);

    // Weight conversions
    k_wconv<<<dim3(16, 16), blk, 0, stream>>>(ffn_w1, 512, 450, w1c, 512, 512);
    k_wconv<<<dim3(15, 12), blk, 0, stream>>>(ffn_w2, 450, 360, w2c, 480, 384);
    for (int l = 0; l < 2; ++l) {
        k_wconv_qkv<<<dim3(1728), blk, 0, stream>>>(wqkv + (size_t)l * 360 * 1080, qkvc[l]);
        k_bias_qkv<<<dim3(5), blk, 0, stream>>>(bqkv + l * 1080, bqp + l * 1152);
        k_wconv_wo<<<dim3(576), blk, 0, stream>>>(wo + (size_t)l * 360 * 360, woc[l]);
        k_wconv<<<dim3(12, 64), blk, 0, stream>>>(wf1 + (size_t)l * 360 * 2048, 360, 2048, f1c[l], 384, 2048);
        k_wconv<<<dim3(64, 12), blk, 0, stream>>>(wf2 + (size_t)l * 2048 * 360, 2048, 360, f2c[l], 2048, 384);
    }

    // Node featurization (fp32-A path)
    k_mgemm<1, false, false, false><<<dim3(4, 25), blk, 0, stream>>>(F_roi, w1c, ffn_b1, nullptr, tmp450, 3200, 450, 512, 512);
    k_mgemm<0, false, false, false><<<dim3(3, 25), blk, 0, stream>>>(tmp450, w2c, ffn_b2, nullptr, F_emb, 3200, 360, 450, 480);
    k_pool<<<dim3(1728, 8), dim3(128), 0, stream>>>(F_emb, C, nodes);
    k_mask<<<dim3(1728), blk, 0, stream>>>(nodes, valid);
    k_scan<<<dim3(1), blk, 0, stream>>>(valid, cidx, tcp);
    k_compact<<<dim3(1728, 8), dim3(128), 0, stream>>>(nodes, cidx, tcp, t360, xh);

    // Transformer layers
    for (int l = 0; l < 2; ++l) {
        k_mgemm<0, false, true, true><<<dim3(9, 108), blk, 0, stream>>>(xh, qkvc[l], bqp + l * 1152, nullptr, qkvh, MTOK, 1152, 360, 384);
        k_mattn<<<dim3(448), blk, 0, stream>>>(qkvh, aob, tcp);
        k_mgemm<0, true, false, true><<<dim3(3, 108), blk, 0, stream>>>(aob, woc[l], bo + l * 360, t360, t360, MTOK, 360, 384, 384);
        k_ln<<<dim3(MTOK), dim3(128), 0, stream>>>(t360, ln1s + l * 360, ln1b + l * 360, t360, xh);
        k_mgemm<1, false, true, true><<<dim3(16, 108), blk, 0, stream>>>(xh, f1c[l], bf1 + l * 2048, nullptr, midb, MTOK, 2048, 360, 384);
        k_skgemm<<<dim3(3, 108, 2), blk, 0, stream>>>(midb, f2c[l], p0);
        k_ln2<<<dim3(MTOK), dim3(128), 0, stream>>>(p0, p1, bf2 + l * 360, t360, ln2s + l * 360, ln2b + l * 360, t360, xh);
    }

    // Head
    k_mean<<<dim3(2, 8), blk, 0, stream>>>(t360, hb, tcp);
    k_head<<<dim3(1), blk, 0, stream>>>(hb, cw1, cb1, cw2, cb2, cw3, cb3, out);
}

// Round 6
// 819.266 us; speedup vs baseline: 6.1160x; 1.1180x over previous
//
#include <hip/hip_runtime.h>
#include <math.h>

#define NB   8
#define NROI 400
#define GG   25
#define EMBD 360
#define HDD  90
#define TBM  1728
#define MTOK 13824      // NB*TBM

typedef __attribute__((ext_vector_type(8)))  _Float16 h8;   // 8 f16 (4 VGPR)
typedef __attribute__((ext_vector_type(4)))  _Float16 h4;
typedef __attribute__((ext_vector_type(16))) float f32x16;

#define MFMA16(a,b,c) __builtin_amdgcn_mfma_f32_32x32x16_f16(a,b,c,0,0,0)
#define QSCALE 0.105409255338945984f   /* 1/sqrt(90) */

__device__ __forceinline__ float gelu_f(float x) {
    return 0.5f * x * (1.0f + erff(x * 0.7071067811865475f));
}

// ---------------------------------------------------------------------------
// Tiled weight convert+transpose: W[K][N] fp32 -> Wt[Np][Kp] f16 (zero-pad).
// blockIdx.z = layer (W += z*Wls, Wt += z*Wtls).
// ---------------------------------------------------------------------------
__global__ __launch_bounds__(256) void k_wconv(
    const float* __restrict__ W, int K, int N,
    _Float16* __restrict__ Wt, int Kp, int Np, int Wls, int Wtls)
{
    W  += (size_t)blockIdx.z * Wls;
    Wt += (size_t)blockIdx.z * Wtls;
    __shared__ float tile[32][33];
    const int k0 = blockIdx.x * 32, n0 = blockIdx.y * 32;
    const int t = threadIdx.x;
    #pragma unroll
    for (int it = 0; it < 4; ++it) {
        int e = t + it * 256;
        int i = e >> 5, j = e & 31;
        tile[j][i] = (k0 + i < K && n0 + j < N) ? W[(size_t)(k0 + i) * N + n0 + j] : 0.0f;
    }
    __syncthreads();
    #pragma unroll
    for (int it = 0; it < 4; ++it) {
        int e = t + it * 256;
        int n = e >> 5, kk = e & 31;
        if (n0 + n < Np && k0 + kk < Kp)
            Wt[(size_t)(n0 + n) * Kp + k0 + kk] = (_Float16)tile[n][kk];
    }
}

// qkv weight: W[360][1080] -> Wt[1152][384], col map n' = sec*384+96h+d,
// Q section scaled by 1/sqrt(90), pads zero. blockIdx.y = layer.
__global__ __launch_bounds__(256) void k_wconv_qkv(
    const float* __restrict__ W, _Float16* __restrict__ Wt)
{
    W  += (size_t)blockIdx.y * 360 * 1080;
    Wt += (size_t)blockIdx.y * 442368;
    int id = blockIdx.x * 256 + threadIdx.x;
    if (id >= 1152 * 384) return;
    int np = id / 384, kk = id - np * 384;
    int sec = np / 384, r = np - sec * 384, h = r / 96, d = r - h * 96;
    float v = 0.0f;
    if (d < HDD && kk < 360) v = W[(size_t)kk * 1080 + sec * 360 + h * HDD + d];
    if (sec == 0) v *= QSCALE;
    Wt[id] = (_Float16)v;
}

// wo weight: W[360][360] -> Wt[384][384] with k' = 96h+d (padded attn layout)
__global__ __launch_bounds__(256) void k_wconv_wo(
    const float* __restrict__ W, _Float16* __restrict__ Wt)
{
    W  += (size_t)blockIdx.y * 360 * 360;
    Wt += (size_t)blockIdx.y * 147456;
    int id = blockIdx.x * 256 + threadIdx.x;
    if (id >= 384 * 384) return;
    int n = id / 384, kp = id - n * 384;
    int h = kp / 96, d = kp - h * 96;
    float v = 0.0f;
    if (d < HDD && n < 360) v = W[(size_t)(h * HDD + d) * 360 + n];
    Wt[id] = (_Float16)v;
}

// padded qkv bias [1152]: Q scaled, V-pad d==90 -> 1.0 (softmax denom column)
__global__ __launch_bounds__(256) void k_bias_qkv(
    const float* __restrict__ bq, float* __restrict__ bp)
{
    bq += (size_t)blockIdx.y * 1080;
    bp += (size_t)blockIdx.y * 1152;
    int id = blockIdx.x * 256 + threadIdx.x;
    if (id >= 1152) return;
    int sec = id / 384, r = id - sec * 384, h = r / 96, d = r - h * 96;
    float v = 0.0f;
    if (d < HDD) v = bq[sec * 360 + h * HDD + d];
    if (sec == 0) v *= QSCALE;
    if (sec == 2 && d == HDD) v = 1.0f;
    bp[id] = v;
}

// ---------------------------------------------------------------------------
// MFMA GEMM (f16): C = act(A@B + bias (+res)). 128x128 tile, BK=32, 4 waves.
// AH: A is f16 [M][Kp] (pre-padded); else fp32 [M][K]. OUTH: write f16.
// ---------------------------------------------------------------------------
template <int ACT, bool RES, bool OUTH, bool AH>
__global__ __launch_bounds__(256, 2) void k_mgemm(
    const void* __restrict__ Ap, const _Float16* __restrict__ Bt,
    const float* __restrict__ bias, const float* res, void* Cp,
    int M, int N, int K, int Kp)
{
    __shared__ __align__(16) _Float16 Ah[4096], Bh[4096];
    const int t = threadIdx.x;
    const int lane = t & 63, wid = t >> 6;
    const int half = lane >> 5, l31 = lane & 31;
    const int m0 = blockIdx.y * 128, n0 = blockIdx.x * 128;
    const int wm = (wid >> 1) * 64, wn = (wid & 1) * 64;

    f32x16 acc00 = {}, acc01 = {}, acc10 = {}, acc11 = {};
    const int nk = Kp >> 5;
    const bool k4 = (K & 3) == 0;

    for (int ks = 0; ks < nk; ++ks) {
        const int k0 = ks << 5;
        __syncthreads();
        if (AH) {
            const _Float16* Af = (const _Float16*)Ap;
            #pragma unroll
            for (int i = 0; i < 2; ++i) {
                int e = t + i * 256;
                int row = e >> 2, c = e & 3;
                int gm = m0 + row; if (gm > M - 1) gm = M - 1;
                *(h8*)&Ah[(c * 128 + row) * 8] =
                    *(const h8*)(Af + (size_t)gm * Kp + k0 + c * 8);
            }
        } else {
            const float* A = (const float*)Ap;
            #pragma unroll
            for (int i = 0; i < 4; ++i) {
                int e = t + i * 256;
                int row = e >> 3, c4 = e & 7;
                int gm = m0 + row, kb = k0 + c4 * 4;
                float v0 = 0.f, v1 = 0.f, v2 = 0.f, v3 = 0.f;
                if (gm < M) {
                    const float* ap = A + (size_t)gm * K + kb;
                    if (k4 && kb + 3 < K) {
                        float4 fv = *(const float4*)ap;
                        v0 = fv.x; v1 = fv.y; v2 = fv.z; v3 = fv.w;
                    } else {
                        if (kb + 0 < K) v0 = ap[0];
                        if (kb + 1 < K) v1 = ap[1];
                        if (kb + 2 < K) v2 = ap[2];
                        if (kb + 3 < K) v3 = ap[3];
                    }
                }
                h4 hv = { (_Float16)v0, (_Float16)v1, (_Float16)v2, (_Float16)v3 };
                int c = c4 >> 1, sub = c4 & 1;
                *(h4*)&Ah[(c * 128 + row) * 8 + sub * 4] = hv;
            }
        }
        #pragma unroll
        for (int i = 0; i < 2; ++i) {
            int e = t + i * 256;
            int col = e >> 2, c = e & 3;
            *(h8*)&Bh[(c * 128 + col) * 8] =
                *(const h8*)(Bt + (size_t)(n0 + col) * Kp + k0 + c * 8);
        }
        __syncthreads();
        h8 af[2][2], bf[2][2];
        #pragma unroll
        for (int m2 = 0; m2 < 2; ++m2)
            #pragma unroll
            for (int ku = 0; ku < 2; ++ku) {
                int c = ku * 2 + half;
                af[m2][ku] = *(const h8*)&Ah[(c * 128 + wm + m2 * 32 + l31) * 8];
                bf[m2][ku] = *(const h8*)&Bh[(c * 128 + wn + m2 * 32 + l31) * 8];
            }
        #pragma unroll
        for (int ku = 0; ku < 2; ++ku) {
            acc00 = MFMA16(af[0][ku], bf[0][ku], acc00);
            acc01 = MFMA16(af[0][ku], bf[1][ku], acc01);
            acc10 = MFMA16(af[1][ku], bf[0][ku], acc10);
            acc11 = MFMA16(af[1][ku], bf[1][ku], acc11);
        }
    }
    float* Cf = (float*)Cp;
    _Float16* Ch = (_Float16*)Cp;
    #define EPILOG(ACCV, M2, N2) { \
        int gn = n0 + wn + (N2) * 32 + l31; \
        if (gn < N) { \
            float bv = bias[gn]; \
            _Pragma("unroll") \
            for (int r = 0; r < 16; ++r) { \
                int gm = m0 + wm + (M2) * 32 + (r & 3) + 8 * (r >> 2) + 4 * half; \
                if (gm < M) { \
                    float v = ACCV[r] + bv; \
                    if (RES) v += res[(size_t)gm * N + gn]; \
                    if (ACT == 1) v = gelu_f(v); \
                    if (OUTH) Ch[(size_t)gm * N + gn] = (_Float16)v; \
                    else      Cf[(size_t)gm * N + gn] = v; \
                } } } }
    EPILOG(acc00, 0, 0) EPILOG(acc01, 0, 1) EPILOG(acc10, 1, 0) EPILOG(acc11, 1, 1)
    #undef EPILOG
}

// ---------------------------------------------------------------------------
// Split-K GEMM for wf2: A f16 [13824][2048], B f16 [384][2048],
// partial[z] fp32 [13824][360], z = blockIdx.z in {0,1}, K-chunk 1024.
// ---------------------------------------------------------------------------
__global__ __launch_bounds__(256, 2) void k_skgemm(
    const _Float16* __restrict__ A, const _Float16* __restrict__ Bt,
    float* __restrict__ P)
{
    __shared__ __align__(16) _Float16 Ah[4096], Bh[4096];
    const int t = threadIdx.x;
    const int lane = t & 63, wid = t >> 6;
    const int half = lane >> 5, l31 = lane & 31;
    const int m0 = blockIdx.y * 128, n0 = blockIdx.x * 128;
    const int wm = (wid >> 1) * 64, wn = (wid & 1) * 64;
    const int zb = blockIdx.z * 1024;
    P += (size_t)blockIdx.z * MTOK * EMBD;

    f32x16 acc00 = {}, acc01 = {}, acc10 = {}, acc11 = {};
    for (int ks = 0; ks < 32; ++ks) {
        const int k0 = zb + (ks << 5);
        __syncthreads();
        #pragma unroll
        for (int i = 0; i < 2; ++i) {
            int e = t + i * 256;
            int row = e >> 2, c = e & 3;
            *(h8*)&Ah[(c * 128 + row) * 8] =
                *(const h8*)(A + (size_t)(m0 + row) * 2048 + k0 + c * 8);
        }
        #pragma unroll
        for (int i = 0; i < 2; ++i) {
            int e = t + i * 256;
            int col = e >> 2, c = e & 3;
            *(h8*)&Bh[(c * 128 + col) * 8] =
                *(const h8*)(Bt + (size_t)(n0 + col) * 2048 + k0 + c * 8);
        }
        __syncthreads();
        h8 af[2][2], bf[2][2];
        #pragma unroll
        for (int m2 = 0; m2 < 2; ++m2)
            #pragma unroll
            for (int ku = 0; ku < 2; ++ku) {
                int c = ku * 2 + half;
                af[m2][ku] = *(const h8*)&Ah[(c * 128 + wm + m2 * 32 + l31) * 8];
                bf[m2][ku] = *(const h8*)&Bh[(c * 128 + wn + m2 * 32 + l31) * 8];
            }
        #pragma unroll
        for (int ku = 0; ku < 2; ++ku) {
            acc00 = MFMA16(af[0][ku], bf[0][ku], acc00);
            acc01 = MFMA16(af[0][ku], bf[1][ku], acc01);
            acc10 = MFMA16(af[1][ku], bf[0][ku], acc10);
            acc11 = MFMA16(af[1][ku], bf[1][ku], acc11);
        }
    }
    #define EPILOGP(ACCV, M2, N2) { \
        int gn = n0 + wn + (N2) * 32 + l31; \
        if (gn < EMBD) { \
            _Pragma("unroll") \
            for (int r = 0; r < 16; ++r) { \
                int gm = m0 + wm + (M2) * 32 + (r & 3) + 8 * (r >> 2) + 4 * half; \
                P[(size_t)gm * EMBD + gn] = ACCV[r]; \
            } } }
    EPILOGP(acc00, 0, 0) EPILOGP(acc01, 0, 1) EPILOGP(acc10, 1, 0) EPILOGP(acc11, 1, 1)
    #undef EPILOGP
}

// ---------------------------------------------------------------------------
// Flash attention, f16 MFMA. qkv f16 [13824][1152]: sec*384 + 96h + d;
// Q pre-scaled; V has 1.0 at d==90 (denominator). Writes aob f16 [13824][384]
// in the PADDED layout col = 96h + d (wo weights permuted to match).
// ---------------------------------------------------------------------------
__global__ __launch_bounds__(256, 2) void k_mattn(
    const _Float16* __restrict__ qkv, _Float16* __restrict__ aob,
    const int* __restrict__ tcp)
{
    __shared__ __align__(16) _Float16 Kl[64 * 128];
    __shared__ __align__(16) _Float16 Vl[64 * 128];
    __shared__ __align__(16) _Float16 Pl[4][32 * 64];

    const int t = threadIdx.x;
    const int lane = t & 63, wid = t >> 6;
    const int half = lane >> 5, l31 = lane & 31;
    const int bid = blockIdx.x;
    const int bh = bid & 31, qt = bid >> 5;
    const int h = bh & 3, b = bh >> 2;
    const int Tc = *tcp;
    const int q0w = qt * 128 + wid * 32;
    const size_t base = (size_t)b * TBM * 1152;

    h8 qf[6];
    {
        int rl = q0w + l31; if (rl > TBM - 1) rl = TBM - 1;
        const _Float16* qrow = qkv + base + (size_t)rl * 1152 + 96 * h;
        #pragma unroll
        for (int ku = 0; ku < 6; ++ku)
            qf[ku] = *(const h8*)(qrow + ku * 16 + half * 8);
    }

    f32x16 o0 = {}, o1 = {}, o2 = {};
    int nkt = (Tc + 63) >> 6; if (nkt > 27) nkt = 27;

    for (int kt = 0; kt < nkt; ++kt) {
        const int k0 = kt * 64;
        __syncthreads();
        #pragma unroll
        for (int i = 0; i < 3; ++i) {
            int cid = t + i * 256;
            int kk = cid / 12, c = cid - kk * 12;
            int cp = c ^ (kk & 7);
            const _Float16* src = qkv + base + (size_t)(k0 + kk) * 1152 + 96 * h;
            *(h8*)&Kl[kk * 128 + cp * 8] = *(const h8*)(src + 384 + c * 8);
            *(h8*)&Vl[kk * 128 + cp * 8] = *(const h8*)(src + 768 + c * 8);
        }
        __syncthreads();
        f32x16 s0 = {}, s1 = {};
        #pragma unroll
        for (int ku = 0; ku < 6; ++ku) {
            int c = ku * 2 + half;
            int cp = c ^ (l31 & 7);
            h8 kb0 = *(const h8*)&Kl[l31 * 128 + cp * 8];
            h8 kb1 = *(const h8*)&Kl[(32 + l31) * 128 + cp * 8];
            s0 = MFMA16(qf[ku], kb0, s0);
            s1 = MFMA16(qf[ku], kb1, s1);
        }
        const bool ok0 = (k0 + l31) < Tc;
        const bool ok1 = (k0 + 32 + l31) < Tc;
        const int c0 = l31 >> 3, c1 = 4 + (l31 >> 3), j0 = l31 & 7;
        #pragma unroll
        for (int r = 0; r < 16; ++r) {
            int ql = (r & 3) + 8 * (r >> 2) + 4 * half;
            float p0 = ok0 ? __expf(s0[r]) : 0.0f;
            float p1 = ok1 ? __expf(s1[r]) : 0.0f;
            Pl[wid][ql * 64 + (c0 ^ (ql & 7)) * 8 + j0] = (_Float16)p0;
            Pl[wid][ql * 64 + (c1 ^ (ql & 7)) * 8 + j0] = (_Float16)p1;
        }
        asm volatile("s_waitcnt lgkmcnt(0)" ::: "memory");
        __builtin_amdgcn_sched_barrier(0);
        h8 pa[4];
        #pragma unroll
        for (int ku = 0; ku < 4; ++ku) {
            int c = ku * 2 + half;
            pa[ku] = *(const h8*)&Pl[wid][l31 * 64 + (c ^ (l31 & 7)) * 8];
        }
        #pragma unroll
        for (int n = 0; n < 3; ++n) {
            f32x16* op = n == 0 ? &o0 : (n == 1 ? &o1 : &o2);
            int d = n * 32 + l31;
            int cd = d >> 3, jd = d & 7;
            #pragma unroll
            for (int ku = 0; ku < 4; ++ku) {
                h8 vb;
                #pragma unroll
                for (int j = 0; j < 8; ++j) {
                    int kk = ku * 16 + half * 8 + j;
                    vb[j] = Vl[kk * 128 + (cd ^ (kk & 7)) * 8 + jd];
                }
                *op = MFMA16(pa[ku], vb, *op);
            }
        }
        __syncthreads();
    }

    #pragma unroll
    for (int r = 0; r < 16; ++r) {
        float den = __shfl(o2[r], (lane & 32) | 26);
        float inv = (den > 0.0f) ? 1.0f / den : 0.0f;
        int qg = q0w + (r & 3) + 8 * (r >> 2) + 4 * half;
        if (qg < Tc) {
            _Float16* orow = aob + ((size_t)b * TBM + qg) * 384 + 96 * h;
            orow[l31]      = (_Float16)(o0[r] * inv);
            orow[32 + l31] = (_Float16)(o1[r] * inv);
            orow[64 + l31] = (64 + l31 < HDD) ? (_Float16)(o2[r] * inv) : (_Float16)0.0f;
        }
    }
}

// ---------------------------------------------------------------------------
// Gather + 3^3 sum-pool; also accumulates per-token |sum| into vsum (atomic)
// so the separate mask pass is not needed.
// ---------------------------------------------------------------------------
__global__ __launch_bounds__(128) void k_pool(
    const float* __restrict__ F_emb, const int* __restrict__ C,
    float* __restrict__ nodes, float* __restrict__ vsum)
{
    const int tkn = blockIdx.x, b = blockIdx.y;
    const int oz = tkn % 12, oy = (tkn / 12) % 12, ox = tkn / 144;
    __shared__ int idx[27];
    const int tid = threadIdx.x;
    if (tid < 27) {
        int dx = tid / 9, dy = (tid / 3) % 3, dz = tid % 3;
        idx[tid] = C[(((b * GG) + ox * 2 + dx) * GG + oy * 2 + dy) * GG + oz * 2 + dz];
    }
    __syncthreads();
    float a0 = 0.f, a1 = 0.f, a2 = 0.f;
    for (int n = 0; n < 27; ++n) {
        int c = idx[n];
        if (c == 0) continue;
        const float* src = F_emb + (size_t)(b * NROI + (c - 1)) * EMBD;
        a0 += src[tid]; a1 += src[tid + 128];
        if (tid < 104) a2 += src[tid + 256];
    }
    float* dst = nodes + ((size_t)b * TBM + tkn) * EMBD;
    dst[tid] = a0; dst[tid + 128] = a1;
    if (tid < 104) dst[tid + 256] = a2;
    // |.| reduction for the validity mask
    float s = fabsf(a0) + fabsf(a1) + ((tid < 104) ? fabsf(a2) : 0.0f);
    #pragma unroll
    for (int o = 32; o >= 1; o >>= 1) s += __shfl_xor(s, o);
    __shared__ float red[2];
    if ((tid & 63) == 0) red[tid >> 6] = s;
    __syncthreads();
    if (tid == 0) atomicAdd(&vsum[tkn], red[0] + red[1]);
}

__global__ __launch_bounds__(256) void k_scan(
    const float* __restrict__ vsum, int* __restrict__ cidx, int* __restrict__ tcp)
{
    __shared__ int csum[256];
    __shared__ int coff[256];
    const int t = threadIdx.x;
    const int base = t * 7;
    int loc[7]; int s = 0;
    #pragma unroll
    for (int i = 0; i < 7; ++i) {
        int g = base + i;
        int v = (g < TBM) ? (vsum[g] > 0.0f ? 1 : 0) : 0;
        loc[i] = v; s += v;
    }
    csum[t] = s;
    __syncthreads();
    if (t == 0) {
        int a = 0;
        for (int i = 0; i < 256; ++i) { coff[i] = a; a += csum[i]; }
        *tcp = a;
    }
    __syncthreads();
    int off = coff[t];
    #pragma unroll
    for (int i = 0; i < 7; ++i) {
        int g = base + i;
        if (g < TBM && loc[i]) cidx[off++] = g;
    }
}

// compact -> t360 fp32 [.][360] and xh f16 [.][384] (pads zero)
__global__ __launch_bounds__(128) void k_compact(
    const float* __restrict__ nodes, const int* __restrict__ cidx,
    const int* __restrict__ tcp, float* __restrict__ xf, _Float16* __restrict__ xh)
{
    const int j = blockIdx.x, b = blockIdx.y;
    const int Tc = *tcp;
    const size_t row = (size_t)b * TBM + j;
    const float* src = (j < Tc) ? nodes + ((size_t)b * TBM + cidx[j]) * EMBD : nullptr;
    for (int e = threadIdx.x; e < 384; e += 128) {
        float v = (e < EMBD && src) ? src[e] : 0.0f;
        if (e < EMBD) xf[row * EMBD + e] = v;
        xh[row * 384 + e] = (_Float16)v;
    }
}

// LayerNorm: y fp32[.][360] -> outf fp32 + outh f16 [.][384] (pads zero)
__global__ __launch_bounds__(128) void k_ln(
    const float* y, const float* __restrict__ sc,
    const float* __restrict__ bc, float* outf, _Float16* __restrict__ outh)
{
    const int row = blockIdx.x;
    const int t = threadIdx.x;
    const float* yr = y + (size_t)row * EMBD;
    float x0 = yr[t], x1 = yr[t + 128];
    float x2 = (t < 104) ? yr[t + 256] : 0.0f;
    float sum = x0 + x1 + x2;
    __shared__ float red[2];
    #pragma unroll
    for (int o = 32; o >= 1; o >>= 1) sum += __shfl_xor(sum, o);
    if ((t & 63) == 0) red[t >> 6] = sum;
    __syncthreads();
    float mean = (red[0] + red[1]) * (1.0f / 360.0f);
    float d0 = x0 - mean, d1 = x1 - mean, d2 = (t < 104) ? (x2 - mean) : 0.0f;
    float vs = d0 * d0 + d1 * d1 + d2 * d2;
    __syncthreads();
    #pragma unroll
    for (int o = 32; o >= 1; o >>= 1) vs += __shfl_xor(vs, o);
    if ((t & 63) == 0) red[t >> 6] = vs;
    __syncthreads();
    float var = (red[0] + red[1]) * (1.0f / 360.0f);
    float rs = rsqrtf(var + 1e-5f);
    float* orow = outf + (size_t)row * EMBD;
    _Float16* hrow = outh + (size_t)row * 384;
    float v0 = d0 * rs * sc[t] + bc[t];
    float v1 = d1 * rs * sc[t + 128] + bc[t + 128];
    orow[t] = v0;       hrow[t] = (_Float16)v0;
    orow[t + 128] = v1; hrow[t + 128] = (_Float16)v1;
    if (t < 104) {
        float v2 = d2 * rs * sc[t + 256] + bc[t + 256];
        orow[t + 256] = v2; hrow[t + 256] = (_Float16)v2;
    } else {
        hrow[t + 256] = (_Float16)0.0f;   // cols 360..383
    }
}

// Split-K reduce + bias + residual + LayerNorm
__global__ __launch_bounds__(128) void k_ln2(
    const float* __restrict__ p0, const float* __restrict__ p1,
    const float* __restrict__ bias, const float* res,
    const float* __restrict__ sc, const float* __restrict__ bc,
    float* outf, _Float16* __restrict__ outh)
{
    const int row = blockIdx.x;
    const int t = threadIdx.x;
    const size_t ro = (size_t)row * EMBD;
    float x0 = p0[ro + t]       + p1[ro + t]       + bias[t]       + res[ro + t];
    float x1 = p0[ro + t + 128] + p1[ro + t + 128] + bias[t + 128] + res[ro + t + 128];
    float x2 = (t < 104) ? (p0[ro + t + 256] + p1[ro + t + 256] + bias[t + 256] + res[ro + t + 256]) : 0.0f;
    float sum = x0 + x1 + x2;
    __shared__ float red[2];
    #pragma unroll
    for (int o = 32; o >= 1; o >>= 1) sum += __shfl_xor(sum, o);
    if ((t & 63) == 0) red[t >> 6] = sum;
    __syncthreads();
    float mean = (red[0] + red[1]) * (1.0f / 360.0f);
    float d0 = x0 - mean, d1 = x1 - mean, d2 = (t < 104) ? (x2 - mean) : 0.0f;
    float vs = d0 * d0 + d1 * d1 + d2 * d2;
    __syncthreads();
    #pragma unroll
    for (int o = 32; o >= 1; o >>= 1) vs += __shfl_xor(vs, o);
    if ((t & 63) == 0) red[t >> 6] = vs;
    __syncthreads();
    float var = (red[0] + red[1]) * (1.0f / 360.0f);
    float rs = rsqrtf(var + 1e-5f);
    float* orow = outf + ro;
    _Float16* hrow = outh + (size_t)row * 384;
    float v0 = d0 * rs * sc[t] + bc[t];
    float v1 = d1 * rs * sc[t + 128] + bc[t + 128];
    orow[t] = v0;       hrow[t] = (_Float16)v0;
    orow[t + 128] = v1; hrow[t + 128] = (_Float16)v1;
    if (t < 104) {
        float v2 = d2 * rs * sc[t + 256] + bc[t + 256];
        orow[t + 256] = v2; hrow[t + 256] = (_Float16)v2;
    } else {
        hrow[t + 256] = (_Float16)0.0f;
    }
}

// ---------------------------------------------------------------------------
// Mean stage 1: partial[chunk][b][e] = sum over tokens in chunk (coalesced).
// 16 chunks x 8 batches = 128 blocks. Division by Tc happens in k_head.
// ---------------------------------------------------------------------------
__global__ __launch_bounds__(128) void k_mean2(
    const float* __restrict__ x, float* __restrict__ partial,
    const int* __restrict__ tcp)
{
    const int chunk = blockIdx.x;   // 0..15, 108 tokens each
    const int b = blockIdx.y;
    const int t = threadIdx.x;
    const int Tc = *tcp;
    int j0 = chunk * 108;
    int j1 = j0 + 108; if (j1 > Tc) j1 = Tc;
    const float* xb = x + (size_t)b * TBM * EMBD;
    float a0 = 0.f, a1 = 0.f, a2 = 0.f;
    for (int j = j0; j < j1; ++j) {
        const float* r = xb + (size_t)j * EMBD;
        a0 += r[t]; a1 += r[t + 128];
        if (t < 104) a2 += r[t + 256];
    }
    float* p = partial + ((size_t)chunk * NB + b) * EMBD;
    p[t] = a0; p[t + 128] = a1;
    if (t < 104) p[t + 256] = a2;
}

__global__ __launch_bounds__(256) void k_head(
    const float* __restrict__ partial, const int* __restrict__ tcp,
    const float* __restrict__ cw1, const float* __restrict__ cb1,
    const float* __restrict__ cw2, const float* __restrict__ cb2,
    const float* __restrict__ cw3, const float* __restrict__ cb3,
    float* __restrict__ outp)
{
    __shared__ float hs[NB * EMBD];
    __shared__ float h1[NB * 256];
    __shared__ float h2[NB * 128];
    const int t = threadIdx.x;
    int Tc = *tcp; if (Tc < 1) Tc = 1;
    const float inv = 1.0f / (float)Tc;
    for (int i = t; i < NB * EMBD; i += 256) {
        float s = 0.f;
        #pragma unroll
        for (int c = 0; c < 16; ++c) s += partial[(size_t)c * NB * EMBD + i];
        hs[i] = s * inv;
    }
    __syncthreads();
    for (int i = t; i < NB * 256; i += 256) {
        int b = i >> 8, o = i & 255;
        float s = cb1[o];
        for (int k = 0; k < EMBD; ++k) s = fmaf(hs[b * EMBD + k], cw1[k * 256 + o], s);
        h1[i] = gelu_f(s);
    }
    __syncthreads();
    for (int i = t; i < NB * 128; i += 256) {
        int b = i >> 7, o = i & 127;
        float s = cb2[o];
        for (int k = 0; k < 256; ++k) s = fmaf(h1[b * 256 + k], cw2[k * 128 + o], s);
        h2[i] = fmaxf(s, 0.0f);
    }
    __syncthreads();
    if (t < 16) {
        int b = t >> 1, o = t & 1;
        float s = cb3[o];
        for (int k = 0; k < 128; ++k) s = fmaf(h2[b * 128 + k], cw3[k * 2 + o], s);
        outp[t] = s;
    }
}

// ---------------------------------------------------------------------------
extern "C" void kernel_launch(void* const* d_in, const int* in_sizes, int n_in,
                              void* d_out, int out_size, void* d_ws, size_t ws_size,
                              hipStream_t stream)
{
    const float* F_roi  = (const float*)d_in[0];
    const int*   C      = (const int*)d_in[1];
    const float* ffn_w1 = (const float*)d_in[2];
    const float* ffn_b1 = (const float*)d_in[3];
    const float* ffn_w2 = (const float*)d_in[4];
    const float* ffn_b2 = (const float*)d_in[5];
    const float* wqkv   = (const float*)d_in[6];
    const float* bqkv   = (const float*)d_in[7];
    const float* wo     = (const float*)d_in[8];
    const float* bo     = (const float*)d_in[9];
    const float* ln1s   = (const float*)d_in[10];
    const float* ln1b   = (const float*)d_in[11];
    const float* wf1    = (const float*)d_in[12];
    const float* bf1    = (const float*)d_in[13];
    const float* wf2    = (const float*)d_in[14];
    const float* bf2    = (const float*)d_in[15];
    const float* ln2s   = (const float*)d_in[16];
    const float* ln2b   = (const float*)d_in[17];
    const float* cw1    = (const float*)d_in[18];
    const float* cb1    = (const float*)d_in[19];
    const float* cw2    = (const float*)d_in[20];
    const float* cb2    = (const float*)d_in[21];
    const float* cw3    = (const float*)d_in[22];
    const float* cb3    = (const float*)d_in[23];
    float* out = (float*)d_out;

    float* ws = (float*)d_ws;
    // layout (float offsets)
    _Float16* qkvh = (_Float16*)ws;                   // [13824][1152] f16 (7,962,624 f)
    float*    tmp450 = ws;                            // alias (1,440,000 f)
    float*    F_emb  = ws + 1440000;                  // alias (1,152,000 f)
    float*    midf   = ws + 7962624;                  // midb f16 area (14,155,776 f)
    _Float16* midb   = (_Float16*)midf;               // [13824][2048] f16
    float*    nodes  = midf;                          // alias fp32 (4,976,640 f)
    _Float16* aob    = (_Float16*)(ws + 22118400);    // [13824][384] f16 (2,654,208 f)
    float*    p0     = ws + 24772608;                 // (4,976,640 f)
    float*    p1     = ws + 29749248;                 // (4,976,640 f)
    float*    t360   = ws + 34725888;                 // (4,976,640 f)
    _Float16* xh     = (_Float16*)(ws + 39702528);    // [13824][384] f16 (2,654,208 f)
    _Float16* sw     = (_Float16*)(ws + 42356736);    // weights (2,385,920 f as shorts)

    size_t so = 0;
    auto salloc = [&](size_t n) { _Float16* p = sw + so; so += n; return p; };
    _Float16* w1c  = salloc(262144);           // [512][512]
    _Float16* w2c  = salloc(184320);           // [384][480]
    _Float16* qkvc = salloc(2 * 442368);       // [1152][384] x2 (contiguous per layer)
    _Float16* woc  = salloc(2 * 147456);       // [384][384]  x2
    _Float16* f1c  = salloc(2 * 786432);       // [2048][384] x2
    _Float16* f2c  = salloc(2 * 786432);       // [384][2048] x2
    float* partial = ws + 44742656;            // 46,080 f (16 x 8 x 360)
    int*   ints    = (int*)(partial + 46080);
    int*   cidx    = ints;                     // 1728
    int*   tcp     = ints + 1728;              // 1
    float* vsumf   = (float*)(ints + 1732);    // 1728
    float* bqp     = vsumf + 1728;             // 2 x 1152

    dim3 blk(256);

    // Weight conversions (layer pairs merged via blockIdx.y/z)
    k_wconv<<<dim3(16, 16, 1), blk, 0, stream>>>(ffn_w1, 512, 450, w1c, 512, 512, 0, 0);
    k_wconv<<<dim3(15, 12, 1), blk, 0, stream>>>(ffn_w2, 450, 360, w2c, 480, 384, 0, 0);
    k_wconv_qkv<<<dim3(1728, 2), blk, 0, stream>>>(wqkv, qkvc);
    k_bias_qkv<<<dim3(5, 2), blk, 0, stream>>>(bqkv, bqp);
    k_wconv_wo<<<dim3(576, 2), blk, 0, stream>>>(wo, woc);
    k_wconv<<<dim3(12, 64, 2), blk, 0, stream>>>(wf1, 360, 2048, f1c, 384, 2048, 360 * 2048, 786432);
    k_wconv<<<dim3(64, 12, 2), blk, 0, stream>>>(wf2, 2048, 360, f2c, 2048, 384, 2048 * 360, 786432);

    // Node featurization
    hipMemsetAsync(vsumf, 0, TBM * sizeof(float), stream);
    k_mgemm<1, false, false, false><<<dim3(4, 25), blk, 0, stream>>>(F_roi, w1c, ffn_b1, nullptr, tmp450, 3200, 450, 512, 512);
    k_mgemm<0, false, false, false><<<dim3(3, 25), blk, 0, stream>>>(tmp450, w2c, ffn_b2, nullptr, F_emb, 3200, 360, 450, 480);
    k_pool<<<dim3(1728, 8), dim3(128), 0, stream>>>(F_emb, C, nodes, vsumf);
    k_scan<<<dim3(1), blk, 0, stream>>>(vsumf, cidx, tcp);
    k_compact<<<dim3(1728, 8), dim3(128), 0, stream>>>(nodes, cidx, tcp, t360, xh);

    // Transformer layers
    for (int l = 0; l < 2; ++l) {
        k_mgemm<0, false, true, true><<<dim3(9, 108), blk, 0, stream>>>(xh, qkvc + (size_t)l * 442368, bqp + l * 1152, nullptr, qkvh, MTOK, 1152, 360, 384);
        k_mattn<<<dim3(448), blk, 0, stream>>>(qkvh, aob, tcp);
        k_mgemm<0, true, false, true><<<dim3(3, 108), blk, 0, stream>>>(aob, woc + (size_t)l * 147456, bo + l * 360, t360, t360, MTOK, 360, 384, 384);
        k_ln<<<dim3(MTOK), dim3(128), 0, stream>>>(t360, ln1s + l * 360, ln1b + l * 360, t360, xh);
        k_mgemm<1, false, true, true><<<dim3(16, 108), blk, 0, stream>>>(xh, f1c + (size_t)l * 786432, bf1 + l * 2048, nullptr, midb, MTOK, 2048, 360, 384);
        k_skgemm<<<dim3(3, 108, 2), blk, 0, stream>>>(midb, f2c + (size_t)l * 786432, p0);
        k_ln2<<<dim3(MTOK), dim3(128), 0, stream>>>(p0, p1, bf2 + l * 360, t360, ln2s + l * 360, ln2b + l * 360, t360, xh);
    }

    // Head
    k_mean2<<<dim3(16, 8), dim3(128), 0, stream>>>(t360, partial, tcp);
    k_head<<<dim3(1), blk, 0, stream>>>(partial, tcp, cw1, cb1, cw2, cb2, cw3, cb3, out);
}

// Round 8
// 790.395 us; speedup vs baseline: 6.3394x; 1.0365x over previous
//
#include <hip/hip_runtime.h>
#include <math.h>

#define NB   8
#define NROI 400
#define GG   25
#define EMBD 360
#define HDD  90
#define TBM  1728
#define MTOK 13824      // NB*TBM

typedef __attribute__((ext_vector_type(8)))  _Float16 h8;   // 8 f16 (4 VGPR)
typedef __attribute__((ext_vector_type(4)))  _Float16 h4;
typedef __attribute__((ext_vector_type(16))) float f32x16;

#define MFMA16(a,b,c) __builtin_amdgcn_mfma_f32_32x32x16_f16(a,b,c,0,0,0)
#define QSCALE 0.105409255338945984f   /* 1/sqrt(90) */

__device__ __forceinline__ float gelu_f(float x) {
    return 0.5f * x * (1.0f + erff(x * 0.7071067811865475f));
}

// ---------------------------------------------------------------------------
// Tiled weight convert+transpose: W[K][N] fp32 -> Wt[Np][Kp] f16 (zero-pad).
// blockIdx.z = layer (W += z*Wls, Wt += z*Wtls).
// ---------------------------------------------------------------------------
__global__ __launch_bounds__(256) void k_wconv(
    const float* __restrict__ W, int K, int N,
    _Float16* __restrict__ Wt, int Kp, int Np, int Wls, int Wtls)
{
    W  += (size_t)blockIdx.z * Wls;
    Wt += (size_t)blockIdx.z * Wtls;
    __shared__ float tile[32][33];
    const int k0 = blockIdx.x * 32, n0 = blockIdx.y * 32;
    const int t = threadIdx.x;
    #pragma unroll
    for (int it = 0; it < 4; ++it) {
        int e = t + it * 256;
        int i = e >> 5, j = e & 31;
        tile[j][i] = (k0 + i < K && n0 + j < N) ? W[(size_t)(k0 + i) * N + n0 + j] : 0.0f;
    }
    __syncthreads();
    #pragma unroll
    for (int it = 0; it < 4; ++it) {
        int e = t + it * 256;
        int n = e >> 5, kk = e & 31;
        if (n0 + n < Np && k0 + kk < Kp)
            Wt[(size_t)(n0 + n) * Kp + k0 + kk] = (_Float16)tile[n][kk];
    }
}

// qkv(2x) + wo(2x) + qkv-bias(2x) conversions fused into one flat kernel.
__global__ __launch_bounds__(256) void k_wmisc(
    const float* __restrict__ wqkv, const float* __restrict__ wo,
    const float* __restrict__ bqkv,
    _Float16* __restrict__ qkvc, _Float16* __restrict__ woc,
    float* __restrict__ bqp)
{
    int id = blockIdx.x * 256 + threadIdx.x;
    if (id < 884736) {                       // qkv: Wt[1152][384], n' = sec*384+96h+d
        int l = id / 442368, r = id - l * 442368;
        int np = r / 384, kk = r - np * 384;
        int sec = np / 384, rr = np - sec * 384, h = rr / 96, d = rr - h * 96;
        float v = 0.0f;
        if (d < HDD && kk < 360) v = wqkv[(size_t)l * 388800 + (size_t)kk * 1080 + sec * 360 + h * HDD + d];
        if (sec == 0) v *= QSCALE;
        qkvc[id] = (_Float16)v;
    } else if (id < 1179648) {               // wo: Wt[384][384], k' = 96h+d
        int r2 = id - 884736;
        int l = r2 / 147456, r = r2 - l * 147456;
        int n = r / 384, kp = r - n * 384;
        int h = kp / 96, d = kp - h * 96;
        float v = 0.0f;
        if (d < HDD && n < 360) v = wo[(size_t)l * 129600 + (size_t)(h * HDD + d) * 360 + n];
        woc[r2] = (_Float16)v;
    } else if (id < 1181952) {               // padded qkv bias [1152]
        int r3 = id - 1179648;
        int l = r3 / 1152, r = r3 - l * 1152;
        int sec = r / 384, rr = r - sec * 384, h = rr / 96, d = rr - h * 96;
        float v = 0.0f;
        if (d < HDD) v = bqkv[l * 1080 + sec * 360 + h * HDD + d];
        if (sec == 0) v *= QSCALE;
        if (sec == 2 && d == HDD) v = 1.0f;  // softmax denominator column
        bqp[r3] = v;
    }
}

// ---------------------------------------------------------------------------
// MFMA GEMM (f16): C = act(A@B + bias (+res)). 128x128 tile, BK=32, 4 waves.
// AH: A is f16 [M][Kp] (pre-padded); else fp32 [M][K]. OUTH: write f16.
// ---------------------------------------------------------------------------
template <int ACT, bool RES, bool OUTH, bool AH>
__global__ __launch_bounds__(256, 2) void k_mgemm(
    const void* __restrict__ Ap, const _Float16* __restrict__ Bt,
    const float* __restrict__ bias, const float* res, void* Cp,
    int M, int N, int K, int Kp)
{
    __shared__ __align__(16) _Float16 Ah[4096], Bh[4096];
    const int t = threadIdx.x;
    const int lane = t & 63, wid = t >> 6;
    const int half = lane >> 5, l31 = lane & 31;
    const int m0 = blockIdx.y * 128, n0 = blockIdx.x * 128;
    const int wm = (wid >> 1) * 64, wn = (wid & 1) * 64;

    f32x16 acc00 = {}, acc01 = {}, acc10 = {}, acc11 = {};
    const int nk = Kp >> 5;
    const bool k4 = (K & 3) == 0;

    for (int ks = 0; ks < nk; ++ks) {
        const int k0 = ks << 5;
        __syncthreads();
        if (AH) {
            const _Float16* Af = (const _Float16*)Ap;
            #pragma unroll
            for (int i = 0; i < 2; ++i) {
                int e = t + i * 256;
                int row = e >> 2, c = e & 3;
                int gm = m0 + row; if (gm > M - 1) gm = M - 1;
                *(h8*)&Ah[(c * 128 + row) * 8] =
                    *(const h8*)(Af + (size_t)gm * Kp + k0 + c * 8);
            }
        } else {
            const float* A = (const float*)Ap;
            #pragma unroll
            for (int i = 0; i < 4; ++i) {
                int e = t + i * 256;
                int row = e >> 3, c4 = e & 7;
                int gm = m0 + row, kb = k0 + c4 * 4;
                float v0 = 0.f, v1 = 0.f, v2 = 0.f, v3 = 0.f;
                if (gm < M) {
                    const float* ap = A + (size_t)gm * K + kb;
                    if (k4 && kb + 3 < K) {
                        float4 fv = *(const float4*)ap;
                        v0 = fv.x; v1 = fv.y; v2 = fv.z; v3 = fv.w;
                    } else {
                        if (kb + 0 < K) v0 = ap[0];
                        if (kb + 1 < K) v1 = ap[1];
                        if (kb + 2 < K) v2 = ap[2];
                        if (kb + 3 < K) v3 = ap[3];
                    }
                }
                h4 hv = { (_Float16)v0, (_Float16)v1, (_Float16)v2, (_Float16)v3 };
                int c = c4 >> 1, sub = c4 & 1;
                *(h4*)&Ah[(c * 128 + row) * 8 + sub * 4] = hv;
            }
        }
        #pragma unroll
        for (int i = 0; i < 2; ++i) {
            int e = t + i * 256;
            int col = e >> 2, c = e & 3;
            *(h8*)&Bh[(c * 128 + col) * 8] =
                *(const h8*)(Bt + (size_t)(n0 + col) * Kp + k0 + c * 8);
        }
        __syncthreads();
        h8 af[2][2], bf[2][2];
        #pragma unroll
        for (int m2 = 0; m2 < 2; ++m2)
            #pragma unroll
            for (int ku = 0; ku < 2; ++ku) {
                int c = ku * 2 + half;
                af[m2][ku] = *(const h8*)&Ah[(c * 128 + wm + m2 * 32 + l31) * 8];
                bf[m2][ku] = *(const h8*)&Bh[(c * 128 + wn + m2 * 32 + l31) * 8];
            }
        #pragma unroll
        for (int ku = 0; ku < 2; ++ku) {
            acc00 = MFMA16(af[0][ku], bf[0][ku], acc00);
            acc01 = MFMA16(af[0][ku], bf[1][ku], acc01);
            acc10 = MFMA16(af[1][ku], bf[0][ku], acc10);
            acc11 = MFMA16(af[1][ku], bf[1][ku], acc11);
        }
    }
    float* Cf = (float*)Cp;
    _Float16* Ch = (_Float16*)Cp;
    #define EPILOG(ACCV, M2, N2) { \
        int gn = n0 + wn + (N2) * 32 + l31; \
        if (gn < N) { \
            float bv = bias[gn]; \
            _Pragma("unroll") \
            for (int r = 0; r < 16; ++r) { \
                int gm = m0 + wm + (M2) * 32 + (r & 3) + 8 * (r >> 2) + 4 * half; \
                if (gm < M) { \
                    float v = ACCV[r] + bv; \
                    if (RES) v += res[(size_t)gm * N + gn]; \
                    if (ACT == 1) v = gelu_f(v); \
                    if (OUTH) Ch[(size_t)gm * N + gn] = (_Float16)v; \
                    else      Cf[(size_t)gm * N + gn] = v; \
                } } } }
    EPILOG(acc00, 0, 0) EPILOG(acc01, 0, 1) EPILOG(acc10, 1, 0) EPILOG(acc11, 1, 1)
    #undef EPILOG
}

// ---------------------------------------------------------------------------
// Split-K GEMM: A f16 [M][Kp], B f16 [Np][Kp], partial[z] fp32 [MTOK][360].
// blockIdx.z = chunk; chunk length KCH, nstep = KCH/32.
// ---------------------------------------------------------------------------
__global__ __launch_bounds__(256, 2) void k_skgemm(
    const _Float16* __restrict__ A, const _Float16* __restrict__ Bt,
    float* __restrict__ P, int Kp, int KCH, int nstep)
{
    __shared__ __align__(16) _Float16 Ah[4096], Bh[4096];
    const int t = threadIdx.x;
    const int lane = t & 63, wid = t >> 6;
    const int half = lane >> 5, l31 = lane & 31;
    const int m0 = blockIdx.y * 128, n0 = blockIdx.x * 128;
    const int wm = (wid >> 1) * 64, wn = (wid & 1) * 64;
    const int zb = blockIdx.z * KCH;
    P += (size_t)blockIdx.z * MTOK * EMBD;

    f32x16 acc00 = {}, acc01 = {}, acc10 = {}, acc11 = {};
    for (int ks = 0; ks < nstep; ++ks) {
        const int k0 = zb + (ks << 5);
        __syncthreads();
        #pragma unroll
        for (int i = 0; i < 2; ++i) {
            int e = t + i * 256;
            int row = e >> 2, c = e & 3;
            *(h8*)&Ah[(c * 128 + row) * 8] =
                *(const h8*)(A + (size_t)(m0 + row) * Kp + k0 + c * 8);
        }
        #pragma unroll
        for (int i = 0; i < 2; ++i) {
            int e = t + i * 256;
            int col = e >> 2, c = e & 3;
            *(h8*)&Bh[(c * 128 + col) * 8] =
                *(const h8*)(Bt + (size_t)(n0 + col) * Kp + k0 + c * 8);
        }
        __syncthreads();
        h8 af[2][2], bf[2][2];
        #pragma unroll
        for (int m2 = 0; m2 < 2; ++m2)
            #pragma unroll
            for (int ku = 0; ku < 2; ++ku) {
                int c = ku * 2 + half;
                af[m2][ku] = *(const h8*)&Ah[(c * 128 + wm + m2 * 32 + l31) * 8];
                bf[m2][ku] = *(const h8*)&Bh[(c * 128 + wn + m2 * 32 + l31) * 8];
            }
        #pragma unroll
        for (int ku = 0; ku < 2; ++ku) {
            acc00 = MFMA16(af[0][ku], bf[0][ku], acc00);
            acc01 = MFMA16(af[0][ku], bf[1][ku], acc01);
            acc10 = MFMA16(af[1][ku], bf[0][ku], acc10);
            acc11 = MFMA16(af[1][ku], bf[1][ku], acc11);
        }
    }
    #define EPILOGP(ACCV, M2, N2) { \
        int gn = n0 + wn + (N2) * 32 + l31; \
        if (gn < EMBD) { \
            _Pragma("unroll") \
            for (int r = 0; r < 16; ++r) { \
                int gm = m0 + wm + (M2) * 32 + (r & 3) + 8 * (r >> 2) + 4 * half; \
                P[(size_t)gm * EMBD + gn] = ACCV[r]; \
            } } }
    EPILOGP(acc00, 0, 0) EPILOGP(acc01, 0, 1) EPILOGP(acc10, 1, 0) EPILOGP(acc11, 1, 1)
    #undef EPILOGP
}

// ---------------------------------------------------------------------------
// Flash attention, f16 MFMA. qkv f16 [13824][1152]: sec*384 + 96h + d;
// Q pre-scaled; V has 1.0 at d==90 (denominator). aob f16 [.][384], col 96h+d.
// V staged into d-major swizzled LDS: Vt[d*64 + (kk ^ ((d&7)<<3))] via scalar
// writes; PV B-fragments are single aligned ds_read_b128
// (8-consecutive-kk block: kk^(z<<3) = 8(m^z)+j keeps it contiguous).
// T14: next K/V tile prefetched to regs under compute. 2 barriers/tile.
// ---------------------------------------------------------------------------
__global__ __launch_bounds__(256, 2) void k_mattn(
    const _Float16* __restrict__ qkv, _Float16* __restrict__ aob,
    const int* __restrict__ tcp)
{
    __shared__ __align__(16) _Float16 Kl[64 * 128];   // [kk][16B chunk ^ (kk&7)]
    __shared__ __align__(16) _Float16 Vl[6144];       // d-major swizzled
    __shared__ __align__(16) _Float16 Pl[4][32 * 64]; // per-wave

    const int t = threadIdx.x;
    const int lane = t & 63, wid = t >> 6;
    const int half = lane >> 5, l31 = lane & 31;
    const int bid = blockIdx.x;
    const int bh = bid & 31, qt = bid >> 5;
    const int h = bh & 3, b = bh >> 2;
    const int Tc = *tcp;
    const int q0w = qt * 128 + wid * 32;
    const size_t base = (size_t)b * TBM * 1152 + 96 * h;

    // staging geometry: thread -> (kk, c), 3 chunks each (768 = 64kk x 12c)
    int skk[3], scc[3];
    #pragma unroll
    for (int i = 0; i < 3; ++i) {
        int cid = t + i * 256;
        skk[i] = cid / 12; scc[i] = cid - skk[i] * 12;
    }

    // Q fragments (96 d, pads zero)
    h8 qf[6];
    {
        int rl = q0w + l31; if (rl > TBM - 1) rl = TBM - 1;
        const _Float16* qrow = qkv + base + (size_t)rl * 1152;
        #pragma unroll
        for (int ku = 0; ku < 6; ++ku)
            qf[ku] = *(const h8*)(qrow + ku * 16 + half * 8);
    }

    f32x16 o0 = {}, o1 = {}, o2 = {};
    int nkt = (Tc + 63) >> 6; if (nkt > 27) nkt = 27;

    // stage tile 0
    if (nkt > 0) {
        #pragma unroll
        for (int i = 0; i < 3; ++i) {
            const _Float16* s = qkv + base + (size_t)skk[i] * 1152 + scc[i] * 8;
            h8 kv = *(const h8*)(s + 384);
            h8 vv = *(const h8*)(s + 768);
            *(h8*)&Kl[skk[i] * 128 + ((scc[i] ^ (skk[i] & 7)) << 3)] = kv;
            #pragma unroll
            for (int j = 0; j < 8; ++j)
                Vl[(scc[i] * 8 + j) * 64 + (skk[i] ^ (j << 3))] = vv[j];
        }
    }
    __syncthreads();

    for (int kt = 0; kt < nkt; ++kt) {
        const int k0 = kt * 64;
        // prefetch next tile into registers (hides under MFMA phase)
        h8 kpre[3], vpre[3];
        const bool pf = (kt + 1 < nkt);
        if (pf) {
            const size_t nb = base + (size_t)(k0 + 64) * 1152;
            #pragma unroll
            for (int i = 0; i < 3; ++i) {
                const _Float16* s = qkv + nb + (size_t)skk[i] * 1152 + scc[i] * 8;
                kpre[i] = *(const h8*)(s + 384);
                vpre[i] = *(const h8*)(s + 768);
            }
        }
        // S = Q K^T (12 MFMAs)
        f32x16 s0 = {}, s1 = {};
        #pragma unroll
        for (int ku = 0; ku < 6; ++ku) {
            int c = ku * 2 + half;
            int cp = c ^ (l31 & 7);
            h8 kb0 = *(const h8*)&Kl[l31 * 128 + cp * 8];
            h8 kb1 = *(const h8*)&Kl[(32 + l31) * 128 + cp * 8];
            s0 = MFMA16(qf[ku], kb0, s0);
            s1 = MFMA16(qf[ku], kb1, s1);
        }
        // P = exp(S), masked, store f16 to per-wave Pl
        const bool ok0 = (k0 + l31) < Tc;
        const bool ok1 = (k0 + 32 + l31) < Tc;
        const int c0 = l31 >> 3, c1 = 4 + (l31 >> 3), j0 = l31 & 7;
        #pragma unroll
        for (int r = 0; r < 16; ++r) {
            int ql = (r & 3) + 8 * (r >> 2) + 4 * half;
            float p0v = ok0 ? __expf(s0[r]) : 0.0f;
            float p1v = ok1 ? __expf(s1[r]) : 0.0f;
            Pl[wid][ql * 64 + (c0 ^ (ql & 7)) * 8 + j0] = (_Float16)p0v;
            Pl[wid][ql * 64 + (c1 ^ (ql & 7)) * 8 + j0] = (_Float16)p1v;
        }
        asm volatile("s_waitcnt lgkmcnt(0)" ::: "memory");
        __builtin_amdgcn_sched_barrier(0);
        h8 pa[4];
        #pragma unroll
        for (int ku = 0; ku < 4; ++ku) {
            int c = ku * 2 + half;
            pa[ku] = *(const h8*)&Pl[wid][l31 * 64 + (c ^ (l31 & 7)) * 8];
        }
        // PV: 12 single-b128 V fragments (d-major swizzled layout)
        #pragma unroll
        for (int n = 0; n < 3; ++n) {
            f32x16* op = n == 0 ? &o0 : (n == 1 ? &o1 : &o2);
            int d = n * 32 + l31;
            #pragma unroll
            for (int ku = 0; ku < 4; ++ku) {
                int m = ku * 2 + half;
                h8 vb = *(const h8*)&Vl[d * 64 + ((m ^ (d & 7)) << 3)];
                *op = MFMA16(pa[ku], vb, *op);
            }
        }
        __syncthreads();              // all waves done reading Kl/Vl
        if (pf) {
            #pragma unroll
            for (int i = 0; i < 3; ++i) {
                *(h8*)&Kl[skk[i] * 128 + ((scc[i] ^ (skk[i] & 7)) << 3)] = kpre[i];
                #pragma unroll
                for (int j = 0; j < 8; ++j)
                    Vl[(scc[i] * 8 + j) * 64 + (skk[i] ^ (j << 3))] = vpre[i][j];
            }
        }
        __syncthreads();              // next tile staged
    }

    // normalize by denominator (d=90 -> o2 col 26) and store padded layout
    #pragma unroll
    for (int r = 0; r < 16; ++r) {
        float den = __shfl(o2[r], (lane & 32) | 26);
        float inv = (den > 0.0f) ? 1.0f / den : 0.0f;
        int qg = q0w + (r & 3) + 8 * (r >> 2) + 4 * half;
        if (qg < Tc) {
            _Float16* orow = aob + ((size_t)b * TBM + qg) * 384 + 96 * h;
            orow[l31]      = (_Float16)(o0[r] * inv);
            orow[32 + l31] = (_Float16)(o1[r] * inv);
            orow[64 + l31] = (64 + l31 < HDD) ? (_Float16)(o2[r] * inv) : (_Float16)0.0f;
        }
    }
}

// ---------------------------------------------------------------------------
// Gather + 3^3 sum-pool + |.| mask accumulation (atomic)
// ---------------------------------------------------------------------------
__global__ __launch_bounds__(128) void k_pool(
    const float* __restrict__ F_emb, const int* __restrict__ C,
    float* __restrict__ nodes, float* __restrict__ vsum)
{
    const int tkn = blockIdx.x, b = blockIdx.y;
    const int oz = tkn % 12, oy = (tkn / 12) % 12, ox = tkn / 144;
    __shared__ int idx[27];
    const int tid = threadIdx.x;
    if (tid < 27) {
        int dx = tid / 9, dy = (tid / 3) % 3, dz = tid % 3;
        idx[tid] = C[(((b * GG) + ox * 2 + dx) * GG + oy * 2 + dy) * GG + oz * 2 + dz];
    }
    __syncthreads();
    float a0 = 0.f, a1 = 0.f, a2 = 0.f;
    for (int n = 0; n < 27; ++n) {
        int c = idx[n];
        if (c == 0) continue;
        const float* src = F_emb + (size_t)(b * NROI + (c - 1)) * EMBD;
        a0 += src[tid]; a1 += src[tid + 128];
        if (tid < 104) a2 += src[tid + 256];
    }
    float* dst = nodes + ((size_t)b * TBM + tkn) * EMBD;
    dst[tid] = a0; dst[tid + 128] = a1;
    if (tid < 104) dst[tid + 256] = a2;
    float s = fabsf(a0) + fabsf(a1) + ((tid < 104) ? fabsf(a2) : 0.0f);
    #pragma unroll
    for (int o = 32; o >= 1; o >>= 1) s += __shfl_xor(s, o);
    __shared__ float red[2];
    if ((tid & 63) == 0) red[tid >> 6] = s;
    __syncthreads();
    if (tid == 0) atomicAdd(&vsum[tkn], red[0] + red[1]);
}

__global__ __launch_bounds__(256) void k_scan(
    const float* __restrict__ vsum, int* __restrict__ cidx, int* __restrict__ tcp)
{
    __shared__ int csum[256];
    __shared__ int coff[256];
    const int t = threadIdx.x;
    const int base = t * 7;
    int loc[7]; int s = 0;
    #pragma unroll
    for (int i = 0; i < 7; ++i) {
        int g = base + i;
        int v = (g < TBM) ? (vsum[g] > 0.0f ? 1 : 0) : 0;
        loc[i] = v; s += v;
    }
    csum[t] = s;
    __syncthreads();
    if (t == 0) {
        int a = 0;
        for (int i = 0; i < 256; ++i) { coff[i] = a; a += csum[i]; }
        *tcp = a;
    }
    __syncthreads();
    int off = coff[t];
    #pragma unroll
    for (int i = 0; i < 7; ++i) {
        int g = base + i;
        if (g < TBM && loc[i]) cidx[off++] = g;
    }
}

// compact -> t360 fp32 [.][360] and xh f16 [.][384] (pads zero)
__global__ __launch_bounds__(128) void k_compact(
    const float* __restrict__ nodes, const int* __restrict__ cidx,
    const int* __restrict__ tcp, float* __restrict__ xf, _Float16* __restrict__ xh)
{
    const int j = blockIdx.x, b = blockIdx.y;
    const int Tc = *tcp;
    const size_t row = (size_t)b * TBM + j;
    const float* src = (j < Tc) ? nodes + ((size_t)b * TBM + cidx[j]) * EMBD : nullptr;
    for (int e = threadIdx.x; e < 384; e += 128) {
        float v = (e < EMBD && src) ? src[e] : 0.0f;
        if (e < EMBD) xf[row * EMBD + e] = v;
        xh[row * 384 + e] = (_Float16)v;
    }
}

// ---------------------------------------------------------------------------
// Fused split-K reduce + bias + residual + LayerNorm, one WAVE per row.
// 256 thr = 4 rows/block; lanes 0..59 hold 6 elems each (shuffle-only reduce).
// outf fp32 [.][360] (may alias res), outh f16 [.][384] (pads zero).
// ---------------------------------------------------------------------------
__global__ __launch_bounds__(256) void k_lnr(
    const float* __restrict__ p0, const float* __restrict__ p1,
    const float* __restrict__ bias, const float* res,
    const float* __restrict__ sc, const float* __restrict__ bc,
    float* outf, _Float16* __restrict__ outh)
{
    const int lane = threadIdx.x & 63;
    const int row = blockIdx.x * 4 + (threadIdx.x >> 6);
    const size_t ro = (size_t)row * EMBD;
    const int e0 = lane * 6;
    float x[6] = {0.f, 0.f, 0.f, 0.f, 0.f, 0.f};
    float sum = 0.f;
    if (lane < 60) {
        #pragma unroll
        for (int i = 0; i < 6; ++i) {
            float v = p0[ro + e0 + i] + p1[ro + e0 + i] + bias[e0 + i] + res[ro + e0 + i];
            x[i] = v; sum += v;
        }
    }
    #pragma unroll
    for (int o = 32; o >= 1; o >>= 1) sum += __shfl_xor(sum, o);
    const float mean = sum * (1.0f / 360.0f);
    float vs = 0.f;
    if (lane < 60) {
        #pragma unroll
        for (int i = 0; i < 6; ++i) { float d = x[i] - mean; vs += d * d; }
    }
    #pragma unroll
    for (int o = 32; o >= 1; o >>= 1) vs += __shfl_xor(vs, o);
    const float rs = rsqrtf(vs * (1.0f / 360.0f) + 1e-5f);
    _Float16* hrow = outh + (size_t)row * 384;
    if (lane < 60) {
        #pragma unroll
        for (int i = 0; i < 6; ++i) {
            float v = (x[i] - mean) * rs * sc[e0 + i] + bc[e0 + i];
            outf[ro + e0 + i] = v;
            hrow[e0 + i] = (_Float16)v;
        }
    } else {
        #pragma unroll
        for (int i = 0; i < 6; ++i)
            hrow[360 + (lane - 60) * 6 + i] = (_Float16)0.0f;
    }
}

// ---------------------------------------------------------------------------
// Mean stage 1: partial[chunk][b][e] = sum over tokens in chunk.
// ---------------------------------------------------------------------------
__global__ __launch_bounds__(128) void k_mean2(
    const float* __restrict__ x, float* __restrict__ partial,
    const int* __restrict__ tcp)
{
    const int chunk = blockIdx.x;   // 0..15, 108 tokens each
    const int b = blockIdx.y;
    const int t = threadIdx.x;
    const int Tc = *tcp;
    int j0 = chunk * 108;
    int j1 = j0 + 108; if (j1 > Tc) j1 = Tc;
    const float* xb = x + (size_t)b * TBM * EMBD;
    float a0 = 0.f, a1 = 0.f, a2 = 0.f;
    for (int j = j0; j < j1; ++j) {
        const float* r = xb + (size_t)j * EMBD;
        a0 += r[t]; a1 += r[t + 128];
        if (t < 104) a2 += r[t + 256];
    }
    float* p = partial + ((size_t)chunk * NB + b) * EMBD;
    p[t] = a0; p[t + 128] = a1;
    if (t < 104) p[t + 256] = a2;
}

// Head: one block per batch. Reduce 16 partials, 3 small dense layers.
__global__ __launch_bounds__(256) void k_head(
    const float* __restrict__ partial, const int* __restrict__ tcp,
    const float* __restrict__ cw1, const float* __restrict__ cb1,
    const float* __restrict__ cw2, const float* __restrict__ cb2,
    const float* __restrict__ cw3, const float* __restrict__ cb3,
    float* __restrict__ outp)
{
    const int b = blockIdx.x;
    __shared__ float hs[EMBD];
    __shared__ float h1[256];
    __shared__ float h2[128];
    const int t = threadIdx.x;
    int Tc = *tcp; if (Tc < 1) Tc = 1;
    const float inv = 1.0f / (float)Tc;
    for (int e = t; e < EMBD; e += 256) {
        float s = 0.f;
        #pragma unroll
        for (int c = 0; c < 16; ++c) s += partial[(size_t)c * NB * EMBD + b * EMBD + e];
        hs[e] = s * inv;
    }
    __syncthreads();
    {
        float s = cb1[t];
        for (int k = 0; k < EMBD; ++k) s = fmaf(hs[k], cw1[k * 256 + t], s);
        h1[t] = gelu_f(s);
    }
    __syncthreads();
    if (t < 128) {
        float s = cb2[t];
        for (int k = 0; k < 256; ++k) s = fmaf(h1[k], cw2[k * 128 + t], s);
        h2[t] = fmaxf(s, 0.0f);
    }
    __syncthreads();
    if (t < 2) {
        float s = cb3[t];
        for (int k = 0; k < 128; ++k) s = fmaf(h2[k], cw3[k * 2 + t], s);
        outp[b * 2 + t] = s;
    }
}

// ---------------------------------------------------------------------------
extern "C" void kernel_launch(void* const* d_in, const int* in_sizes, int n_in,
                              void* d_out, int out_size, void* d_ws, size_t ws_size,
                              hipStream_t stream)
{
    const float* F_roi  = (const float*)d_in[0];
    const int*   C      = (const int*)d_in[1];
    const float* ffn_w1 = (const float*)d_in[2];
    const float* ffn_b1 = (const float*)d_in[3];
    const float* ffn_w2 = (const float*)d_in[4];
    const float* ffn_b2 = (const float*)d_in[5];
    const float* wqkv   = (const float*)d_in[6];
    const float* bqkv   = (const float*)d_in[7];
    const float* wo     = (const float*)d_in[8];
    const float* bo     = (const float*)d_in[9];
    const float* ln1s   = (const float*)d_in[10];
    const float* ln1b   = (const float*)d_in[11];
    const float* wf1    = (const float*)d_in[12];
    const float* bf1    = (const float*)d_in[13];
    const float* wf2    = (const float*)d_in[14];
    const float* bf2    = (const float*)d_in[15];
    const float* ln2s   = (const float*)d_in[16];
    const float* ln2b   = (const float*)d_in[17];
    const float* cw1    = (const float*)d_in[18];
    const float* cb1    = (const float*)d_in[19];
    const float* cw2    = (const float*)d_in[20];
    const float* cb2    = (const float*)d_in[21];
    const float* cw3    = (const float*)d_in[22];
    const float* cb3    = (const float*)d_in[23];
    float* out = (float*)d_out;

    float* ws = (float*)d_ws;
    _Float16* qkvh = (_Float16*)ws;                   // [13824][1152] f16
    float*    tmp450 = ws;                            // alias
    float*    F_emb  = ws + 1440000;                  // alias
    float*    midf   = ws + 7962624;
    _Float16* midb   = (_Float16*)midf;               // [13824][2048] f16
    float*    nodes  = midf;                          // alias fp32
    _Float16* aob    = (_Float16*)(ws + 22118400);    // [13824][384] f16
    float*    p0     = ws + 24772608;
    float*    p1     = ws + 29749248;
    float*    t360   = ws + 34725888;
    _Float16* xh     = (_Float16*)(ws + 39702528);    // [13824][384] f16
    _Float16* sw     = (_Float16*)(ws + 42356736);

    size_t so = 0;
    auto salloc = [&](size_t n) { _Float16* p = sw + so; so += n; return p; };
    _Float16* w1c  = salloc(262144);           // [512][512]
    _Float16* w2c  = salloc(184320);           // [384][480]
    _Float16* qkvc = salloc(2 * 442368);       // [1152][384] x2
    _Float16* woc  = salloc(2 * 147456);       // [384][384]  x2
    _Float16* f1c  = salloc(2 * 786432);       // [2048][384] x2
    _Float16* f2c  = salloc(2 * 786432);       // [384][2048] x2
    float* partial = ws + 44742656;            // 16 x 8 x 360
    int*   ints    = (int*)(partial + 46080);
    int*   cidx    = ints;                     // 1728
    int*   tcp     = ints + 1728;              // 1
    float* vsumf   = (float*)(ints + 1732);    // 1728
    float* bqp     = vsumf + 1728;             // 2 x 1152

    dim3 blk(256);

    // Weight conversions
    k_wconv<<<dim3(16, 16, 1), blk, 0, stream>>>(ffn_w1, 512, 450, w1c, 512, 512, 0, 0);
    k_wconv<<<dim3(15, 12, 1), blk, 0, stream>>>(ffn_w2, 450, 360, w2c, 480, 384, 0, 0);
    k_wconv<<<dim3(12, 64, 2), blk, 0, stream>>>(wf1, 360, 2048, f1c, 384, 2048, 360 * 2048, 786432);
    k_wconv<<<dim3(64, 12, 2), blk, 0, stream>>>(wf2, 2048, 360, f2c, 2048, 384, 2048 * 360, 786432);
    k_wmisc<<<dim3(4618), blk, 0, stream>>>(wqkv, wo, bqkv, qkvc, woc, bqp);

    // Node featurization
    hipMemsetAsync(vsumf, 0, TBM * sizeof(float), stream);
    k_mgemm<1, false, false, false><<<dim3(4, 25), blk, 0, stream>>>(F_roi, w1c, ffn_b1, nullptr, tmp450, 3200, 450, 512, 512);
    k_mgemm<0, false, false, false><<<dim3(3, 25), blk, 0, stream>>>(tmp450, w2c, ffn_b2, nullptr, F_emb, 3200, 360, 450, 480);
    k_pool<<<dim3(1728, 8), dim3(128), 0, stream>>>(F_emb, C, nodes, vsumf);
    k_scan<<<dim3(1), blk, 0, stream>>>(vsumf, cidx, tcp);
    k_compact<<<dim3(1728, 8), dim3(128), 0, stream>>>(nodes, cidx, tcp, t360, xh);

    // Transformer layers
    for (int l = 0; l < 2; ++l) {
        k_mgemm<0, false, true, true><<<dim3(9, 108), blk, 0, stream>>>(xh, qkvc + (size_t)l * 442368, bqp + l * 1152, nullptr, qkvh, MTOK, 1152, 360, 384);
        k_mattn<<<dim3(448), blk, 0, stream>>>(qkvh, aob, tcp);
        k_skgemm<<<dim3(3, 108, 2), blk, 0, stream>>>(aob, woc + (size_t)l * 147456, p0, 384, 192, 6);
        k_lnr<<<dim3(MTOK / 4), blk, 0, stream>>>(p0, p1, bo + l * 360, t360, ln1s + l * 360, ln1b + l * 360, t360, xh);
        k_mgemm<1, false, true, true><<<dim3(16, 108), blk, 0, stream>>>(xh, f1c + (size_t)l * 786432, bf1 + l * 2048, nullptr, midb, MTOK, 2048, 360, 384);
        k_skgemm<<<dim3(3, 108, 2), blk, 0, stream>>>(midb, f2c + (size_t)l * 786432, p0, 2048, 1024, 32);
        k_lnr<<<dim3(MTOK / 4), blk, 0, stream>>>(p0, p1, bf2 + l * 360, t360, ln2s + l * 360, ln2b + l * 360, t360, xh);
    }

    // Head
    k_mean2<<<dim3(16, 8), dim3(128), 0, stream>>>(t360, partial, tcp);
    k_head<<<dim3(8), blk, 0, stream>>>(partial, tcp, cw1, cb1, cw2, cb2, cw3, cb3, out);
}

// Round 9
// 708.647 us; speedup vs baseline: 7.0707x; 1.1154x over previous
//
#include <hip/hip_runtime.h>
#include <math.h>

#define NB   8
#define NROI 400
#define GG   25
#define EMBD 360
#define HDD  90
#define TBM  1728
#define MTOK 13824      // NB*TBM

typedef __attribute__((ext_vector_type(8)))  _Float16 h8;   // 8 f16 (4 VGPR)
typedef __attribute__((ext_vector_type(4)))  _Float16 h4;
typedef __attribute__((ext_vector_type(16))) float f32x16;

#define MFMA16(a,b,c) __builtin_amdgcn_mfma_f32_32x32x16_f16(a,b,c,0,0,0)
#define QSCALE 0.105409255338945984f   /* 1/sqrt(90) */

__device__ __forceinline__ float gelu_f(float x) {
    return 0.5f * x * (1.0f + erff(x * 0.7071067811865475f));
}

// ---------------------------------------------------------------------------
// Tiled weight convert+transpose: W[K][N] fp32 -> Wt[Np][Kp] f16 (zero-pad).
// blockIdx.z = layer (W += z*Wls, Wt += z*Wtls).
// ---------------------------------------------------------------------------
__global__ __launch_bounds__(256) void k_wconv(
    const float* __restrict__ W, int K, int N,
    _Float16* __restrict__ Wt, int Kp, int Np, int Wls, int Wtls)
{
    W  += (size_t)blockIdx.z * Wls;
    Wt += (size_t)blockIdx.z * Wtls;
    __shared__ float tile[32][33];
    const int k0 = blockIdx.x * 32, n0 = blockIdx.y * 32;
    const int t = threadIdx.x;
    #pragma unroll
    for (int it = 0; it < 4; ++it) {
        int e = t + it * 256;
        int i = e >> 5, j = e & 31;
        tile[j][i] = (k0 + i < K && n0 + j < N) ? W[(size_t)(k0 + i) * N + n0 + j] : 0.0f;
    }
    __syncthreads();
    #pragma unroll
    for (int it = 0; it < 4; ++it) {
        int e = t + it * 256;
        int n = e >> 5, kk = e & 31;
        if (n0 + n < Np && k0 + kk < Kp)
            Wt[(size_t)(n0 + n) * Kp + k0 + kk] = (_Float16)tile[n][kk];
    }
}

// qkv(2x) + wo(2x) + qkv-bias(2x) conversions fused into one flat kernel.
__global__ __launch_bounds__(256) void k_wmisc(
    const float* __restrict__ wqkv, const float* __restrict__ wo,
    const float* __restrict__ bqkv,
    _Float16* __restrict__ qkvc, _Float16* __restrict__ woc,
    float* __restrict__ bqp)
{
    int id = blockIdx.x * 256 + threadIdx.x;
    if (id < 884736) {                       // qkv: Wt[1152][384], n' = sec*384+96h+d
        int l = id / 442368, r = id - l * 442368;
        int np = r / 384, kk = r - np * 384;
        int sec = np / 384, rr = np - sec * 384, h = rr / 96, d = rr - h * 96;
        float v = 0.0f;
        if (d < HDD && kk < 360) v = wqkv[(size_t)l * 388800 + (size_t)kk * 1080 + sec * 360 + h * HDD + d];
        if (sec == 0) v *= QSCALE;
        qkvc[id] = (_Float16)v;
    } else if (id < 1179648) {               // wo: Wt[384][384], k' = 96h+d
        int r2 = id - 884736;
        int l = r2 / 147456, r = r2 - l * 147456;
        int n = r / 384, kp = r - n * 384;
        int h = kp / 96, d = kp - h * 96;
        float v = 0.0f;
        if (d < HDD && n < 360) v = wo[(size_t)l * 129600 + (size_t)(h * HDD + d) * 360 + n];
        woc[r2] = (_Float16)v;
    } else if (id < 1181952) {               // padded qkv bias [1152]
        int r3 = id - 1179648;
        int l = r3 / 1152, r = r3 - l * 1152;
        int sec = r / 384, rr = r - sec * 384, h = rr / 96, d = rr - h * 96;
        float v = 0.0f;
        if (d < HDD) v = bqkv[l * 1080 + sec * 360 + h * HDD + d];
        if (sec == 0) v *= QSCALE;
        if (sec == 2 && d == HDD) v = 1.0f;  // softmax denominator column
        bqp[r3] = v;
    }
}

// ---------------------------------------------------------------------------
// V transpose: qkvh V-section [13824][96 per head] -> vT[bh][96][1728] f16.
// LDS 32x33 tile, coalesced both sides. grid (54, 3, 32).
// ---------------------------------------------------------------------------
__global__ __launch_bounds__(256) void k_vtr(
    const _Float16* __restrict__ qkvh, _Float16* __restrict__ vT)
{
    __shared__ _Float16 tile[32][33];
    const int t = threadIdx.x;
    const int tok0 = blockIdx.x * 32;
    const int d0 = blockIdx.y * 32;
    const int bh = blockIdx.z;              // b*4 + h
    const int b = bh >> 2, h = bh & 3;
    const size_t src = ((size_t)b * TBM + tok0) * 1152 + 768 + 96 * h + d0;
    #pragma unroll
    for (int it = 0; it < 4; ++it) {
        int tl = (t >> 5) + it * 8, dl = t & 31;
        tile[tl][dl] = qkvh[src + (size_t)tl * 1152 + dl];
    }
    __syncthreads();
    const size_t dst = ((size_t)bh * 96 + d0) * TBM + tok0;
    #pragma unroll
    for (int it = 0; it < 4; ++it) {
        int dl = (t >> 5) + it * 8, tl = t & 31;
        vT[dst + (size_t)dl * TBM + tl] = tile[tl][dl];
    }
}

// ---------------------------------------------------------------------------
// MFMA GEMM (f16): C = act(A@B + bias (+res)). 128x128 tile, BK=32, 4 waves.
// AH: A is f16 [M][Kp] (pre-padded); else fp32 [M][K]. OUTH: write f16.
// ---------------------------------------------------------------------------
template <int ACT, bool RES, bool OUTH, bool AH>
__global__ __launch_bounds__(256, 2) void k_mgemm(
    const void* __restrict__ Ap, const _Float16* __restrict__ Bt,
    const float* __restrict__ bias, const float* res, void* Cp,
    int M, int N, int K, int Kp)
{
    __shared__ __align__(16) _Float16 Ah[4096], Bh[4096];
    const int t = threadIdx.x;
    const int lane = t & 63, wid = t >> 6;
    const int half = lane >> 5, l31 = lane & 31;
    const int m0 = blockIdx.y * 128, n0 = blockIdx.x * 128;
    const int wm = (wid >> 1) * 64, wn = (wid & 1) * 64;

    f32x16 acc00 = {}, acc01 = {}, acc10 = {}, acc11 = {};
    const int nk = Kp >> 5;
    const bool k4 = (K & 3) == 0;

    for (int ks = 0; ks < nk; ++ks) {
        const int k0 = ks << 5;
        __syncthreads();
        if (AH) {
            const _Float16* Af = (const _Float16*)Ap;
            #pragma unroll
            for (int i = 0; i < 2; ++i) {
                int e = t + i * 256;
                int row = e >> 2, c = e & 3;
                int gm = m0 + row; if (gm > M - 1) gm = M - 1;
                *(h8*)&Ah[(c * 128 + row) * 8] =
                    *(const h8*)(Af + (size_t)gm * Kp + k0 + c * 8);
            }
        } else {
            const float* A = (const float*)Ap;
            #pragma unroll
            for (int i = 0; i < 4; ++i) {
                int e = t + i * 256;
                int row = e >> 3, c4 = e & 7;
                int gm = m0 + row, kb = k0 + c4 * 4;
                float v0 = 0.f, v1 = 0.f, v2 = 0.f, v3 = 0.f;
                if (gm < M) {
                    const float* ap = A + (size_t)gm * K + kb;
                    if (k4 && kb + 3 < K) {
                        float4 fv = *(const float4*)ap;
                        v0 = fv.x; v1 = fv.y; v2 = fv.z; v3 = fv.w;
                    } else {
                        if (kb + 0 < K) v0 = ap[0];
                        if (kb + 1 < K) v1 = ap[1];
                        if (kb + 2 < K) v2 = ap[2];
                        if (kb + 3 < K) v3 = ap[3];
                    }
                }
                h4 hv = { (_Float16)v0, (_Float16)v1, (_Float16)v2, (_Float16)v3 };
                int c = c4 >> 1, sub = c4 & 1;
                *(h4*)&Ah[(c * 128 + row) * 8 + sub * 4] = hv;
            }
        }
        #pragma unroll
        for (int i = 0; i < 2; ++i) {
            int e = t + i * 256;
            int col = e >> 2, c = e & 3;
            *(h8*)&Bh[(c * 128 + col) * 8] =
                *(const h8*)(Bt + (size_t)(n0 + col) * Kp + k0 + c * 8);
        }
        __syncthreads();
        h8 af[2][2], bf[2][2];
        #pragma unroll
        for (int m2 = 0; m2 < 2; ++m2)
            #pragma unroll
            for (int ku = 0; ku < 2; ++ku) {
                int c = ku * 2 + half;
                af[m2][ku] = *(const h8*)&Ah[(c * 128 + wm + m2 * 32 + l31) * 8];
                bf[m2][ku] = *(const h8*)&Bh[(c * 128 + wn + m2 * 32 + l31) * 8];
            }
        #pragma unroll
        for (int ku = 0; ku < 2; ++ku) {
            acc00 = MFMA16(af[0][ku], bf[0][ku], acc00);
            acc01 = MFMA16(af[0][ku], bf[1][ku], acc01);
            acc10 = MFMA16(af[1][ku], bf[0][ku], acc10);
            acc11 = MFMA16(af[1][ku], bf[1][ku], acc11);
        }
    }
    float* Cf = (float*)Cp;
    _Float16* Ch = (_Float16*)Cp;
    #define EPILOG(ACCV, M2, N2) { \
        int gn = n0 + wn + (N2) * 32 + l31; \
        if (gn < N) { \
            float bv = bias[gn]; \
            _Pragma("unroll") \
            for (int r = 0; r < 16; ++r) { \
                int gm = m0 + wm + (M2) * 32 + (r & 3) + 8 * (r >> 2) + 4 * half; \
                if (gm < M) { \
                    float v = ACCV[r] + bv; \
                    if (RES) v += res[(size_t)gm * N + gn]; \
                    if (ACT == 1) v = gelu_f(v); \
                    if (OUTH) Ch[(size_t)gm * N + gn] = (_Float16)v; \
                    else      Cf[(size_t)gm * N + gn] = v; \
                } } } }
    EPILOG(acc00, 0, 0) EPILOG(acc01, 0, 1) EPILOG(acc10, 1, 0) EPILOG(acc11, 1, 1)
    #undef EPILOG
}

// ---------------------------------------------------------------------------
// Split-K GEMM: A f16 [M][Kp], B f16 [Np][Kp], partial[z] fp32 [MTOK][360].
// ---------------------------------------------------------------------------
__global__ __launch_bounds__(256, 2) void k_skgemm(
    const _Float16* __restrict__ A, const _Float16* __restrict__ Bt,
    float* __restrict__ P, int Kp, int KCH, int nstep)
{
    __shared__ __align__(16) _Float16 Ah[4096], Bh[4096];
    const int t = threadIdx.x;
    const int lane = t & 63, wid = t >> 6;
    const int half = lane >> 5, l31 = lane & 31;
    const int m0 = blockIdx.y * 128, n0 = blockIdx.x * 128;
    const int wm = (wid >> 1) * 64, wn = (wid & 1) * 64;
    const int zb = blockIdx.z * KCH;
    P += (size_t)blockIdx.z * MTOK * EMBD;

    f32x16 acc00 = {}, acc01 = {}, acc10 = {}, acc11 = {};
    for (int ks = 0; ks < nstep; ++ks) {
        const int k0 = zb + (ks << 5);
        __syncthreads();
        #pragma unroll
        for (int i = 0; i < 2; ++i) {
            int e = t + i * 256;
            int row = e >> 2, c = e & 3;
            *(h8*)&Ah[(c * 128 + row) * 8] =
                *(const h8*)(A + (size_t)(m0 + row) * Kp + k0 + c * 8);
        }
        #pragma unroll
        for (int i = 0; i < 2; ++i) {
            int e = t + i * 256;
            int col = e >> 2, c = e & 3;
            *(h8*)&Bh[(c * 128 + col) * 8] =
                *(const h8*)(Bt + (size_t)(n0 + col) * Kp + k0 + c * 8);
        }
        __syncthreads();
        h8 af[2][2], bf[2][2];
        #pragma unroll
        for (int m2 = 0; m2 < 2; ++m2)
            #pragma unroll
            for (int ku = 0; ku < 2; ++ku) {
                int c = ku * 2 + half;
                af[m2][ku] = *(const h8*)&Ah[(c * 128 + wm + m2 * 32 + l31) * 8];
                bf[m2][ku] = *(const h8*)&Bh[(c * 128 + wn + m2 * 32 + l31) * 8];
            }
        #pragma unroll
        for (int ku = 0; ku < 2; ++ku) {
            acc00 = MFMA16(af[0][ku], bf[0][ku], acc00);
            acc01 = MFMA16(af[0][ku], bf[1][ku], acc01);
            acc10 = MFMA16(af[1][ku], bf[0][ku], acc10);
            acc11 = MFMA16(af[1][ku], bf[1][ku], acc11);
        }
    }
    #define EPILOGP(ACCV, M2, N2) { \
        int gn = n0 + wn + (N2) * 32 + l31; \
        if (gn < EMBD) { \
            _Pragma("unroll") \
            for (int r = 0; r < 16; ++r) { \
                int gm = m0 + wm + (M2) * 32 + (r & 3) + 8 * (r >> 2) + 4 * half; \
                P[(size_t)gm * EMBD + gn] = ACCV[r]; \
            } } }
    EPILOGP(acc00, 0, 0) EPILOGP(acc01, 0, 1) EPILOGP(acc10, 1, 0) EPILOGP(acc11, 1, 1)
    #undef EPILOGP
}

// ---------------------------------------------------------------------------
// Flash attention, f16 MFMA. K from qkvh (row-major + XOR swz). V from vT
// (d-major global) staged into Vl[d*64 + ((m ^ (d&7))<<3)] with 16B copies:
// conflict-free writes AND reads (same layout/reads as R8, new producer).
// T14: next K/V tile prefetched to regs under compute. 2 barriers/tile.
// ---------------------------------------------------------------------------
__global__ __launch_bounds__(256, 2) void k_mattn(
    const _Float16* __restrict__ qkv, const _Float16* __restrict__ vT,
    _Float16* __restrict__ aob, const int* __restrict__ tcp)
{
    __shared__ __align__(16) _Float16 Kl[64 * 128];   // [kk][16B chunk ^ (kk&7)]
    __shared__ __align__(16) _Float16 Vl[6144];       // d-major swizzled
    __shared__ __align__(16) _Float16 Pl[4][32 * 64]; // per-wave

    const int t = threadIdx.x;
    const int lane = t & 63, wid = t >> 6;
    const int half = lane >> 5, l31 = lane & 31;
    const int bid = blockIdx.x;
    const int bh = bid & 31, qt = bid >> 5;
    const int h = bh & 3, b = bh >> 2;
    const int Tc = *tcp;
    const int q0w = qt * 128 + wid * 32;
    const size_t base = (size_t)b * TBM * 1152 + 96 * h;
    const _Float16* vTb = vT + (size_t)bh * 96 * TBM;

    // staging geometry: K thread -> (kk, c) of 64x12; V thread -> (d, m) of 96x8
    int skk[3], scc[3], sdd[3], smm[3];
    #pragma unroll
    for (int i = 0; i < 3; ++i) {
        int cid = t + i * 256;
        skk[i] = cid / 12; scc[i] = cid - skk[i] * 12;
        sdd[i] = cid >> 3; smm[i] = cid & 7;
    }

    // Q fragments (96 d, pads zero)
    h8 qf[6];
    {
        int rl = q0w + l31; if (rl > TBM - 1) rl = TBM - 1;
        const _Float16* qrow = qkv + base + (size_t)rl * 1152;
        #pragma unroll
        for (int ku = 0; ku < 6; ++ku)
            qf[ku] = *(const h8*)(qrow + ku * 16 + half * 8);
    }

    f32x16 o0 = {}, o1 = {}, o2 = {};
    int nkt = (Tc + 63) >> 6; if (nkt > 27) nkt = 27;

    // stage tile 0 (all 16B copies)
    if (nkt > 0) {
        #pragma unroll
        for (int i = 0; i < 3; ++i) {
            *(h8*)&Kl[skk[i] * 128 + ((scc[i] ^ (skk[i] & 7)) << 3)] =
                *(const h8*)(qkv + base + (size_t)skk[i] * 1152 + 384 + scc[i] * 8);
            *(h8*)&Vl[sdd[i] * 64 + ((smm[i] ^ (sdd[i] & 7)) << 3)] =
                *(const h8*)(vTb + (size_t)sdd[i] * TBM + smm[i] * 8);
        }
    }
    __syncthreads();

    for (int kt = 0; kt < nkt; ++kt) {
        const int k0 = kt * 64;
        // prefetch next tile into registers (hides under MFMA phase)
        h8 kpre[3], vpre[3];
        const bool pf = (kt + 1 < nkt);
        if (pf) {
            #pragma unroll
            for (int i = 0; i < 3; ++i) {
                kpre[i] = *(const h8*)(qkv + base + (size_t)(k0 + 64 + skk[i]) * 1152 + 384 + scc[i] * 8);
                vpre[i] = *(const h8*)(vTb + (size_t)sdd[i] * TBM + k0 + 64 + smm[i] * 8);
            }
        }
        // S = Q K^T (12 MFMAs)
        f32x16 s0 = {}, s1 = {};
        #pragma unroll
        for (int ku = 0; ku < 6; ++ku) {
            int c = ku * 2 + half;
            int cp = c ^ (l31 & 7);
            h8 kb0 = *(const h8*)&Kl[l31 * 128 + cp * 8];
            h8 kb1 = *(const h8*)&Kl[(32 + l31) * 128 + cp * 8];
            s0 = MFMA16(qf[ku], kb0, s0);
            s1 = MFMA16(qf[ku], kb1, s1);
        }
        // P = exp(S), masked, store f16 to per-wave Pl
        const bool ok0 = (k0 + l31) < Tc;
        const bool ok1 = (k0 + 32 + l31) < Tc;
        const int c0 = l31 >> 3, c1 = 4 + (l31 >> 3), j0 = l31 & 7;
        #pragma unroll
        for (int r = 0; r < 16; ++r) {
            int ql = (r & 3) + 8 * (r >> 2) + 4 * half;
            float p0v = ok0 ? __expf(s0[r]) : 0.0f;
            float p1v = ok1 ? __expf(s1[r]) : 0.0f;
            Pl[wid][ql * 64 + (c0 ^ (ql & 7)) * 8 + j0] = (_Float16)p0v;
            Pl[wid][ql * 64 + (c1 ^ (ql & 7)) * 8 + j0] = (_Float16)p1v;
        }
        asm volatile("s_waitcnt lgkmcnt(0)" ::: "memory");
        __builtin_amdgcn_sched_barrier(0);
        h8 pa[4];
        #pragma unroll
        for (int ku = 0; ku < 4; ++ku) {
            int c = ku * 2 + half;
            pa[ku] = *(const h8*)&Pl[wid][l31 * 64 + (c ^ (l31 & 7)) * 8];
        }
        // PV: 12 single-b128 V fragments (d-major swizzled layout)
        #pragma unroll
        for (int n = 0; n < 3; ++n) {
            f32x16* op = n == 0 ? &o0 : (n == 1 ? &o1 : &o2);
            int d = n * 32 + l31;
            #pragma unroll
            for (int ku = 0; ku < 4; ++ku) {
                int m = ku * 2 + half;
                h8 vb = *(const h8*)&Vl[d * 64 + ((m ^ (d & 7)) << 3)];
                *op = MFMA16(pa[ku], vb, *op);
            }
        }
        __syncthreads();              // all waves done reading Kl/Vl
        if (pf) {
            #pragma unroll
            for (int i = 0; i < 3; ++i) {
                *(h8*)&Kl[skk[i] * 128 + ((scc[i] ^ (skk[i] & 7)) << 3)] = kpre[i];
                *(h8*)&Vl[sdd[i] * 64 + ((smm[i] ^ (sdd[i] & 7)) << 3)] = vpre[i];
            }
        }
        __syncthreads();              // next tile staged
    }

    // normalize by denominator (d=90 -> o2 col 26) and store padded layout
    #pragma unroll
    for (int r = 0; r < 16; ++r) {
        float den = __shfl(o2[r], (lane & 32) | 26);
        float inv = (den > 0.0f) ? 1.0f / den : 0.0f;
        int qg = q0w + (r & 3) + 8 * (r >> 2) + 4 * half;
        if (qg < Tc) {
            _Float16* orow = aob + ((size_t)b * TBM + qg) * 384 + 96 * h;
            orow[l31]      = (_Float16)(o0[r] * inv);
            orow[32 + l31] = (_Float16)(o1[r] * inv);
            orow[64 + l31] = (64 + l31 < HDD) ? (_Float16)(o2[r] * inv) : (_Float16)0.0f;
        }
    }
}

// ---------------------------------------------------------------------------
// Gather + 3^3 sum-pool + |.| mask accumulation (atomic)
// ---------------------------------------------------------------------------
__global__ __launch_bounds__(128) void k_pool(
    const float* __restrict__ F_emb, const int* __restrict__ C,
    float* __restrict__ nodes, float* __restrict__ vsum)
{
    const int tkn = blockIdx.x, b = blockIdx.y;
    const int oz = tkn % 12, oy = (tkn / 12) % 12, ox = tkn / 144;
    __shared__ int idx[27];
    const int tid = threadIdx.x;
    if (tid < 27) {
        int dx = tid / 9, dy = (tid / 3) % 3, dz = tid % 3;
        idx[tid] = C[(((b * GG) + ox * 2 + dx) * GG + oy * 2 + dy) * GG + oz * 2 + dz];
    }
    __syncthreads();
    float a0 = 0.f, a1 = 0.f, a2 = 0.f;
    for (int n = 0; n < 27; ++n) {
        int c = idx[n];
        if (c == 0) continue;
        const float* src = F_emb + (size_t)(b * NROI + (c - 1)) * EMBD;
        a0 += src[tid]; a1 += src[tid + 128];
        if (tid < 104) a2 += src[tid + 256];
    }
    float* dst = nodes + ((size_t)b * TBM + tkn) * EMBD;
    dst[tid] = a0; dst[tid + 128] = a1;
    if (tid < 104) dst[tid + 256] = a2;
    float s = fabsf(a0) + fabsf(a1) + ((tid < 104) ? fabsf(a2) : 0.0f);
    #pragma unroll
    for (int o = 32; o >= 1; o >>= 1) s += __shfl_xor(s, o);
    __shared__ float red[2];
    if ((tid & 63) == 0) red[tid >> 6] = s;
    __syncthreads();
    if (tid == 0) atomicAdd(&vsum[tkn], red[0] + red[1]);
}

__global__ __launch_bounds__(256) void k_scan(
    const float* __restrict__ vsum, int* __restrict__ cidx, int* __restrict__ tcp)
{
    __shared__ int csum[256];
    __shared__ int coff[256];
    const int t = threadIdx.x;
    const int base = t * 7;
    int loc[7]; int s = 0;
    #pragma unroll
    for (int i = 0; i < 7; ++i) {
        int g = base + i;
        int v = (g < TBM) ? (vsum[g] > 0.0f ? 1 : 0) : 0;
        loc[i] = v; s += v;
    }
    csum[t] = s;
    __syncthreads();
    if (t == 0) {
        int a = 0;
        for (int i = 0; i < 256; ++i) { coff[i] = a; a += csum[i]; }
        *tcp = a;
    }
    __syncthreads();
    int off = coff[t];
    #pragma unroll
    for (int i = 0; i < 7; ++i) {
        int g = base + i;
        if (g < TBM && loc[i]) cidx[off++] = g;
    }
}

// compact -> t360 fp32 [.][360] and xh f16 [.][384] (pads zero)
__global__ __launch_bounds__(128) void k_compact(
    const float* __restrict__ nodes, const int* __restrict__ cidx,
    const int* __restrict__ tcp, float* __restrict__ xf, _Float16* __restrict__ xh)
{
    const int j = blockIdx.x, b = blockIdx.y;
    const int Tc = *tcp;
    const size_t row = (size_t)b * TBM + j;
    const float* src = (j < Tc) ? nodes + ((size_t)b * TBM + cidx[j]) * EMBD : nullptr;
    for (int e = threadIdx.x; e < 384; e += 128) {
        float v = (e < EMBD && src) ? src[e] : 0.0f;
        if (e < EMBD) xf[row * EMBD + e] = v;
        xh[row * 384 + e] = (_Float16)v;
    }
}

// ---------------------------------------------------------------------------
// Fused split-K reduce + bias + residual + LayerNorm, one WAVE per row.
// ---------------------------------------------------------------------------
__global__ __launch_bounds__(256) void k_lnr(
    const float* __restrict__ p0, const float* __restrict__ p1,
    const float* __restrict__ bias, const float* res,
    const float* __restrict__ sc, const float* __restrict__ bc,
    float* outf, _Float16* __restrict__ outh)
{
    const int lane = threadIdx.x & 63;
    const int row = blockIdx.x * 4 + (threadIdx.x >> 6);
    const size_t ro = (size_t)row * EMBD;
    const int e0 = lane * 6;
    float x[6] = {0.f, 0.f, 0.f, 0.f, 0.f, 0.f};
    float sum = 0.f;
    if (lane < 60) {
        #pragma unroll
        for (int i = 0; i < 6; ++i) {
            float v = p0[ro + e0 + i] + p1[ro + e0 + i] + bias[e0 + i] + res[ro + e0 + i];
            x[i] = v; sum += v;
        }
    }
    #pragma unroll
    for (int o = 32; o >= 1; o >>= 1) sum += __shfl_xor(sum, o);
    const float mean = sum * (1.0f / 360.0f);
    float vs = 0.f;
    if (lane < 60) {
        #pragma unroll
        for (int i = 0; i < 6; ++i) { float d = x[i] - mean; vs += d * d; }
    }
    #pragma unroll
    for (int o = 32; o >= 1; o >>= 1) vs += __shfl_xor(vs, o);
    const float rs = rsqrtf(vs * (1.0f / 360.0f) + 1e-5f);
    _Float16* hrow = outh + (size_t)row * 384;
    if (lane < 60) {
        #pragma unroll
        for (int i = 0; i < 6; ++i) {
            float v = (x[i] - mean) * rs * sc[e0 + i] + bc[e0 + i];
            outf[ro + e0 + i] = v;
            hrow[e0 + i] = (_Float16)v;
        }
    } else {
        #pragma unroll
        for (int i = 0; i < 6; ++i)
            hrow[360 + (lane - 60) * 6 + i] = (_Float16)0.0f;
    }
}

// ---------------------------------------------------------------------------
// Mean stage 1: partial[chunk][b][e] = sum over tokens in chunk.
// ---------------------------------------------------------------------------
__global__ __launch_bounds__(128) void k_mean2(
    const float* __restrict__ x, float* __restrict__ partial,
    const int* __restrict__ tcp)
{
    const int chunk = blockIdx.x;   // 0..15, 108 tokens each
    const int b = blockIdx.y;
    const int t = threadIdx.x;
    const int Tc = *tcp;
    int j0 = chunk * 108;
    int j1 = j0 + 108; if (j1 > Tc) j1 = Tc;
    const float* xb = x + (size_t)b * TBM * EMBD;
    float a0 = 0.f, a1 = 0.f, a2 = 0.f;
    for (int j = j0; j < j1; ++j) {
        const float* r = xb + (size_t)j * EMBD;
        a0 += r[t]; a1 += r[t + 128];
        if (t < 104) a2 += r[t + 256];
    }
    float* p = partial + ((size_t)chunk * NB + b) * EMBD;
    p[t] = a0; p[t + 128] = a1;
    if (t < 104) p[t + 256] = a2;
}

// Head: one block per batch.
__global__ __launch_bounds__(256) void k_head(
    const float* __restrict__ partial, const int* __restrict__ tcp,
    const float* __restrict__ cw1, const float* __restrict__ cb1,
    const float* __restrict__ cw2, const float* __restrict__ cb2,
    const float* __restrict__ cw3, const float* __restrict__ cb3,
    float* __restrict__ outp)
{
    const int b = blockIdx.x;
    __shared__ float hs[EMBD];
    __shared__ float h1[256];
    __shared__ float h2[128];
    const int t = threadIdx.x;
    int Tc = *tcp; if (Tc < 1) Tc = 1;
    const float inv = 1.0f / (float)Tc;
    for (int e = t; e < EMBD; e += 256) {
        float s = 0.f;
        #pragma unroll
        for (int c = 0; c < 16; ++c) s += partial[(size_t)c * NB * EMBD + b * EMBD + e];
        hs[e] = s * inv;
    }
    __syncthreads();
    {
        float s = cb1[t];
        for (int k = 0; k < EMBD; ++k) s = fmaf(hs[k], cw1[k * 256 + t], s);
        h1[t] = gelu_f(s);
    }
    __syncthreads();
    if (t < 128) {
        float s = cb2[t];
        for (int k = 0; k < 256; ++k) s = fmaf(h1[k], cw2[k * 128 + t], s);
        h2[t] = fmaxf(s, 0.0f);
    }
    __syncthreads();
    if (t < 2) {
        float s = cb3[t];
        for (int k = 0; k < 128; ++k) s = fmaf(h2[k], cw3[k * 2 + t], s);
        outp[b * 2 + t] = s;
    }
}

// ---------------------------------------------------------------------------
extern "C" void kernel_launch(void* const* d_in, const int* in_sizes, int n_in,
                              void* d_out, int out_size, void* d_ws, size_t ws_size,
                              hipStream_t stream)
{
    const float* F_roi  = (const float*)d_in[0];
    const int*   C      = (const int*)d_in[1];
    const float* ffn_w1 = (const float*)d_in[2];
    const float* ffn_b1 = (const float*)d_in[3];
    const float* ffn_w2 = (const float*)d_in[4];
    const float* ffn_b2 = (const float*)d_in[5];
    const float* wqkv   = (const float*)d_in[6];
    const float* bqkv   = (const float*)d_in[7];
    const float* wo     = (const float*)d_in[8];
    const float* bo     = (const float*)d_in[9];
    const float* ln1s   = (const float*)d_in[10];
    const float* ln1b   = (const float*)d_in[11];
    const float* wf1    = (const float*)d_in[12];
    const float* bf1    = (const float*)d_in[13];
    const float* wf2    = (const float*)d_in[14];
    const float* bf2    = (const float*)d_in[15];
    const float* ln2s   = (const float*)d_in[16];
    const float* ln2b   = (const float*)d_in[17];
    const float* cw1    = (const float*)d_in[18];
    const float* cb1    = (const float*)d_in[19];
    const float* cw2    = (const float*)d_in[20];
    const float* cb2    = (const float*)d_in[21];
    const float* cw3    = (const float*)d_in[22];
    const float* cb3    = (const float*)d_in[23];
    float* out = (float*)d_out;

    float* ws = (float*)d_ws;
    _Float16* qkvh = (_Float16*)ws;                   // [13824][1152] f16
    float*    tmp450 = ws;                            // alias
    float*    F_emb  = ws + 1440000;                  // alias
    float*    midf   = ws + 7962624;
    _Float16* midb   = (_Float16*)midf;               // [13824][2048] f16
    float*    nodes  = midf;                          // alias fp32
    _Float16* aob    = (_Float16*)(ws + 22118400);    // [13824][384] f16
    float*    p0     = ws + 24772608;
    float*    p1     = ws + 29749248;
    float*    t360   = ws + 34725888;
    _Float16* xh     = (_Float16*)(ws + 39702528);    // [13824][384] f16
    _Float16* sw     = (_Float16*)(ws + 42356736);

    size_t so = 0;
    auto salloc = [&](size_t n) { _Float16* p = sw + so; so += n; return p; };
    _Float16* w1c  = salloc(262144);           // [512][512]
    _Float16* w2c  = salloc(184320);           // [384][480]
    _Float16* qkvc = salloc(2 * 442368);       // [1152][384] x2
    _Float16* woc  = salloc(2 * 147456);       // [384][384]  x2
    _Float16* f1c  = salloc(2 * 786432);       // [2048][384] x2
    _Float16* f2c  = salloc(2 * 786432);       // [384][2048] x2
    float* partial = ws + 44742656;            // 16 x 8 x 360
    int*   ints    = (int*)(partial + 46080);
    int*   cidx    = ints;                     // 1728
    int*   tcp     = ints + 1728;              // 1
    float* vsumf   = (float*)(ints + 1732);    // 1728
    float* bqp     = vsumf + 1728;             // 2 x 1152
    _Float16* vT   = (_Float16*)(ws + 44800000); // [32][96][1728] f16 (2,654,208 f32)

    dim3 blk(256);

    // Weight conversions
    k_wconv<<<dim3(16, 16, 1), blk, 0, stream>>>(ffn_w1, 512, 450, w1c, 512, 512, 0, 0);
    k_wconv<<<dim3(15, 12, 1), blk, 0, stream>>>(ffn_w2, 450, 360, w2c, 480, 384, 0, 0);
    k_wconv<<<dim3(12, 64, 2), blk, 0, stream>>>(wf1, 360, 2048, f1c, 384, 2048, 360 * 2048, 786432);
    k_wconv<<<dim3(64, 12, 2), blk, 0, stream>>>(wf2, 2048, 360, f2c, 2048, 384, 2048 * 360, 786432);
    k_wmisc<<<dim3(4618), blk, 0, stream>>>(wqkv, wo, bqkv, qkvc, woc, bqp);

    // Node featurization
    hipMemsetAsync(vsumf, 0, TBM * sizeof(float), stream);
    k_mgemm<1, false, false, false><<<dim3(4, 25), blk, 0, stream>>>(F_roi, w1c, ffn_b1, nullptr, tmp450, 3200, 450, 512, 512);
    k_mgemm<0, false, false, false><<<dim3(3, 25), blk, 0, stream>>>(tmp450, w2c, ffn_b2, nullptr, F_emb, 3200, 360, 450, 480);
    k_pool<<<dim3(1728, 8), dim3(128), 0, stream>>>(F_emb, C, nodes, vsumf);
    k_scan<<<dim3(1), blk, 0, stream>>>(vsumf, cidx, tcp);
    k_compact<<<dim3(1728, 8), dim3(128), 0, stream>>>(nodes, cidx, tcp, t360, xh);

    // Transformer layers
    for (int l = 0; l < 2; ++l) {
        k_mgemm<0, false, true, true><<<dim3(9, 108), blk, 0, stream>>>(xh, qkvc + (size_t)l * 442368, bqp + l * 1152, nullptr, qkvh, MTOK, 1152, 360, 384);
        k_vtr<<<dim3(54, 3, 32), blk, 0, stream>>>(qkvh, vT);
        k_mattn<<<dim3(448), blk, 0, stream>>>(qkvh, vT, aob, tcp);
        k_skgemm<<<dim3(3, 108, 2), blk, 0, stream>>>(aob, woc + (size_t)l * 147456, p0, 384, 192, 6);
        k_lnr<<<dim3(MTOK / 4), blk, 0, stream>>>(p0, p1, bo + l * 360, t360, ln1s + l * 360, ln1b + l * 360, t360, xh);
        k_mgemm<1, false, true, true><<<dim3(16, 108), blk, 0, stream>>>(xh, f1c + (size_t)l * 786432, bf1 + l * 2048, nullptr, midb, MTOK, 2048, 360, 384);
        k_skgemm<<<dim3(3, 108, 2), blk, 0, stream>>>(midb, f2c + (size_t)l * 786432, p0, 2048, 1024, 32);
        k_lnr<<<dim3(MTOK / 4), blk, 0, stream>>>(p0, p1, bf2 + l * 360, t360, ln2s + l * 360, ln2b + l * 360, t360, xh);
    }

    // Head
    k_mean2<<<dim3(16, 8), dim3(128), 0, stream>>>(t360, partial, tcp);
    k_head<<<dim3(8), blk, 0, stream>>>(partial, tcp, cw1, cb1, cw2, cb2, cw3, cb3, out);
}

// Round 10
// 680.772 us; speedup vs baseline: 7.3602x; 1.0409x over previous
//
#include <hip/hip_runtime.h>
#include <math.h>

#define NB   8
#define NROI 400
#define GG   25
#define EMBD 360
#define HDD  90
#define TBM  1728
#define MTOK 13824      // NB*TBM

typedef __attribute__((ext_vector_type(8)))  _Float16 h8;   // 8 f16 (4 VGPR)
typedef __attribute__((ext_vector_type(4)))  _Float16 h4;
typedef __attribute__((ext_vector_type(16))) float f32x16;

#define MFMA16(a,b,c) __builtin_amdgcn_mfma_f32_32x32x16_f16(a,b,c,0,0,0)
#define QSCALE 0.105409255338945984f   /* 1/sqrt(90) */

__device__ __forceinline__ float gelu_f(float x) {
    return 0.5f * x * (1.0f + erff(x * 0.7071067811865475f));
}

// ---------------------------------------------------------------------------
// Tiled weight convert+transpose: W[K][N] fp32 -> Wt[Np][Kp] f16 (zero-pad).
// blockIdx.z = layer (W += z*Wls, Wt += z*Wtls).
// ---------------------------------------------------------------------------
__global__ __launch_bounds__(256) void k_wconv(
    const float* __restrict__ W, int K, int N,
    _Float16* __restrict__ Wt, int Kp, int Np, int Wls, int Wtls)
{
    W  += (size_t)blockIdx.z * Wls;
    Wt += (size_t)blockIdx.z * Wtls;
    __shared__ float tile[32][33];
    const int k0 = blockIdx.x * 32, n0 = blockIdx.y * 32;
    const int t = threadIdx.x;
    #pragma unroll
    for (int it = 0; it < 4; ++it) {
        int e = t + it * 256;
        int i = e >> 5, j = e & 31;
        tile[j][i] = (k0 + i < K && n0 + j < N) ? W[(size_t)(k0 + i) * N + n0 + j] : 0.0f;
    }
    __syncthreads();
    #pragma unroll
    for (int it = 0; it < 4; ++it) {
        int e = t + it * 256;
        int n = e >> 5, kk = e & 31;
        if (n0 + n < Np && k0 + kk < Kp)
            Wt[(size_t)(n0 + n) * Kp + k0 + kk] = (_Float16)tile[n][kk];
    }
}

// qkv(2x) + wo(2x) + qkv-bias(2x) conversions fused into one flat kernel.
__global__ __launch_bounds__(256) void k_wmisc(
    const float* __restrict__ wqkv, const float* __restrict__ wo,
    const float* __restrict__ bqkv,
    _Float16* __restrict__ qkvc, _Float16* __restrict__ woc,
    float* __restrict__ bqp)
{
    int id = blockIdx.x * 256 + threadIdx.x;
    if (id < 884736) {                       // qkv: Wt[1152][384], n' = sec*384+96h+d
        int l = id / 442368, r = id - l * 442368;
        int np = r / 384, kk = r - np * 384;
        int sec = np / 384, rr = np - sec * 384, h = rr / 96, d = rr - h * 96;
        float v = 0.0f;
        if (d < HDD && kk < 360) v = wqkv[(size_t)l * 388800 + (size_t)kk * 1080 + sec * 360 + h * HDD + d];
        if (sec == 0) v *= QSCALE;
        qkvc[id] = (_Float16)v;
    } else if (id < 1179648) {               // wo: Wt[384][384], k' = 96h+d
        int r2 = id - 884736;
        int l = r2 / 147456, r = r2 - l * 147456;
        int n = r / 384, kp = r - n * 384;
        int h = kp / 96, d = kp - h * 96;
        float v = 0.0f;
        if (d < HDD && n < 360) v = wo[(size_t)l * 129600 + (size_t)(h * HDD + d) * 360 + n];
        woc[r2] = (_Float16)v;
    } else if (id < 1181952) {               // padded qkv bias [1152]
        int r3 = id - 1179648;
        int l = r3 / 1152, r = r3 - l * 1152;
        int sec = r / 384, rr = r - sec * 384, h = rr / 96, d = rr - h * 96;
        float v = 0.0f;
        if (d < HDD) v = bqkv[l * 1080 + sec * 360 + h * HDD + d];
        if (sec == 0) v *= QSCALE;
        if (sec == 2 && d == HDD) v = 1.0f;  // softmax denominator column
        bqp[r3] = v;
    }
}

// ---------------------------------------------------------------------------
// V transpose: qkvh V-section [13824][96 per head] -> vT[bh][96][1728] f16.
// ---------------------------------------------------------------------------
__global__ __launch_bounds__(256) void k_vtr(
    const _Float16* __restrict__ qkvh, _Float16* __restrict__ vT)
{
    __shared__ _Float16 tile[32][33];
    const int t = threadIdx.x;
    const int tok0 = blockIdx.x * 32;
    const int d0 = blockIdx.y * 32;
    const int bh = blockIdx.z;              // b*4 + h
    const int b = bh >> 2, h = bh & 3;
    const size_t src = ((size_t)b * TBM + tok0) * 1152 + 768 + 96 * h + d0;
    #pragma unroll
    for (int it = 0; it < 4; ++it) {
        int tl = (t >> 5) + it * 8, dl = t & 31;
        tile[tl][dl] = qkvh[src + (size_t)tl * 1152 + dl];
    }
    __syncthreads();
    const size_t dst = ((size_t)bh * 96 + d0) * TBM + tok0;
    #pragma unroll
    for (int it = 0; it < 4; ++it) {
        int dl = (t >> 5) + it * 8, tl = t & 31;
        vT[dst + (size_t)dl * TBM + tl] = tile[tl][dl];
    }
}

// ---------------------------------------------------------------------------
// MFMA GEMM (f16): C = act(A@B + bias (+res)). 128x128 tile, BK=32, 4 waves.
// T14: next k-step's staging loads issued into regs BEFORE ds_write/barriers,
// so global latency hides under the MFMA phase (counted vmcnt at ds_write).
// ---------------------------------------------------------------------------
template <int ACT, bool RES, bool OUTH, bool AH>
__global__ __launch_bounds__(256, 3) void k_mgemm(
    const void* __restrict__ Ap, const _Float16* __restrict__ Bt,
    const float* __restrict__ bias, const float* res, void* Cp,
    int M, int N, int K, int Kp)
{
    __shared__ __align__(16) _Float16 Ah[4096], Bh[4096];
    const int t = threadIdx.x;
    const int lane = t & 63, wid = t >> 6;
    const int half = lane >> 5, l31 = lane & 31;
    const int m0 = blockIdx.y * 128, n0 = blockIdx.x * 128;
    const int wm = (wid >> 1) * 64, wn = (wid & 1) * 64;

    f32x16 acc00 = {}, acc01 = {}, acc10 = {}, acc11 = {};
    const int nk = Kp >> 5;
    const bool k4 = (K & 3) == 0;

    h8 acur[2], anxt[2], bcur[2], bnxt[2];
    float4 fcur[4], fnxt[4];

    const _Float16* Af = (const _Float16*)Ap;
    const float* A = (const float*)Ap;

    auto loadA_h = [&](int k0, h8* dst) {
        #pragma unroll
        for (int i = 0; i < 2; ++i) {
            int e = t + i * 256;
            int row = e >> 2, c = e & 3;
            int gm = m0 + row; if (gm > M - 1) gm = M - 1;
            dst[i] = *(const h8*)(Af + (size_t)gm * Kp + k0 + c * 8);
        }
    };
    auto loadA_f = [&](int k0, float4* dst) {
        #pragma unroll
        for (int i = 0; i < 4; ++i) {
            int e = t + i * 256;
            int row = e >> 3, c4 = e & 7;
            int gm = m0 + row, kb = k0 + c4 * 4;
            float4 fv = {0.f, 0.f, 0.f, 0.f};
            if (gm < M) {
                const float* ap = A + (size_t)gm * K + kb;
                if (k4 && kb + 3 < K) {
                    fv = *(const float4*)ap;
                } else {
                    if (kb + 0 < K) fv.x = ap[0];
                    if (kb + 1 < K) fv.y = ap[1];
                    if (kb + 2 < K) fv.z = ap[2];
                    if (kb + 3 < K) fv.w = ap[3];
                }
            }
            dst[i] = fv;
        }
    };
    auto loadB = [&](int k0, h8* dst) {
        #pragma unroll
        for (int i = 0; i < 2; ++i) {
            int e = t + i * 256;
            int col = e >> 2, c = e & 3;
            dst[i] = *(const h8*)(Bt + (size_t)(n0 + col) * Kp + k0 + c * 8);
        }
    };

    if (AH) loadA_h(0, acur); else loadA_f(0, fcur);
    loadB(0, bcur);

    for (int ks = 0; ks < nk; ++ks) {
        const bool pf = (ks + 1 < nk);
        if (pf) {
            if (AH) loadA_h((ks + 1) << 5, anxt); else loadA_f((ks + 1) << 5, fnxt);
            loadB((ks + 1) << 5, bnxt);
        }
        __syncthreads();   // previous iteration's LDS readers done
        if (AH) {
            #pragma unroll
            for (int i = 0; i < 2; ++i) {
                int e = t + i * 256;
                int row = e >> 2, c = e & 3;
                *(h8*)&Ah[(c * 128 + row) * 8] = acur[i];
            }
        } else {
            #pragma unroll
            for (int i = 0; i < 4; ++i) {
                int e = t + i * 256;
                int row = e >> 3, c4 = e & 7;
                float4 fv = fcur[i];
                h4 hv = { (_Float16)fv.x, (_Float16)fv.y, (_Float16)fv.z, (_Float16)fv.w };
                int c = c4 >> 1, sub = c4 & 1;
                *(h4*)&Ah[(c * 128 + row) * 8 + sub * 4] = hv;
            }
        }
        #pragma unroll
        for (int i = 0; i < 2; ++i) {
            int e = t + i * 256;
            int col = e >> 2, c = e & 3;
            *(h8*)&Bh[(c * 128 + col) * 8] = bcur[i];
        }
        __syncthreads();
        h8 af[2][2], bf[2][2];
        #pragma unroll
        for (int m2 = 0; m2 < 2; ++m2)
            #pragma unroll
            for (int ku = 0; ku < 2; ++ku) {
                int c = ku * 2 + half;
                af[m2][ku] = *(const h8*)&Ah[(c * 128 + wm + m2 * 32 + l31) * 8];
                bf[m2][ku] = *(const h8*)&Bh[(c * 128 + wn + m2 * 32 + l31) * 8];
            }
        #pragma unroll
        for (int ku = 0; ku < 2; ++ku) {
            acc00 = MFMA16(af[0][ku], bf[0][ku], acc00);
            acc01 = MFMA16(af[0][ku], bf[1][ku], acc01);
            acc10 = MFMA16(af[1][ku], bf[0][ku], acc10);
            acc11 = MFMA16(af[1][ku], bf[1][ku], acc11);
        }
        if (pf) {
            if (AH) { acur[0] = anxt[0]; acur[1] = anxt[1]; }
            else    { fcur[0] = fnxt[0]; fcur[1] = fnxt[1]; fcur[2] = fnxt[2]; fcur[3] = fnxt[3]; }
            bcur[0] = bnxt[0]; bcur[1] = bnxt[1];
        }
    }
    float* Cf = (float*)Cp;
    _Float16* Ch = (_Float16*)Cp;
    #define EPILOG(ACCV, M2, N2) { \
        int gn = n0 + wn + (N2) * 32 + l31; \
        if (gn < N) { \
            float bv = bias[gn]; \
            _Pragma("unroll") \
            for (int r = 0; r < 16; ++r) { \
                int gm = m0 + wm + (M2) * 32 + (r & 3) + 8 * (r >> 2) + 4 * half; \
                if (gm < M) { \
                    float v = ACCV[r] + bv; \
                    if (RES) v += res[(size_t)gm * N + gn]; \
                    if (ACT == 1) v = gelu_f(v); \
                    if (OUTH) Ch[(size_t)gm * N + gn] = (_Float16)v; \
                    else      Cf[(size_t)gm * N + gn] = v; \
                } } } }
    EPILOG(acc00, 0, 0) EPILOG(acc01, 0, 1) EPILOG(acc10, 1, 0) EPILOG(acc11, 1, 1)
    #undef EPILOG
}

// ---------------------------------------------------------------------------
// Split-K GEMM with the same T14 prefetch: A f16 [M][Kp], B f16 [Np][Kp],
// partial[z] fp32 [MTOK][360]. blockIdx.z = chunk; length KCH, nstep = KCH/32.
// ---------------------------------------------------------------------------
__global__ __launch_bounds__(256, 3) void k_skgemm(
    const _Float16* __restrict__ A, const _Float16* __restrict__ Bt,
    float* __restrict__ P, int Kp, int KCH, int nstep)
{
    __shared__ __align__(16) _Float16 Ah[4096], Bh[4096];
    const int t = threadIdx.x;
    const int lane = t & 63, wid = t >> 6;
    const int half = lane >> 5, l31 = lane & 31;
    const int m0 = blockIdx.y * 128, n0 = blockIdx.x * 128;
    const int wm = (wid >> 1) * 64, wn = (wid & 1) * 64;
    const int zb = blockIdx.z * KCH;
    P += (size_t)blockIdx.z * MTOK * EMBD;

    f32x16 acc00 = {}, acc01 = {}, acc10 = {}, acc11 = {};

    h8 acur[2], anxt[2], bcur[2], bnxt[2];
    auto loadA = [&](int k0, h8* dst) {
        #pragma unroll
        for (int i = 0; i < 2; ++i) {
            int e = t + i * 256;
            int row = e >> 2, c = e & 3;
            dst[i] = *(const h8*)(A + (size_t)(m0 + row) * Kp + k0 + c * 8);
        }
    };
    auto loadB = [&](int k0, h8* dst) {
        #pragma unroll
        for (int i = 0; i < 2; ++i) {
            int e = t + i * 256;
            int col = e >> 2, c = e & 3;
            dst[i] = *(const h8*)(Bt + (size_t)(n0 + col) * Kp + k0 + c * 8);
        }
    };

    loadA(zb, acur); loadB(zb, bcur);

    for (int ks = 0; ks < nstep; ++ks) {
        const bool pf = (ks + 1 < nstep);
        if (pf) { loadA(zb + ((ks + 1) << 5), anxt); loadB(zb + ((ks + 1) << 5), bnxt); }
        __syncthreads();
        #pragma unroll
        for (int i = 0; i < 2; ++i) {
            int e = t + i * 256;
            int row = e >> 2, c = e & 3;
            *(h8*)&Ah[(c * 128 + row) * 8] = acur[i];
        }
        #pragma unroll
        for (int i = 0; i < 2; ++i) {
            int e = t + i * 256;
            int col = e >> 2, c = e & 3;
            *(h8*)&Bh[(c * 128 + col) * 8] = bcur[i];
        }
        __syncthreads();
        h8 af[2][2], bf[2][2];
        #pragma unroll
        for (int m2 = 0; m2 < 2; ++m2)
            #pragma unroll
            for (int ku = 0; ku < 2; ++ku) {
                int c = ku * 2 + half;
                af[m2][ku] = *(const h8*)&Ah[(c * 128 + wm + m2 * 32 + l31) * 8];
                bf[m2][ku] = *(const h8*)&Bh[(c * 128 + wn + m2 * 32 + l31) * 8];
            }
        #pragma unroll
        for (int ku = 0; ku < 2; ++ku) {
            acc00 = MFMA16(af[0][ku], bf[0][ku], acc00);
            acc01 = MFMA16(af[0][ku], bf[1][ku], acc01);
            acc10 = MFMA16(af[1][ku], bf[0][ku], acc10);
            acc11 = MFMA16(af[1][ku], bf[1][ku], acc11);
        }
        if (pf) { acur[0] = anxt[0]; acur[1] = anxt[1]; bcur[0] = bnxt[0]; bcur[1] = bnxt[1]; }
    }
    #define EPILOGP(ACCV, M2, N2) { \
        int gn = n0 + wn + (N2) * 32 + l31; \
        if (gn < EMBD) { \
            _Pragma("unroll") \
            for (int r = 0; r < 16; ++r) { \
                int gm = m0 + wm + (M2) * 32 + (r & 3) + 8 * (r >> 2) + 4 * half; \
                P[(size_t)gm * EMBD + gn] = ACCV[r]; \
            } } }
    EPILOGP(acc00, 0, 0) EPILOGP(acc01, 0, 1) EPILOGP(acc10, 1, 0) EPILOGP(acc11, 1, 1)
    #undef EPILOGP
}

// ---------------------------------------------------------------------------
// Flash attention, f16 MFMA. Unchanged from R9 (verified).
// ---------------------------------------------------------------------------
__global__ __launch_bounds__(256, 2) void k_mattn(
    const _Float16* __restrict__ qkv, const _Float16* __restrict__ vT,
    _Float16* __restrict__ aob, const int* __restrict__ tcp)
{
    __shared__ __align__(16) _Float16 Kl[64 * 128];   // [kk][16B chunk ^ (kk&7)]
    __shared__ __align__(16) _Float16 Vl[6144];       // d-major swizzled
    __shared__ __align__(16) _Float16 Pl[4][32 * 64]; // per-wave

    const int t = threadIdx.x;
    const int lane = t & 63, wid = t >> 6;
    const int half = lane >> 5, l31 = lane & 31;
    const int bid = blockIdx.x;
    const int bh = bid & 31, qt = bid >> 5;
    const int h = bh & 3, b = bh >> 2;
    const int Tc = *tcp;
    const int q0w = qt * 128 + wid * 32;
    const size_t base = (size_t)b * TBM * 1152 + 96 * h;
    const _Float16* vTb = vT + (size_t)bh * 96 * TBM;

    int skk[3], scc[3], sdd[3], smm[3];
    #pragma unroll
    for (int i = 0; i < 3; ++i) {
        int cid = t + i * 256;
        skk[i] = cid / 12; scc[i] = cid - skk[i] * 12;
        sdd[i] = cid >> 3; smm[i] = cid & 7;
    }

    h8 qf[6];
    {
        int rl = q0w + l31; if (rl > TBM - 1) rl = TBM - 1;
        const _Float16* qrow = qkv + base + (size_t)rl * 1152;
        #pragma unroll
        for (int ku = 0; ku < 6; ++ku)
            qf[ku] = *(const h8*)(qrow + ku * 16 + half * 8);
    }

    f32x16 o0 = {}, o1 = {}, o2 = {};
    int nkt = (Tc + 63) >> 6; if (nkt > 27) nkt = 27;

    if (nkt > 0) {
        #pragma unroll
        for (int i = 0; i < 3; ++i) {
            *(h8*)&Kl[skk[i] * 128 + ((scc[i] ^ (skk[i] & 7)) << 3)] =
                *(const h8*)(qkv + base + (size_t)skk[i] * 1152 + 384 + scc[i] * 8);
            *(h8*)&Vl[sdd[i] * 64 + ((smm[i] ^ (sdd[i] & 7)) << 3)] =
                *(const h8*)(vTb + (size_t)sdd[i] * TBM + smm[i] * 8);
        }
    }
    __syncthreads();

    for (int kt = 0; kt < nkt; ++kt) {
        const int k0 = kt * 64;
        h8 kpre[3], vpre[3];
        const bool pf = (kt + 1 < nkt);
        if (pf) {
            #pragma unroll
            for (int i = 0; i < 3; ++i) {
                kpre[i] = *(const h8*)(qkv + base + (size_t)(k0 + 64 + skk[i]) * 1152 + 384 + scc[i] * 8);
                vpre[i] = *(const h8*)(vTb + (size_t)sdd[i] * TBM + k0 + 64 + smm[i] * 8);
            }
        }
        f32x16 s0 = {}, s1 = {};
        #pragma unroll
        for (int ku = 0; ku < 6; ++ku) {
            int c = ku * 2 + half;
            int cp = c ^ (l31 & 7);
            h8 kb0 = *(const h8*)&Kl[l31 * 128 + cp * 8];
            h8 kb1 = *(const h8*)&Kl[(32 + l31) * 128 + cp * 8];
            s0 = MFMA16(qf[ku], kb0, s0);
            s1 = MFMA16(qf[ku], kb1, s1);
        }
        const bool ok0 = (k0 + l31) < Tc;
        const bool ok1 = (k0 + 32 + l31) < Tc;
        const int c0 = l31 >> 3, c1 = 4 + (l31 >> 3), j0 = l31 & 7;
        #pragma unroll
        for (int r = 0; r < 16; ++r) {
            int ql = (r & 3) + 8 * (r >> 2) + 4 * half;
            float p0v = ok0 ? __expf(s0[r]) : 0.0f;
            float p1v = ok1 ? __expf(s1[r]) : 0.0f;
            Pl[wid][ql * 64 + (c0 ^ (ql & 7)) * 8 + j0] = (_Float16)p0v;
            Pl[wid][ql * 64 + (c1 ^ (ql & 7)) * 8 + j0] = (_Float16)p1v;
        }
        asm volatile("s_waitcnt lgkmcnt(0)" ::: "memory");
        __builtin_amdgcn_sched_barrier(0);
        h8 pa[4];
        #pragma unroll
        for (int ku = 0; ku < 4; ++ku) {
            int c = ku * 2 + half;
            pa[ku] = *(const h8*)&Pl[wid][l31 * 64 + (c ^ (l31 & 7)) * 8];
        }
        #pragma unroll
        for (int n = 0; n < 3; ++n) {
            f32x16* op = n == 0 ? &o0 : (n == 1 ? &o1 : &o2);
            int d = n * 32 + l31;
            #pragma unroll
            for (int ku = 0; ku < 4; ++ku) {
                int m = ku * 2 + half;
                h8 vb = *(const h8*)&Vl[d * 64 + ((m ^ (d & 7)) << 3)];
                *op = MFMA16(pa[ku], vb, *op);
            }
        }
        __syncthreads();
        if (pf) {
            #pragma unroll
            for (int i = 0; i < 3; ++i) {
                *(h8*)&Kl[skk[i] * 128 + ((scc[i] ^ (skk[i] & 7)) << 3)] = kpre[i];
                *(h8*)&Vl[sdd[i] * 64 + ((smm[i] ^ (sdd[i] & 7)) << 3)] = vpre[i];
            }
        }
        __syncthreads();
    }

    #pragma unroll
    for (int r = 0; r < 16; ++r) {
        float den = __shfl(o2[r], (lane & 32) | 26);
        float inv = (den > 0.0f) ? 1.0f / den : 0.0f;
        int qg = q0w + (r & 3) + 8 * (r >> 2) + 4 * half;
        if (qg < Tc) {
            _Float16* orow = aob + ((size_t)b * TBM + qg) * 384 + 96 * h;
            orow[l31]      = (_Float16)(o0[r] * inv);
            orow[32 + l31] = (_Float16)(o1[r] * inv);
            orow[64 + l31] = (64 + l31 < HDD) ? (_Float16)(o2[r] * inv) : (_Float16)0.0f;
        }
    }
}

// ---------------------------------------------------------------------------
// Gather + 3^3 sum-pool + |.| mask accumulation (atomic)
// ---------------------------------------------------------------------------
__global__ __launch_bounds__(128) void k_pool(
    const float* __restrict__ F_emb, const int* __restrict__ C,
    float* __restrict__ nodes, float* __restrict__ vsum)
{
    const int tkn = blockIdx.x, b = blockIdx.y;
    const int oz = tkn % 12, oy = (tkn / 12) % 12, ox = tkn / 144;
    __shared__ int idx[27];
    const int tid = threadIdx.x;
    if (tid < 27) {
        int dx = tid / 9, dy = (tid / 3) % 3, dz = tid % 3;
        idx[tid] = C[(((b * GG) + ox * 2 + dx) * GG + oy * 2 + dy) * GG + oz * 2 + dz];
    }
    __syncthreads();
    float a0 = 0.f, a1 = 0.f, a2 = 0.f;
    for (int n = 0; n < 27; ++n) {
        int c = idx[n];
        if (c == 0) continue;
        const float* src = F_emb + (size_t)(b * NROI + (c - 1)) * EMBD;
        a0 += src[tid]; a1 += src[tid + 128];
        if (tid < 104) a2 += src[tid + 256];
    }
    float* dst = nodes + ((size_t)b * TBM + tkn) * EMBD;
    dst[tid] = a0; dst[tid + 128] = a1;
    if (tid < 104) dst[tid + 256] = a2;
    float s = fabsf(a0) + fabsf(a1) + ((tid < 104) ? fabsf(a2) : 0.0f);
    #pragma unroll
    for (int o = 32; o >= 1; o >>= 1) s += __shfl_xor(s, o);
    __shared__ float red[2];
    if ((tid & 63) == 0) red[tid >> 6] = s;
    __syncthreads();
    if (tid == 0) atomicAdd(&vsum[tkn], red[0] + red[1]);
}

__global__ __launch_bounds__(256) void k_scan(
    const float* __restrict__ vsum, int* __restrict__ cidx, int* __restrict__ tcp)
{
    __shared__ int csum[256];
    __shared__ int coff[256];
    const int t = threadIdx.x;
    const int base = t * 7;
    int loc[7]; int s = 0;
    #pragma unroll
    for (int i = 0; i < 7; ++i) {
        int g = base + i;
        int v = (g < TBM) ? (vsum[g] > 0.0f ? 1 : 0) : 0;
        loc[i] = v; s += v;
    }
    csum[t] = s;
    __syncthreads();
    if (t == 0) {
        int a = 0;
        for (int i = 0; i < 256; ++i) { coff[i] = a; a += csum[i]; }
        *tcp = a;
    }
    __syncthreads();
    int off = coff[t];
    #pragma unroll
    for (int i = 0; i < 7; ++i) {
        int g = base + i;
        if (g < TBM && loc[i]) cidx[off++] = g;
    }
}

// compact -> t360 fp32 [.][360] and xh f16 [.][384] (pads zero)
__global__ __launch_bounds__(128) void k_compact(
    const float* __restrict__ nodes, const int* __restrict__ cidx,
    const int* __restrict__ tcp, float* __restrict__ xf, _Float16* __restrict__ xh)
{
    const int j = blockIdx.x, b = blockIdx.y;
    const int Tc = *tcp;
    const size_t row = (size_t)b * TBM + j;
    const float* src = (j < Tc) ? nodes + ((size_t)b * TBM + cidx[j]) * EMBD : nullptr;
    for (int e = threadIdx.x; e < 384; e += 128) {
        float v = (e < EMBD && src) ? src[e] : 0.0f;
        if (e < EMBD) xf[row * EMBD + e] = v;
        xh[row * 384 + e] = (_Float16)v;
    }
}

// ---------------------------------------------------------------------------
// Fused split-K reduce + bias + residual + LayerNorm, one WAVE per row.
// ---------------------------------------------------------------------------
__global__ __launch_bounds__(256) void k_lnr(
    const float* __restrict__ p0, const float* __restrict__ p1,
    const float* __restrict__ bias, const float* res,
    const float* __restrict__ sc, const float* __restrict__ bc,
    float* outf, _Float16* __restrict__ outh)
{
    const int lane = threadIdx.x & 63;
    const int row = blockIdx.x * 4 + (threadIdx.x >> 6);
    const size_t ro = (size_t)row * EMBD;
    const int e0 = lane * 6;
    float x[6] = {0.f, 0.f, 0.f, 0.f, 0.f, 0.f};
    float sum = 0.f;
    if (lane < 60) {
        #pragma unroll
        for (int i = 0; i < 6; ++i) {
            float v = p0[ro + e0 + i] + p1[ro + e0 + i] + bias[e0 + i] + res[ro + e0 + i];
            x[i] = v; sum += v;
        }
    }
    #pragma unroll
    for (int o = 32; o >= 1; o >>= 1) sum += __shfl_xor(sum, o);
    const float mean = sum * (1.0f / 360.0f);
    float vs = 0.f;
    if (lane < 60) {
        #pragma unroll
        for (int i = 0; i < 6; ++i) { float d = x[i] - mean; vs += d * d; }
    }
    #pragma unroll
    for (int o = 32; o >= 1; o >>= 1) vs += __shfl_xor(vs, o);
    const float rs = rsqrtf(vs * (1.0f / 360.0f) + 1e-5f);
    _Float16* hrow = outh + (size_t)row * 384;
    if (lane < 60) {
        #pragma unroll
        for (int i = 0; i < 6; ++i) {
            float v = (x[i] - mean) * rs * sc[e0 + i] + bc[e0 + i];
            outf[ro + e0 + i] = v;
            hrow[e0 + i] = (_Float16)v;
        }
    } else {
        #pragma unroll
        for (int i = 0; i < 6; ++i)
            hrow[360 + (lane - 60) * 6 + i] = (_Float16)0.0f;
    }
}

// ---------------------------------------------------------------------------
// Mean stage 1: partial[chunk][b][e] = sum over tokens in chunk.
// ---------------------------------------------------------------------------
__global__ __launch_bounds__(128) void k_mean2(
    const float* __restrict__ x, float* __restrict__ partial,
    const int* __restrict__ tcp)
{
    const int chunk = blockIdx.x;   // 0..15, 108 tokens each
    const int b = blockIdx.y;
    const int t = threadIdx.x;
    const int Tc = *tcp;
    int j0 = chunk * 108;
    int j1 = j0 + 108; if (j1 > Tc) j1 = Tc;
    const float* xb = x + (size_t)b * TBM * EMBD;
    float a0 = 0.f, a1 = 0.f, a2 = 0.f;
    for (int j = j0; j < j1; ++j) {
        const float* r = xb + (size_t)j * EMBD;
        a0 += r[t]; a1 += r[t + 128];
        if (t < 104) a2 += r[t + 256];
    }
    float* p = partial + ((size_t)chunk * NB + b) * EMBD;
    p[t] = a0; p[t + 128] = a1;
    if (t < 104) p[t + 256] = a2;
}

// Head: one block per batch.
__global__ __launch_bounds__(256) void k_head(
    const float* __restrict__ partial, const int* __restrict__ tcp,
    const float* __restrict__ cw1, const float* __restrict__ cb1,
    const float* __restrict__ cw2, const float* __restrict__ cb2,
    const float* __restrict__ cw3, const float* __restrict__ cb3,
    float* __restrict__ outp)
{
    const int b = blockIdx.x;
    __shared__ float hs[EMBD];
    __shared__ float h1[256];
    __shared__ float h2[128];
    const int t = threadIdx.x;
    int Tc = *tcp; if (Tc < 1) Tc = 1;
    const float inv = 1.0f / (float)Tc;
    for (int e = t; e < EMBD; e += 256) {
        float s = 0.f;
        #pragma unroll
        for (int c = 0; c < 16; ++c) s += partial[(size_t)c * NB * EMBD + b * EMBD + e];
        hs[e] = s * inv;
    }
    __syncthreads();
    {
        float s = cb1[t];
        for (int k = 0; k < EMBD; ++k) s = fmaf(hs[k], cw1[k * 256 + t], s);
        h1[t] = gelu_f(s);
    }
    __syncthreads();
    if (t < 128) {
        float s = cb2[t];
        for (int k = 0; k < 256; ++k) s = fmaf(h1[k], cw2[k * 128 + t], s);
        h2[t] = fmaxf(s, 0.0f);
    }
    __syncthreads();
    if (t < 2) {
        float s = cb3[t];
        for (int k = 0; k < 128; ++k) s = fmaf(h2[k], cw3[k * 2 + t], s);
        outp[b * 2 + t] = s;
    }
}

// ---------------------------------------------------------------------------
extern "C" void kernel_launch(void* const* d_in, const int* in_sizes, int n_in,
                              void* d_out, int out_size, void* d_ws, size_t ws_size,
                              hipStream_t stream)
{
    const float* F_roi  = (const float*)d_in[0];
    const int*   C      = (const int*)d_in[1];
    const float* ffn_w1 = (const float*)d_in[2];
    const float* ffn_b1 = (const float*)d_in[3];
    const float* ffn_w2 = (const float*)d_in[4];
    const float* ffn_b2 = (const float*)d_in[5];
    const float* wqkv   = (const float*)d_in[6];
    const float* bqkv   = (const float*)d_in[7];
    const float* wo     = (const float*)d_in[8];
    const float* bo     = (const float*)d_in[9];
    const float* ln1s   = (const float*)d_in[10];
    const float* ln1b   = (const float*)d_in[11];
    const float* wf1    = (const float*)d_in[12];
    const float* bf1    = (const float*)d_in[13];
    const float* wf2    = (const float*)d_in[14];
    const float* bf2    = (const float*)d_in[15];
    const float* ln2s   = (const float*)d_in[16];
    const float* ln2b   = (const float*)d_in[17];
    const float* cw1    = (const float*)d_in[18];
    const float* cb1    = (const float*)d_in[19];
    const float* cw2    = (const float*)d_in[20];
    const float* cb2    = (const float*)d_in[21];
    const float* cw3    = (const float*)d_in[22];
    const float* cb3    = (const float*)d_in[23];
    float* out = (float*)d_out;

    float* ws = (float*)d_ws;
    _Float16* qkvh = (_Float16*)ws;                   // [13824][1152] f16
    float*    tmp450 = ws;                            // alias
    float*    F_emb  = ws + 1440000;                  // alias
    float*    midf   = ws + 7962624;
    _Float16* midb   = (_Float16*)midf;               // [13824][2048] f16
    float*    nodes  = midf;                          // alias fp32
    _Float16* aob    = (_Float16*)(ws + 22118400);    // [13824][384] f16
    float*    p0     = ws + 24772608;
    float*    p1     = ws + 29749248;
    float*    t360   = ws + 34725888;
    _Float16* xh     = (_Float16*)(ws + 39702528);    // [13824][384] f16
    _Float16* sw     = (_Float16*)(ws + 42356736);

    size_t so = 0;
    auto salloc = [&](size_t n) { _Float16* p = sw + so; so += n; return p; };
    _Float16* w1c  = salloc(262144);           // [512][512]
    _Float16* w2c  = salloc(184320);           // [384][480]
    _Float16* qkvc = salloc(2 * 442368);       // [1152][384] x2
    _Float16* woc  = salloc(2 * 147456);       // [384][384]  x2
    _Float16* f1c  = salloc(2 * 786432);       // [2048][384] x2
    _Float16* f2c  = salloc(2 * 786432);       // [384][2048] x2
    float* partial = ws + 44742656;            // 16 x 8 x 360
    int*   ints    = (int*)(partial + 46080);
    int*   cidx    = ints;                     // 1728
    int*   tcp     = ints + 1728;              // 1
    float* vsumf   = (float*)(ints + 1732);    // 1728
    float* bqp     = vsumf + 1728;             // 2 x 1152
    _Float16* vT   = (_Float16*)(ws + 44800000); // [32][96][1728] f16

    dim3 blk(256);

    // Weight conversions
    k_wconv<<<dim3(16, 16, 1), blk, 0, stream>>>(ffn_w1, 512, 450, w1c, 512, 512, 0, 0);
    k_wconv<<<dim3(15, 12, 1), blk, 0, stream>>>(ffn_w2, 450, 360, w2c, 480, 384, 0, 0);
    k_wconv<<<dim3(12, 64, 2), blk, 0, stream>>>(wf1, 360, 2048, f1c, 384, 2048, 360 * 2048, 786432);
    k_wconv<<<dim3(64, 12, 2), blk, 0, stream>>>(wf2, 2048, 360, f2c, 2048, 384, 2048 * 360, 786432);
    k_wmisc<<<dim3(4618), blk, 0, stream>>>(wqkv, wo, bqkv, qkvc, woc, bqp);

    // Node featurization
    hipMemsetAsync(vsumf, 0, TBM * sizeof(float), stream);
    k_mgemm<1, false, false, false><<<dim3(4, 25), blk, 0, stream>>>(F_roi, w1c, ffn_b1, nullptr, tmp450, 3200, 450, 512, 512);
    k_mgemm<0, false, false, false><<<dim3(3, 25), blk, 0, stream>>>(tmp450, w2c, ffn_b2, nullptr, F_emb, 3200, 360, 450, 480);
    k_pool<<<dim3(1728, 8), dim3(128), 0, stream>>>(F_emb, C, nodes, vsumf);
    k_scan<<<dim3(1), blk, 0, stream>>>(vsumf, cidx, tcp);
    k_compact<<<dim3(1728, 8), dim3(128), 0, stream>>>(nodes, cidx, tcp, t360, xh);

    // Transformer layers
    for (int l = 0; l < 2; ++l) {
        k_mgemm<0, false, true, true><<<dim3(9, 108), blk, 0, stream>>>(xh, qkvc + (size_t)l * 442368, bqp + l * 1152, nullptr, qkvh, MTOK, 1152, 360, 384);
        k_vtr<<<dim3(54, 3, 32), blk, 0, stream>>>(qkvh, vT);
        k_mattn<<<dim3(448), blk, 0, stream>>>(qkvh, vT, aob, tcp);
        k_skgemm<<<dim3(3, 108, 2), blk, 0, stream>>>(aob, woc + (size_t)l * 147456, p0, 384, 192, 6);
        k_lnr<<<dim3(MTOK / 4), blk, 0, stream>>>(p0, p1, bo + l * 360, t360, ln1s + l * 360, ln1b + l * 360, t360, xh);
        k_mgemm<1, false, true, true><<<dim3(16, 108), blk, 0, stream>>>(xh, f1c + (size_t)l * 786432, bf1 + l * 2048, nullptr, midb, MTOK, 2048, 360, 384);
        k_skgemm<<<dim3(3, 108, 2), blk, 0, stream>>>(midb, f2c + (size_t)l * 786432, p0, 2048, 1024, 32);
        k_lnr<<<dim3(MTOK / 4), blk, 0, stream>>>(p0, p1, bf2 + l * 360, t360, ln2s + l * 360, ln2b + l * 360, t360, xh);
    }

    // Head
    k_mean2<<<dim3(16, 8), dim3(128), 0, stream>>>(t360, partial, tcp);
    k_head<<<dim3(8), blk, 0, stream>>>(partial, tcp, cw1, cb1, cw2, cb2, cw3, cb3, out);
}

// Round 12
// 666.608 us; speedup vs baseline: 7.5166x; 1.0212x over previous
//
#include <hip/hip_runtime.h>
#include <math.h>

#define NB   8
#define NROI 400
#define GG   25
#define EMBD 360
#define HDD  90
#define TBM  1728
#define MTOK 13824      // NB*TBM

typedef __attribute__((ext_vector_type(8)))  _Float16 h8;   // 8 f16 (4 VGPR)
typedef __attribute__((ext_vector_type(4)))  _Float16 h4;
typedef __attribute__((ext_vector_type(16))) float f32x16;
typedef __attribute__((ext_vector_type(4)))  unsigned u32x4;

#define MFMA16(a,b,c) __builtin_amdgcn_mfma_f32_32x32x16_f16(a,b,c,0,0,0)
#define QSCALE 0.105409255338945984f   /* 1/sqrt(90) */

__device__ __forceinline__ float gelu_f(float x) {
    return 0.5f * x * (1.0f + erff(x * 0.7071067811865475f));
}

// ---------------------------------------------------------------------------
// Tiled weight convert+transpose: W[K][N] fp32 -> Wt[Np][Kp] f16 (zero-pad).
// ---------------------------------------------------------------------------
__global__ __launch_bounds__(256) void k_wconv(
    const float* __restrict__ W, int K, int N,
    _Float16* __restrict__ Wt, int Kp, int Np, int Wls, int Wtls)
{
    W  += (size_t)blockIdx.z * Wls;
    Wt += (size_t)blockIdx.z * Wtls;
    __shared__ float tile[32][33];
    const int k0 = blockIdx.x * 32, n0 = blockIdx.y * 32;
    const int t = threadIdx.x;
    #pragma unroll
    for (int it = 0; it < 4; ++it) {
        int e = t + it * 256;
        int i = e >> 5, j = e & 31;
        tile[j][i] = (k0 + i < K && n0 + j < N) ? W[(size_t)(k0 + i) * N + n0 + j] : 0.0f;
    }
    __syncthreads();
    #pragma unroll
    for (int it = 0; it < 4; ++it) {
        int e = t + it * 256;
        int n = e >> 5, kk = e & 31;
        if (n0 + n < Np && k0 + kk < Kp)
            Wt[(size_t)(n0 + n) * Kp + k0 + kk] = (_Float16)tile[n][kk];
    }
}

// qkv(2x) + wo(2x) + qkv-bias(2x) conversions fused into one flat kernel.
__global__ __launch_bounds__(256) void k_wmisc(
    const float* __restrict__ wqkv, const float* __restrict__ wo,
    const float* __restrict__ bqkv,
    _Float16* __restrict__ qkvc, _Float16* __restrict__ woc,
    float* __restrict__ bqp)
{
    int id = blockIdx.x * 256 + threadIdx.x;
    if (id < 884736) {                       // qkv: Wt[1152][384], n' = sec*384+96h+d
        int l = id / 442368, r = id - l * 442368;
        int np = r / 384, kk = r - np * 384;
        int sec = np / 384, rr = np - sec * 384, h = rr / 96, d = rr - h * 96;
        float v = 0.0f;
        if (d < HDD && kk < 360) v = wqkv[(size_t)l * 388800 + (size_t)kk * 1080 + sec * 360 + h * HDD + d];
        if (sec == 0) v *= QSCALE;
        qkvc[id] = (_Float16)v;
    } else if (id < 1179648) {               // wo: Wt[384][384], k' = 96h+d
        int r2 = id - 884736;
        int l = r2 / 147456, r = r2 - l * 147456;
        int n = r / 384, kp = r - n * 384;
        int h = kp / 96, d = kp - h * 96;
        float v = 0.0f;
        if (d < HDD && n < 360) v = wo[(size_t)l * 129600 + (size_t)(h * HDD + d) * 360 + n];
        woc[r2] = (_Float16)v;
    } else if (id < 1181952) {               // padded qkv bias [1152]
        int r3 = id - 1179648;
        int l = r3 / 1152, r = r3 - l * 1152;
        int sec = r / 384, rr = r - sec * 384, h = rr / 96, d = rr - h * 96;
        float v = 0.0f;
        if (d < HDD) v = bqkv[l * 1080 + sec * 360 + h * HDD + d];
        if (sec == 0) v *= QSCALE;
        if (sec == 2 && d == HDD) v = 1.0f;  // softmax denominator column
        bqp[r3] = v;
    }
}

// ---------------------------------------------------------------------------
// V transpose: qkvh V-section [13824][96 per head] -> vT[bh][96][1728] f16.
// ---------------------------------------------------------------------------
__global__ __launch_bounds__(256) void k_vtr(
    const _Float16* __restrict__ qkvh, _Float16* __restrict__ vT)
{
    __shared__ _Float16 tile[32][33];
    const int t = threadIdx.x;
    const int tok0 = blockIdx.x * 32;
    const int d0 = blockIdx.y * 32;
    const int bh = blockIdx.z;              // b*4 + h
    const int b = bh >> 2, h = bh & 3;
    const size_t src = ((size_t)b * TBM + tok0) * 1152 + 768 + 96 * h + d0;
    #pragma unroll
    for (int it = 0; it < 4; ++it) {
        int tl = (t >> 5) + it * 8, dl = t & 31;
        tile[tl][dl] = qkvh[src + (size_t)tl * 1152 + dl];
    }
    __syncthreads();
    const size_t dst = ((size_t)bh * 96 + d0) * TBM + tok0;
    #pragma unroll
    for (int it = 0; it < 4; ++it) {
        int dl = (t >> 5) + it * 8, tl = t & 31;
        vT[dst + (size_t)dl * TBM + tl] = tile[tl][dl];
    }
}

// ---------------------------------------------------------------------------
// MFMA GEMM (f16): C = act(A@B + bias (+res)). 128x128 tile, BK=32, 4 waves.
// T14 register prefetch of next k-step's staging loads.
// ---------------------------------------------------------------------------
template <int ACT, bool RES, bool OUTH, bool AH>
__global__ __launch_bounds__(256, 3) void k_mgemm(
    const void* __restrict__ Ap, const _Float16* __restrict__ Bt,
    const float* __restrict__ bias, const float* res, void* Cp,
    int M, int N, int K, int Kp)
{
    __shared__ __align__(16) _Float16 Ah[4096], Bh[4096];
    const int t = threadIdx.x;
    const int lane = t & 63, wid = t >> 6;
    const int half = lane >> 5, l31 = lane & 31;
    const int m0 = blockIdx.y * 128, n0 = blockIdx.x * 128;
    const int wm = (wid >> 1) * 64, wn = (wid & 1) * 64;

    f32x16 acc00 = {}, acc01 = {}, acc10 = {}, acc11 = {};
    const int nk = Kp >> 5;
    const bool k4 = (K & 3) == 0;

    h8 acur[2], anxt[2], bcur[2], bnxt[2];
    float4 fcur[4], fnxt[4];

    const _Float16* Af = (const _Float16*)Ap;
    const float* A = (const float*)Ap;

    auto loadA_h = [&](int k0, h8* dst) {
        #pragma unroll
        for (int i = 0; i < 2; ++i) {
            int e = t + i * 256;
            int row = e >> 2, c = e & 3;
            int gm = m0 + row; if (gm > M - 1) gm = M - 1;
            dst[i] = *(const h8*)(Af + (size_t)gm * Kp + k0 + c * 8);
        }
    };
    auto loadA_f = [&](int k0, float4* dst) {
        #pragma unroll
        for (int i = 0; i < 4; ++i) {
            int e = t + i * 256;
            int row = e >> 3, c4 = e & 7;
            int gm = m0 + row, kb = k0 + c4 * 4;
            float4 fv = {0.f, 0.f, 0.f, 0.f};
            if (gm < M) {
                const float* ap = A + (size_t)gm * K + kb;
                if (k4 && kb + 3 < K) {
                    fv = *(const float4*)ap;
                } else {
                    if (kb + 0 < K) fv.x = ap[0];
                    if (kb + 1 < K) fv.y = ap[1];
                    if (kb + 2 < K) fv.z = ap[2];
                    if (kb + 3 < K) fv.w = ap[3];
                }
            }
            dst[i] = fv;
        }
    };
    auto loadB = [&](int k0, h8* dst) {
        #pragma unroll
        for (int i = 0; i < 2; ++i) {
            int e = t + i * 256;
            int col = e >> 2, c = e & 3;
            dst[i] = *(const h8*)(Bt + (size_t)(n0 + col) * Kp + k0 + c * 8);
        }
    };

    if (AH) loadA_h(0, acur); else loadA_f(0, fcur);
    loadB(0, bcur);

    for (int ks = 0; ks < nk; ++ks) {
        const bool pf = (ks + 1 < nk);
        if (pf) {
            if (AH) loadA_h((ks + 1) << 5, anxt); else loadA_f((ks + 1) << 5, fnxt);
            loadB((ks + 1) << 5, bnxt);
        }
        __syncthreads();   // previous iteration's LDS readers done
        if (AH) {
            #pragma unroll
            for (int i = 0; i < 2; ++i) {
                int e = t + i * 256;
                int row = e >> 2, c = e & 3;
                *(h8*)&Ah[(c * 128 + row) * 8] = acur[i];
            }
        } else {
            #pragma unroll
            for (int i = 0; i < 4; ++i) {
                int e = t + i * 256;
                int row = e >> 3, c4 = e & 7;
                float4 fv = fcur[i];
                h4 hv = { (_Float16)fv.x, (_Float16)fv.y, (_Float16)fv.z, (_Float16)fv.w };
                int c = c4 >> 1, sub = c4 & 1;
                *(h4*)&Ah[(c * 128 + row) * 8 + sub * 4] = hv;
            }
        }
        #pragma unroll
        for (int i = 0; i < 2; ++i) {
            int e = t + i * 256;
            int col = e >> 2, c = e & 3;
            *(h8*)&Bh[(c * 128 + col) * 8] = bcur[i];
        }
        __syncthreads();
        h8 af[2][2], bf[2][2];
        #pragma unroll
        for (int m2 = 0; m2 < 2; ++m2)
            #pragma unroll
            for (int ku = 0; ku < 2; ++ku) {
                int c = ku * 2 + half;
                af[m2][ku] = *(const h8*)&Ah[(c * 128 + wm + m2 * 32 + l31) * 8];
                bf[m2][ku] = *(const h8*)&Bh[(c * 128 + wn + m2 * 32 + l31) * 8];
            }
        #pragma unroll
        for (int ku = 0; ku < 2; ++ku) {
            acc00 = MFMA16(af[0][ku], bf[0][ku], acc00);
            acc01 = MFMA16(af[0][ku], bf[1][ku], acc01);
            acc10 = MFMA16(af[1][ku], bf[0][ku], acc10);
            acc11 = MFMA16(af[1][ku], bf[1][ku], acc11);
        }
        if (pf) {
            if (AH) { acur[0] = anxt[0]; acur[1] = anxt[1]; }
            else    { fcur[0] = fnxt[0]; fcur[1] = fnxt[1]; fcur[2] = fnxt[2]; fcur[3] = fnxt[3]; }
            bcur[0] = bnxt[0]; bcur[1] = bnxt[1];
        }
    }
    float* Cf = (float*)Cp;
    _Float16* Ch = (_Float16*)Cp;
    #define EPILOG(ACCV, M2, N2) { \
        int gn = n0 + wn + (N2) * 32 + l31; \
        if (gn < N) { \
            float bv = bias[gn]; \
            _Pragma("unroll") \
            for (int r = 0; r < 16; ++r) { \
                int gm = m0 + wm + (M2) * 32 + (r & 3) + 8 * (r >> 2) + 4 * half; \
                if (gm < M) { \
                    float v = ACCV[r] + bv; \
                    if (RES) v += res[(size_t)gm * N + gn]; \
                    if (ACT == 1) v = gelu_f(v); \
                    if (OUTH) Ch[(size_t)gm * N + gn] = (_Float16)v; \
                    else      Cf[(size_t)gm * N + gn] = v; \
                } } } }
    EPILOG(acc00, 0, 0) EPILOG(acc01, 0, 1) EPILOG(acc10, 1, 0) EPILOG(acc11, 1, 1)
    #undef EPILOG
}

// ---------------------------------------------------------------------------
// Split-K GEMM with T14 prefetch: partial[z] fp32 [MTOK][360].
// ---------------------------------------------------------------------------
__global__ __launch_bounds__(256, 3) void k_skgemm(
    const _Float16* __restrict__ A, const _Float16* __restrict__ Bt,
    float* __restrict__ P, int Kp, int KCH, int nstep)
{
    __shared__ __align__(16) _Float16 Ah[4096], Bh[4096];
    const int t = threadIdx.x;
    const int lane = t & 63, wid = t >> 6;
    const int half = lane >> 5, l31 = lane & 31;
    const int m0 = blockIdx.y * 128, n0 = blockIdx.x * 128;
    const int wm = (wid >> 1) * 64, wn = (wid & 1) * 64;
    const int zb = blockIdx.z * KCH;
    P += (size_t)blockIdx.z * MTOK * EMBD;

    f32x16 acc00 = {}, acc01 = {}, acc10 = {}, acc11 = {};

    h8 acur[2], anxt[2], bcur[2], bnxt[2];
    auto loadA = [&](int k0, h8* dst) {
        #pragma unroll
        for (int i = 0; i < 2; ++i) {
            int e = t + i * 256;
            int row = e >> 2, c = e & 3;
            dst[i] = *(const h8*)(A + (size_t)(m0 + row) * Kp + k0 + c * 8);
        }
    };
    auto loadB = [&](int k0, h8* dst) {
        #pragma unroll
        for (int i = 0; i < 2; ++i) {
            int e = t + i * 256;
            int col = e >> 2, c = e & 3;
            dst[i] = *(const h8*)(Bt + (size_t)(n0 + col) * Kp + k0 + c * 8);
        }
    };

    loadA(zb, acur); loadB(zb, bcur);

    for (int ks = 0; ks < nstep; ++ks) {
        const bool pf = (ks + 1 < nstep);
        if (pf) { loadA(zb + ((ks + 1) << 5), anxt); loadB(zb + ((ks + 1) << 5), bnxt); }
        __syncthreads();
        #pragma unroll
        for (int i = 0; i < 2; ++i) {
            int e = t + i * 256;
            int row = e >> 2, c = e & 3;
            *(h8*)&Ah[(c * 128 + row) * 8] = acur[i];
        }
        #pragma unroll
        for (int i = 0; i < 2; ++i) {
            int e = t + i * 256;
            int col = e >> 2, c = e & 3;
            *(h8*)&Bh[(c * 128 + col) * 8] = bcur[i];
        }
        __syncthreads();
        h8 af[2][2], bf[2][2];
        #pragma unroll
        for (int m2 = 0; m2 < 2; ++m2)
            #pragma unroll
            for (int ku = 0; ku < 2; ++ku) {
                int c = ku * 2 + half;
                af[m2][ku] = *(const h8*)&Ah[(c * 128 + wm + m2 * 32 + l31) * 8];
                bf[m2][ku] = *(const h8*)&Bh[(c * 128 + wn + m2 * 32 + l31) * 8];
            }
        #pragma unroll
        for (int ku = 0; ku < 2; ++ku) {
            acc00 = MFMA16(af[0][ku], bf[0][ku], acc00);
            acc01 = MFMA16(af[0][ku], bf[1][ku], acc01);
            acc10 = MFMA16(af[1][ku], bf[0][ku], acc10);
            acc11 = MFMA16(af[1][ku], bf[1][ku], acc11);
        }
        if (pf) { acur[0] = anxt[0]; acur[1] = anxt[1]; bcur[0] = bnxt[0]; bcur[1] = bnxt[1]; }
    }
    #define EPILOGP(ACCV, M2, N2) { \
        int gn = n0 + wn + (N2) * 32 + l31; \
        if (gn < EMBD) { \
            _Pragma("unroll") \
            for (int r = 0; r < 16; ++r) { \
                int gm = m0 + wm + (M2) * 32 + (r & 3) + 8 * (r >> 2) + 4 * half; \
                P[(size_t)gm * EMBD + gn] = ACCV[r]; \
            } } }
    EPILOGP(acc00, 0, 0) EPILOGP(acc01, 0, 1) EPILOGP(acc10, 1, 0) EPILOGP(acc11, 1, 1)
    #undef EPILOGP
}

// ---------------------------------------------------------------------------
// Flash attention, f16 MFMA. T12: S^T = MFMA(K, Q) puts each lane's q-row
// scores in-register; exp -> cvt_pkrtz -> v_permlane32_swap_b32 builds the
// PV A-fragments with NO LDS P buffer. K/V double-buffered: 1 barrier/tile.
// Output layout identical to R10 (verified epilogue unchanged).
// ---------------------------------------------------------------------------
__global__ __launch_bounds__(256, 2) void k_mattn(
    const _Float16* __restrict__ qkv, const _Float16* __restrict__ vT,
    _Float16* __restrict__ aob, const int* __restrict__ tcp)
{
    __shared__ __align__(16) _Float16 Kl[2][8192];   // [buf][kk*128 + chunk^ (kk&7)]
    __shared__ __align__(16) _Float16 Vl[2][6144];   // [buf][d*64 + (m^(d&7))*8]

    const int t = threadIdx.x;
    const int lane = t & 63, wid = t >> 6;
    const int half = lane >> 5, l31 = lane & 31;
    const int bid = blockIdx.x;
    const int bh = bid & 31, qt = bid >> 5;
    const int h = bh & 3, b = bh >> 2;
    const int Tc = *tcp;
    const int q0w = qt * 128 + wid * 32;
    const size_t base = (size_t)b * TBM * 1152 + 96 * h;
    const _Float16* vTb = vT + (size_t)bh * 96 * TBM;

    // staging geometry: K thread -> (kk, c) of 64x12; V thread -> (d, m) of 96x8
    int skk[3], scc[3], sdd[3], smm[3];
    int koff[3], voff[3];
    #pragma unroll
    for (int i = 0; i < 3; ++i) {
        int cid = t + i * 256;
        skk[i] = cid / 12; scc[i] = cid - skk[i] * 12;
        sdd[i] = cid >> 3; smm[i] = cid & 7;
        koff[i] = skk[i] * 128 + ((scc[i] ^ (skk[i] & 7)) << 3);
        voff[i] = sdd[i] * 64 + ((smm[i] ^ (sdd[i] & 7)) << 3);
    }

    // Q fragments (96 d, pads zero)
    h8 qf[6];
    {
        int rl = q0w + l31; if (rl > TBM - 1) rl = TBM - 1;
        const _Float16* qrow = qkv + base + (size_t)rl * 1152;
        #pragma unroll
        for (int ku = 0; ku < 6; ++ku)
            qf[ku] = *(const h8*)(qrow + ku * 16 + half * 8);
    }

    f32x16 o0 = {}, o1 = {}, o2 = {};
    int nkt = (Tc + 63) >> 6; if (nkt > 27) nkt = 27;

    // stage tile 0 into buffer 0 (all 16B copies)
    if (nkt > 0) {
        #pragma unroll
        for (int i = 0; i < 3; ++i) {
            *(h8*)&Kl[0][koff[i]] =
                *(const h8*)(qkv + base + (size_t)skk[i] * 1152 + 384 + scc[i] * 8);
            *(h8*)&Vl[0][voff[i]] =
                *(const h8*)(vTb + (size_t)sdd[i] * TBM + smm[i] * 8);
        }
    }
    __syncthreads();

    for (int kt = 0; kt < nkt; ++kt) {
        const int k0 = kt * 64;
        const int cur = kt & 1, nxt = cur ^ 1;
        // prefetch next tile into registers (hides under MFMA phase)
        h8 kpre[3], vpre[3];
        const bool pf = (kt + 1 < nkt);
        if (pf) {
            #pragma unroll
            for (int i = 0; i < 3; ++i) {
                kpre[i] = *(const h8*)(qkv + base + (size_t)(k0 + 64 + skk[i]) * 1152 + 384 + scc[i] * 8);
                vpre[i] = *(const h8*)(vTb + (size_t)sdd[i] * TBM + k0 + 64 + smm[i] * 8);
            }
        }
        // S^T = K Q (12 MFMAs): sT[r] at lane l = S[k = k0(+32) + crow(r,half)][q = l31]
        f32x16 sT0 = {}, sT1 = {};
        #pragma unroll
        for (int ku = 0; ku < 6; ++ku) {
            int c = ku * 2 + half;
            int cp = c ^ (l31 & 7);
            h8 kb0 = *(const h8*)&Kl[cur][l31 * 128 + cp * 8];
            h8 kb1 = *(const h8*)&Kl[cur][(32 + l31) * 128 + cp * 8];
            sT0 = MFMA16(kb0, qf[ku], sT0);
            sT1 = MFMA16(kb1, qf[ku], sT1);
        }
        // exp -> f16 pack -> permlane half-swap -> PV A-fragments (no LDS)
        h8 pa[4];
        #pragma unroll
        for (int g = 0; g < 2; ++g) {
            const f32x16& sT = g ? sT1 : sT0;
            const int kbase = k0 + g * 32;
            unsigned w0, w1, w2, w3, w4, w5, w6, w7;
            #define CVTW(W, R0, R1) { \
                int ka = kbase + ((R0) & 3) + 8 * ((R0) >> 2) + 4 * half; \
                int kb_ = kbase + ((R1) & 3) + 8 * ((R1) >> 2) + 4 * half; \
                float pva = (ka  < Tc) ? __expf(sT[R0]) : 0.0f; \
                float pvb = (kb_ < Tc) ? __expf(sT[R1]) : 0.0f; \
                W = __builtin_bit_cast(unsigned, __builtin_amdgcn_cvt_pkrtz(pva, pvb)); }
            CVTW(w0, 0, 1)  CVTW(w1, 2, 3)  CVTW(w2, 4, 5)  CVTW(w3, 6, 7)
            CVTW(w4, 8, 9)  CVTW(w5, 10, 11) CVTW(w6, 12, 13) CVTW(w7, 14, 15)
            #undef CVTW
            asm volatile("v_permlane32_swap_b32 %0, %1" : "+v"(w0), "+v"(w2));
            asm volatile("v_permlane32_swap_b32 %0, %1" : "+v"(w1), "+v"(w3));
            asm volatile("v_permlane32_swap_b32 %0, %1" : "+v"(w4), "+v"(w6));
            asm volatile("v_permlane32_swap_b32 %0, %1" : "+v"(w5), "+v"(w7));
            u32x4 lo = { w0, w1, w2, w3 };
            u32x4 hi = { w4, w5, w6, w7 };
            pa[g * 2 + 0] = __builtin_bit_cast(h8, lo);
            pa[g * 2 + 1] = __builtin_bit_cast(h8, hi);
        }
        // PV (12 MFMAs, single-b128 V fragments)
        #pragma unroll
        for (int n = 0; n < 3; ++n) {
            f32x16* op = n == 0 ? &o0 : (n == 1 ? &o1 : &o2);
            int d = n * 32 + l31;
            #pragma unroll
            for (int ku = 0; ku < 4; ++ku) {
                int m = ku * 2 + half;
                h8 vb = *(const h8*)&Vl[cur][d * 64 + ((m ^ (d & 7)) << 3)];
                *op = MFMA16(pa[ku], vb, *op);
            }
        }
        // write prefetched tile into the other buffer; 1 barrier per tile
        if (pf) {
            #pragma unroll
            for (int i = 0; i < 3; ++i) {
                *(h8*)&Kl[nxt][koff[i]] = kpre[i];
                *(h8*)&Vl[nxt][voff[i]] = vpre[i];
            }
        }
        __syncthreads();
    }

    // normalize by denominator (d=90 -> o2 col 26) and store padded layout
    #pragma unroll
    for (int r = 0; r < 16; ++r) {
        float den = __shfl(o2[r], (lane & 32) | 26);
        float inv = (den > 0.0f) ? 1.0f / den : 0.0f;
        int qg = q0w + (r & 3) + 8 * (r >> 2) + 4 * half;
        if (qg < Tc) {
            _Float16* orow = aob + ((size_t)b * TBM + qg) * 384 + 96 * h;
            orow[l31]      = (_Float16)(o0[r] * inv);
            orow[32 + l31] = (_Float16)(o1[r] * inv);
            orow[64 + l31] = (64 + l31 < HDD) ? (_Float16)(o2[r] * inv) : (_Float16)0.0f;
        }
    }
}

// ---------------------------------------------------------------------------
// Gather + 3^3 sum-pool + |.| mask accumulation (atomic)
// ---------------------------------------------------------------------------
__global__ __launch_bounds__(128) void k_pool(
    const float* __restrict__ F_emb, const int* __restrict__ C,
    float* __restrict__ nodes, float* __restrict__ vsum)
{
    const int tkn = blockIdx.x, b = blockIdx.y;
    const int oz = tkn % 12, oy = (tkn / 12) % 12, ox = tkn / 144;
    __shared__ int idx[27];
    const int tid = threadIdx.x;
    if (tid < 27) {
        int dx = tid / 9, dy = (tid / 3) % 3, dz = tid % 3;
        idx[tid] = C[(((b * GG) + ox * 2 + dx) * GG + oy * 2 + dy) * GG + oz * 2 + dz];
    }
    __syncthreads();
    float a0 = 0.f, a1 = 0.f, a2 = 0.f;
    for (int n = 0; n < 27; ++n) {
        int c = idx[n];
        if (c == 0) continue;
        const float* src = F_emb + (size_t)(b * NROI + (c - 1)) * EMBD;
        a0 += src[tid]; a1 += src[tid + 128];
        if (tid < 104) a2 += src[tid + 256];
    }
    float* dst = nodes + ((size_t)b * TBM + tkn) * EMBD;
    dst[tid] = a0; dst[tid + 128] = a1;
    if (tid < 104) dst[tid + 256] = a2;
    float s = fabsf(a0) + fabsf(a1) + ((tid < 104) ? fabsf(a2) : 0.0f);
    #pragma unroll
    for (int o = 32; o >= 1; o >>= 1) s += __shfl_xor(s, o);
    __shared__ float red[2];
    if ((tid & 63) == 0) red[tid >> 6] = s;
    __syncthreads();
    if (tid == 0) atomicAdd(&vsum[tkn], red[0] + red[1]);
}

__global__ __launch_bounds__(256) void k_scan(
    const float* __restrict__ vsum, int* __restrict__ cidx, int* __restrict__ tcp)
{
    __shared__ int csum[256];
    __shared__ int coff[256];
    const int t = threadIdx.x;
    const int base = t * 7;
    int loc[7]; int s = 0;
    #pragma unroll
    for (int i = 0; i < 7; ++i) {
        int g = base + i;
        int v = (g < TBM) ? (vsum[g] > 0.0f ? 1 : 0) : 0;
        loc[i] = v; s += v;
    }
    csum[t] = s;
    __syncthreads();
    if (t == 0) {
        int a = 0;
        for (int i = 0; i < 256; ++i) { coff[i] = a; a += csum[i]; }
        *tcp = a;
    }
    __syncthreads();
    int off = coff[t];
    #pragma unroll
    for (int i = 0; i < 7; ++i) {
        int g = base + i;
        if (g < TBM && loc[i]) cidx[off++] = g;
    }
}

// compact -> t360 fp32 [.][360] and xh f16 [.][384] (pads zero)
__global__ __launch_bounds__(128) void k_compact(
    const float* __restrict__ nodes, const int* __restrict__ cidx,
    const int* __restrict__ tcp, float* __restrict__ xf, _Float16* __restrict__ xh)
{
    const int j = blockIdx.x, b = blockIdx.y;
    const int Tc = *tcp;
    const size_t row = (size_t)b * TBM + j;
    const float* src = (j < Tc) ? nodes + ((size_t)b * TBM + cidx[j]) * EMBD : nullptr;
    for (int e = threadIdx.x; e < 384; e += 128) {
        float v = (e < EMBD && src) ? src[e] : 0.0f;
        if (e < EMBD) xf[row * EMBD + e] = v;
        xh[row * 384 + e] = (_Float16)v;
    }
}

// ---------------------------------------------------------------------------
// Fused split-K reduce + bias + residual + LayerNorm, one WAVE per row.
// ---------------------------------------------------------------------------
__global__ __launch_bounds__(256) void k_lnr(
    const float* __restrict__ p0, const float* __restrict__ p1,
    const float* __restrict__ bias, const float* res,
    const float* __restrict__ sc, const float* __restrict__ bc,
    float* outf, _Float16* __restrict__ outh)
{
    const int lane = threadIdx.x & 63;
    const int row = blockIdx.x * 4 + (threadIdx.x >> 6);
    const size_t ro = (size_t)row * EMBD;
    const int e0 = lane * 6;
    float x[6] = {0.f, 0.f, 0.f, 0.f, 0.f, 0.f};
    float sum = 0.f;
    if (lane < 60) {
        #pragma unroll
        for (int i = 0; i < 6; ++i) {
            float v = p0[ro + e0 + i] + p1[ro + e0 + i] + bias[e0 + i] + res[ro + e0 + i];
            x[i] = v; sum += v;
        }
    }
    #pragma unroll
    for (int o = 32; o >= 1; o >>= 1) sum += __shfl_xor(sum, o);
    const float mean = sum * (1.0f / 360.0f);
    float vs = 0.f;
    if (lane < 60) {
        #pragma unroll
        for (int i = 0; i < 6; ++i) { float d = x[i] - mean; vs += d * d; }
    }
    #pragma unroll
    for (int o = 32; o >= 1; o >>= 1) vs += __shfl_xor(vs, o);
    const float rs = rsqrtf(vs * (1.0f / 360.0f) + 1e-5f);
    _Float16* hrow = outh + (size_t)row * 384;
    if (lane < 60) {
        #pragma unroll
        for (int i = 0; i < 6; ++i) {
            float v = (x[i] - mean) * rs * sc[e0 + i] + bc[e0 + i];
            outf[ro + e0 + i] = v;
            hrow[e0 + i] = (_Float16)v;
        }
    } else {
        #pragma unroll
        for (int i = 0; i < 6; ++i)
            hrow[360 + (lane - 60) * 6 + i] = (_Float16)0.0f;
    }
}

// ---------------------------------------------------------------------------
// Mean stage 1: partial[chunk][b][e] = sum over tokens in chunk.
// ---------------------------------------------------------------------------
__global__ __launch_bounds__(128) void k_mean2(
    const float* __restrict__ x, float* __restrict__ partial,
    const int* __restrict__ tcp)
{
    const int chunk = blockIdx.x;   // 0..15, 108 tokens each
    const int b = blockIdx.y;
    const int t = threadIdx.x;
    const int Tc = *tcp;
    int j0 = chunk * 108;
    int j1 = j0 + 108; if (j1 > Tc) j1 = Tc;
    const float* xb = x + (size_t)b * TBM * EMBD;
    float a0 = 0.f, a1 = 0.f, a2 = 0.f;
    for (int j = j0; j < j1; ++j) {
        const float* r = xb + (size_t)j * EMBD;
        a0 += r[t]; a1 += r[t + 128];
        if (t < 104) a2 += r[t + 256];
    }
    float* p = partial + ((size_t)chunk * NB + b) * EMBD;
    p[t] = a0; p[t + 128] = a1;
    if (t < 104) p[t + 256] = a2;
}

// Head: one block per batch.
__global__ __launch_bounds__(256) void k_head(
    const float* __restrict__ partial, const int* __restrict__ tcp,
    const float* __restrict__ cw1, const float* __restrict__ cb1,
    const float* __restrict__ cw2, const float* __restrict__ cb2,
    const float* __restrict__ cw3, const float* __restrict__ cb3,
    float* __restrict__ outp)
{
    const int b = blockIdx.x;
    __shared__ float hs[EMBD];
    __shared__ float h1[256];
    __shared__ float h2[128];
    const int t = threadIdx.x;
    int Tc = *tcp; if (Tc < 1) Tc = 1;
    const float inv = 1.0f / (float)Tc;
    for (int e = t; e < EMBD; e += 256) {
        float s = 0.f;
        #pragma unroll
        for (int c = 0; c < 16; ++c) s += partial[(size_t)c * NB * EMBD + b * EMBD + e];
        hs[e] = s * inv;
    }
    __syncthreads();
    {
        float s = cb1[t];
        for (int k = 0; k < EMBD; ++k) s = fmaf(hs[k], cw1[k * 256 + t], s);
        h1[t] = gelu_f(s);
    }
    __syncthreads();
    if (t < 128) {
        float s = cb2[t];
        for (int k = 0; k < 256; ++k) s = fmaf(h1[k], cw2[k * 128 + t], s);
        h2[t] = fmaxf(s, 0.0f);
    }
    __syncthreads();
    if (t < 2) {
        float s = cb3[t];
        for (int k = 0; k < 128; ++k) s = fmaf(h2[k], cw3[k * 2 + t], s);
        outp[b * 2 + t] = s;
    }
}

// ---------------------------------------------------------------------------
extern "C" void kernel_launch(void* const* d_in, const int* in_sizes, int n_in,
                              void* d_out, int out_size, void* d_ws, size_t ws_size,
                              hipStream_t stream)
{
    const float* F_roi  = (const float*)d_in[0];
    const int*   C      = (const int*)d_in[1];
    const float* ffn_w1 = (const float*)d_in[2];
    const float* ffn_b1 = (const float*)d_in[3];
    const float* ffn_w2 = (const float*)d_in[4];
    const float* ffn_b2 = (const float*)d_in[5];
    const float* wqkv   = (const float*)d_in[6];
    const float* bqkv   = (const float*)d_in[7];
    const float* wo     = (const float*)d_in[8];
    const float* bo     = (const float*)d_in[9];
    const float* ln1s   = (const float*)d_in[10];
    const float* ln1b   = (const float*)d_in[11];
    const float* wf1    = (const float*)d_in[12];
    const float* bf1    = (const float*)d_in[13];
    const float* wf2    = (const float*)d_in[14];
    const float* bf2    = (const float*)d_in[15];
    const float* ln2s   = (const float*)d_in[16];
    const float* ln2b   = (const float*)d_in[17];
    const float* cw1    = (const float*)d_in[18];
    const float* cb1    = (const float*)d_in[19];
    const float* cw2    = (const float*)d_in[20];
    const float* cb2    = (const float*)d_in[21];
    const float* cw3    = (const float*)d_in[22];
    const float* cb3    = (const float*)d_in[23];
    float* out = (float*)d_out;

    float* ws = (float*)d_ws;
    _Float16* qkvh = (_Float16*)ws;                   // [13824][1152] f16
    float*    tmp450 = ws;                            // alias
    float*    F_emb  = ws + 1440000;                  // alias
    float*    midf   = ws + 7962624;
    _Float16* midb   = (_Float16*)midf;               // [13824][2048] f16
    float*    nodes  = midf;                          // alias fp32
    _Float16* aob    = (_Float16*)(ws + 22118400);    // [13824][384] f16
    float*    p0     = ws + 24772608;
    float*    p1     = ws + 29749248;
    float*    t360   = ws + 34725888;
    _Float16* xh     = (_Float16*)(ws + 39702528);    // [13824][384] f16
    _Float16* sw     = (_Float16*)(ws + 42356736);

    size_t so = 0;
    auto salloc = [&](size_t n) { _Float16* p = sw + so; so += n; return p; };
    _Float16* w1c  = salloc(262144);           // [512][512]
    _Float16* w2c  = salloc(184320);           // [384][480]
    _Float16* qkvc = salloc(2 * 442368);       // [1152][384] x2
    _Float16* woc  = salloc(2 * 147456);       // [384][384]  x2
    _Float16* f1c  = salloc(2 * 786432);       // [2048][384] x2
    _Float16* f2c  = salloc(2 * 786432);       // [384][2048] x2
    float* partial = ws + 44742656;            // 16 x 8 x 360
    int*   ints    = (int*)(partial + 46080);
    int*   cidx    = ints;                     // 1728
    int*   tcp     = ints + 1728;              // 1
    float* vsumf   = (float*)(ints + 1732);    // 1728
    float* bqp     = vsumf + 1728;             // 2 x 1152
    _Float16* vT   = (_Float16*)(ws + 44800000); // [32][96][1728] f16

    dim3 blk(256);

    // Weight conversions
    k_wconv<<<dim3(16, 16, 1), blk, 0, stream>>>(ffn_w1, 512, 450, w1c, 512, 512, 0, 0);
    k_wconv<<<dim3(15, 12, 1), blk, 0, stream>>>(ffn_w2, 450, 360, w2c, 480, 384, 0, 0);
    k_wconv<<<dim3(12, 64, 2), blk, 0, stream>>>(wf1, 360, 2048, f1c, 384, 2048, 360 * 2048, 786432);
    k_wconv<<<dim3(64, 12, 2), blk, 0, stream>>>(wf2, 2048, 360, f2c, 2048, 384, 2048 * 360, 786432);
    k_wmisc<<<dim3(4618), blk, 0, stream>>>(wqkv, wo, bqkv, qkvc, woc, bqp);

    // Node featurization
    hipError_t e0 = hipMemsetAsync(vsumf, 0, TBM * sizeof(float), stream); (void)e0;
    k_mgemm<1, false, false, false><<<dim3(4, 25), blk, 0, stream>>>(F_roi, w1c, ffn_b1, nullptr, tmp450, 3200, 450, 512, 512);
    k_mgemm<0, false, false, false><<<dim3(3, 25), blk, 0, stream>>>(tmp450, w2c, ffn_b2, nullptr, F_emb, 3200, 360, 450, 480);
    k_pool<<<dim3(1728, 8), dim3(128), 0, stream>>>(F_emb, C, nodes, vsumf);
    k_scan<<<dim3(1), blk, 0, stream>>>(vsumf, cidx, tcp);
    k_compact<<<dim3(1728, 8), dim3(128), 0, stream>>>(nodes, cidx, tcp, t360, xh);

    // Transformer layers
    for (int l = 0; l < 2; ++l) {
        k_mgemm<0, false, true, true><<<dim3(9, 108), blk, 0, stream>>>(xh, qkvc + (size_t)l * 442368, bqp + l * 1152, nullptr, qkvh, MTOK, 1152, 360, 384);
        k_vtr<<<dim3(54, 3, 32), blk, 0, stream>>>(qkvh, vT);
        k_mattn<<<dim3(448), blk, 0, stream>>>(qkvh, vT, aob, tcp);
        k_skgemm<<<dim3(3, 108, 2), blk, 0, stream>>>(aob, woc + (size_t)l * 147456, p0, 384, 192, 6);
        k_lnr<<<dim3(MTOK / 4), blk, 0, stream>>>(p0, p1, bo + l * 360, t360, ln1s + l * 360, ln1b + l * 360, t360, xh);
        k_mgemm<1, false, true, true><<<dim3(16, 108), blk, 0, stream>>>(xh, f1c + (size_t)l * 786432, bf1 + l * 2048, nullptr, midb, MTOK, 2048, 360, 384);
        k_skgemm<<<dim3(3, 108, 2), blk, 0, stream>>>(midb, f2c + (size_t)l * 786432, p0, 2048, 1024, 32);
        k_lnr<<<dim3(MTOK / 4), blk, 0, stream>>>(p0, p1, bf2 + l * 360, t360, ln2s + l * 360, ln2b + l * 360, t360, xh);
    }

    // Head
    k_mean2<<<dim3(16, 8), dim3(128), 0, stream>>>(t360, partial, tcp);
    k_head<<<dim3(8), blk, 0, stream>>>(partial, tcp, cw1, cb1, cw2, cb2, cw3, cb3, out);
}

// Round 13
// 665.762 us; speedup vs baseline: 7.5262x; 1.0013x over previous
//
#include <hip/hip_runtime.h>
#include <math.h>

#define NB   8
#define NROI 400
#define GG   25
#define EMBD 360
#define HDD  90
#define TBM  1728
#define MTOK 13824      // NB*TBM

typedef __attribute__((ext_vector_type(8)))  _Float16 h8;   // 8 f16 (4 VGPR)
typedef __attribute__((ext_vector_type(4)))  _Float16 h4;
typedef __attribute__((ext_vector_type(16))) float f32x16;
typedef __attribute__((ext_vector_type(4)))  unsigned u32x4;

#define MFMA16(a,b,c) __builtin_amdgcn_mfma_f32_32x32x16_f16(a,b,c,0,0,0)
#define QSCALE 0.105409255338945984f   /* 1/sqrt(90) */

__device__ __forceinline__ float gelu_f(float x) {
    return 0.5f * x * (1.0f + erff(x * 0.7071067811865475f));
}

// ---------------------------------------------------------------------------
// Tiled weight convert+transpose: W[K][N] fp32 -> Wt[Np][Kp] f16 (zero-pad).
// ---------------------------------------------------------------------------
__global__ __launch_bounds__(256) void k_wconv(
    const float* __restrict__ W, int K, int N,
    _Float16* __restrict__ Wt, int Kp, int Np, int Wls, int Wtls)
{
    W  += (size_t)blockIdx.z * Wls;
    Wt += (size_t)blockIdx.z * Wtls;
    __shared__ float tile[32][33];
    const int k0 = blockIdx.x * 32, n0 = blockIdx.y * 32;
    const int t = threadIdx.x;
    #pragma unroll
    for (int it = 0; it < 4; ++it) {
        int e = t + it * 256;
        int i = e >> 5, j = e & 31;
        tile[j][i] = (k0 + i < K && n0 + j < N) ? W[(size_t)(k0 + i) * N + n0 + j] : 0.0f;
    }
    __syncthreads();
    #pragma unroll
    for (int it = 0; it < 4; ++it) {
        int e = t + it * 256;
        int n = e >> 5, kk = e & 31;
        if (n0 + n < Np && k0 + kk < Kp)
            Wt[(size_t)(n0 + n) * Kp + k0 + kk] = (_Float16)tile[n][kk];
    }
}

// qkv(2x) + wo(2x) + qkv-bias(2x) conversions fused into one flat kernel.
__global__ __launch_bounds__(256) void k_wmisc(
    const float* __restrict__ wqkv, const float* __restrict__ wo,
    const float* __restrict__ bqkv,
    _Float16* __restrict__ qkvc, _Float16* __restrict__ woc,
    float* __restrict__ bqp)
{
    int id = blockIdx.x * 256 + threadIdx.x;
    if (id < 884736) {                       // qkv: Wt[1152][384], n' = sec*384+96h+d
        int l = id / 442368, r = id - l * 442368;
        int np = r / 384, kk = r - np * 384;
        int sec = np / 384, rr = np - sec * 384, h = rr / 96, d = rr - h * 96;
        float v = 0.0f;
        if (d < HDD && kk < 360) v = wqkv[(size_t)l * 388800 + (size_t)kk * 1080 + sec * 360 + h * HDD + d];
        if (sec == 0) v *= QSCALE;
        qkvc[id] = (_Float16)v;
    } else if (id < 1179648) {               // wo: Wt[384][384], k' = 96h+d
        int r2 = id - 884736;
        int l = r2 / 147456, r = r2 - l * 147456;
        int n = r / 384, kp = r - n * 384;
        int h = kp / 96, d = kp - h * 96;
        float v = 0.0f;
        if (d < HDD && n < 360) v = wo[(size_t)l * 129600 + (size_t)(h * HDD + d) * 360 + n];
        woc[r2] = (_Float16)v;
    } else if (id < 1181952) {               // padded qkv bias [1152]
        int r3 = id - 1179648;
        int l = r3 / 1152, r = r3 - l * 1152;
        int sec = r / 384, rr = r - sec * 384, h = rr / 96, d = rr - h * 96;
        float v = 0.0f;
        if (d < HDD) v = bqkv[l * 1080 + sec * 360 + h * HDD + d];
        if (sec == 0) v *= QSCALE;
        if (sec == 2 && d == HDD) v = 1.0f;  // softmax denominator column
        bqp[r3] = v;
    }
}

// ---------------------------------------------------------------------------
// V transpose: qkvh V-section [13824][96 per head] -> vT[bh][96][1728] f16.
// ---------------------------------------------------------------------------
__global__ __launch_bounds__(256) void k_vtr(
    const _Float16* __restrict__ qkvh, _Float16* __restrict__ vT)
{
    __shared__ _Float16 tile[32][33];
    const int t = threadIdx.x;
    const int tok0 = blockIdx.x * 32;
    const int d0 = blockIdx.y * 32;
    const int bh = blockIdx.z;              // b*4 + h
    const int b = bh >> 2, h = bh & 3;
    const size_t src = ((size_t)b * TBM + tok0) * 1152 + 768 + 96 * h + d0;
    #pragma unroll
    for (int it = 0; it < 4; ++it) {
        int tl = (t >> 5) + it * 8, dl = t & 31;
        tile[tl][dl] = qkvh[src + (size_t)tl * 1152 + dl];
    }
    __syncthreads();
    const size_t dst = ((size_t)bh * 96 + d0) * TBM + tok0;
    #pragma unroll
    for (int it = 0; it < 4; ++it) {
        int dl = (t >> 5) + it * 8, tl = t & 31;
        vT[dst + (size_t)dl * TBM + tl] = tile[tl][dl];
    }
}

// ---------------------------------------------------------------------------
// MFMA GEMM (f16): C = act(A@B + bias (+res)). 128x128 tile, BK=32, 4 waves.
// Double-buffered LDS + T14 register prefetch: ONE barrier per k-step.
// ---------------------------------------------------------------------------
template <int ACT, bool RES, bool OUTH, bool AH>
__global__ __launch_bounds__(256, 3) void k_mgemm(
    const void* __restrict__ Ap, const _Float16* __restrict__ Bt,
    const float* __restrict__ bias, const float* res, void* Cp,
    int M, int N, int K, int Kp)
{
    __shared__ __align__(16) _Float16 Ah[2][4096], Bh[2][4096];
    const int t = threadIdx.x;
    const int lane = t & 63, wid = t >> 6;
    const int half = lane >> 5, l31 = lane & 31;
    const int m0 = blockIdx.y * 128, n0 = blockIdx.x * 128;
    const int wm = (wid >> 1) * 64, wn = (wid & 1) * 64;

    f32x16 acc00 = {}, acc01 = {}, acc10 = {}, acc11 = {};
    const int nk = Kp >> 5;
    const bool k4 = (K & 3) == 0;

    h8 acur[2], anxt[2], bcur[2], bnxt[2];
    float4 fcur[4], fnxt[4];

    const _Float16* Af = (const _Float16*)Ap;
    const float* A = (const float*)Ap;

    auto loadA_h = [&](int k0, h8* dst) {
        #pragma unroll
        for (int i = 0; i < 2; ++i) {
            int e = t + i * 256;
            int row = e >> 2, c = e & 3;
            int gm = m0 + row; if (gm > M - 1) gm = M - 1;
            dst[i] = *(const h8*)(Af + (size_t)gm * Kp + k0 + c * 8);
        }
    };
    auto loadA_f = [&](int k0, float4* dst) {
        #pragma unroll
        for (int i = 0; i < 4; ++i) {
            int e = t + i * 256;
            int row = e >> 3, c4 = e & 7;
            int gm = m0 + row, kb = k0 + c4 * 4;
            float4 fv = {0.f, 0.f, 0.f, 0.f};
            if (gm < M) {
                const float* ap = A + (size_t)gm * K + kb;
                if (k4 && kb + 3 < K) {
                    fv = *(const float4*)ap;
                } else {
                    if (kb + 0 < K) fv.x = ap[0];
                    if (kb + 1 < K) fv.y = ap[1];
                    if (kb + 2 < K) fv.z = ap[2];
                    if (kb + 3 < K) fv.w = ap[3];
                }
            }
            dst[i] = fv;
        }
    };
    auto loadB = [&](int k0, h8* dst) {
        #pragma unroll
        for (int i = 0; i < 2; ++i) {
            int e = t + i * 256;
            int col = e >> 2, c = e & 3;
            dst[i] = *(const h8*)(Bt + (size_t)(n0 + col) * Kp + k0 + c * 8);
        }
    };
    auto writeA_h = [&](int buf, const h8* src) {
        #pragma unroll
        for (int i = 0; i < 2; ++i) {
            int e = t + i * 256;
            int row = e >> 2, c = e & 3;
            *(h8*)&Ah[buf][(c * 128 + row) * 8] = src[i];
        }
    };
    auto writeA_f = [&](int buf, const float4* src) {
        #pragma unroll
        for (int i = 0; i < 4; ++i) {
            int e = t + i * 256;
            int row = e >> 3, c4 = e & 7;
            float4 fv = src[i];
            h4 hv = { (_Float16)fv.x, (_Float16)fv.y, (_Float16)fv.z, (_Float16)fv.w };
            int c = c4 >> 1, sub = c4 & 1;
            *(h4*)&Ah[buf][(c * 128 + row) * 8 + sub * 4] = hv;
        }
    };
    auto writeB = [&](int buf, const h8* src) {
        #pragma unroll
        for (int i = 0; i < 2; ++i) {
            int e = t + i * 256;
            int col = e >> 2, c = e & 3;
            *(h8*)&Bh[buf][(c * 128 + col) * 8] = src[i];
        }
    };

    // preload k-step 0 into buffer 0
    if (AH) { loadA_h(0, acur); writeA_h(0, acur); }
    else    { loadA_f(0, fcur); writeA_f(0, fcur); }
    loadB(0, bcur); writeB(0, bcur);
    __syncthreads();

    for (int ks = 0; ks < nk; ++ks) {
        const int cur = ks & 1, nxt = cur ^ 1;
        const bool pf = (ks + 1 < nk);
        if (pf) {
            if (AH) loadA_h((ks + 1) << 5, anxt); else loadA_f((ks + 1) << 5, fnxt);
            loadB((ks + 1) << 5, bnxt);
        }
        h8 af[2][2], bf[2][2];
        #pragma unroll
        for (int m2 = 0; m2 < 2; ++m2)
            #pragma unroll
            for (int ku = 0; ku < 2; ++ku) {
                int c = ku * 2 + half;
                af[m2][ku] = *(const h8*)&Ah[cur][(c * 128 + wm + m2 * 32 + l31) * 8];
                bf[m2][ku] = *(const h8*)&Bh[cur][(c * 128 + wn + m2 * 32 + l31) * 8];
            }
        #pragma unroll
        for (int ku = 0; ku < 2; ++ku) {
            acc00 = MFMA16(af[0][ku], bf[0][ku], acc00);
            acc01 = MFMA16(af[0][ku], bf[1][ku], acc01);
            acc10 = MFMA16(af[1][ku], bf[0][ku], acc10);
            acc11 = MFMA16(af[1][ku], bf[1][ku], acc11);
        }
        if (pf) {
            if (AH) writeA_h(nxt, anxt); else writeA_f(nxt, fnxt);
            writeB(nxt, bnxt);
        }
        __syncthreads();
    }
    float* Cf = (float*)Cp;
    _Float16* Ch = (_Float16*)Cp;
    #define EPILOG(ACCV, M2, N2) { \
        int gn = n0 + wn + (N2) * 32 + l31; \
        if (gn < N) { \
            float bv = bias[gn]; \
            _Pragma("unroll") \
            for (int r = 0; r < 16; ++r) { \
                int gm = m0 + wm + (M2) * 32 + (r & 3) + 8 * (r >> 2) + 4 * half; \
                if (gm < M) { \
                    float v = ACCV[r] + bv; \
                    if (RES) v += res[(size_t)gm * N + gn]; \
                    if (ACT == 1) v = gelu_f(v); \
                    if (OUTH) Ch[(size_t)gm * N + gn] = (_Float16)v; \
                    else      Cf[(size_t)gm * N + gn] = v; \
                } } } }
    EPILOG(acc00, 0, 0) EPILOG(acc01, 0, 1) EPILOG(acc10, 1, 0) EPILOG(acc11, 1, 1)
    #undef EPILOG
}

// ---------------------------------------------------------------------------
// Split-K GEMM, double-buffered LDS + T14 prefetch: partial[z] fp32 [MTOK][360].
// ---------------------------------------------------------------------------
__global__ __launch_bounds__(256, 3) void k_skgemm(
    const _Float16* __restrict__ A, const _Float16* __restrict__ Bt,
    float* __restrict__ P, int Kp, int KCH, int nstep)
{
    __shared__ __align__(16) _Float16 Ah[2][4096], Bh[2][4096];
    const int t = threadIdx.x;
    const int lane = t & 63, wid = t >> 6;
    const int half = lane >> 5, l31 = lane & 31;
    const int m0 = blockIdx.y * 128, n0 = blockIdx.x * 128;
    const int wm = (wid >> 1) * 64, wn = (wid & 1) * 64;
    const int zb = blockIdx.z * KCH;
    P += (size_t)blockIdx.z * MTOK * EMBD;

    f32x16 acc00 = {}, acc01 = {}, acc10 = {}, acc11 = {};

    h8 acur[2], anxt[2], bcur[2], bnxt[2];
    auto loadA = [&](int k0, h8* dst) {
        #pragma unroll
        for (int i = 0; i < 2; ++i) {
            int e = t + i * 256;
            int row = e >> 2, c = e & 3;
            dst[i] = *(const h8*)(A + (size_t)(m0 + row) * Kp + k0 + c * 8);
        }
    };
    auto loadB = [&](int k0, h8* dst) {
        #pragma unroll
        for (int i = 0; i < 2; ++i) {
            int e = t + i * 256;
            int col = e >> 2, c = e & 3;
            dst[i] = *(const h8*)(Bt + (size_t)(n0 + col) * Kp + k0 + c * 8);
        }
    };
    auto writeA = [&](int buf, const h8* src) {
        #pragma unroll
        for (int i = 0; i < 2; ++i) {
            int e = t + i * 256;
            int row = e >> 2, c = e & 3;
            *(h8*)&Ah[buf][(c * 128 + row) * 8] = src[i];
        }
    };
    auto writeB = [&](int buf, const h8* src) {
        #pragma unroll
        for (int i = 0; i < 2; ++i) {
            int e = t + i * 256;
            int col = e >> 2, c = e & 3;
            *(h8*)&Bh[buf][(c * 128 + col) * 8] = src[i];
        }
    };

    loadA(zb, acur); writeA(0, acur);
    loadB(zb, bcur); writeB(0, bcur);
    __syncthreads();

    for (int ks = 0; ks < nstep; ++ks) {
        const int cur = ks & 1, nxt = cur ^ 1;
        const bool pf = (ks + 1 < nstep);
        if (pf) { loadA(zb + ((ks + 1) << 5), anxt); loadB(zb + ((ks + 1) << 5), bnxt); }
        h8 af[2][2], bf[2][2];
        #pragma unroll
        for (int m2 = 0; m2 < 2; ++m2)
            #pragma unroll
            for (int ku = 0; ku < 2; ++ku) {
                int c = ku * 2 + half;
                af[m2][ku] = *(const h8*)&Ah[cur][(c * 128 + wm + m2 * 32 + l31) * 8];
                bf[m2][ku] = *(const h8*)&Bh[cur][(c * 128 + wn + m2 * 32 + l31) * 8];
            }
        #pragma unroll
        for (int ku = 0; ku < 2; ++ku) {
            acc00 = MFMA16(af[0][ku], bf[0][ku], acc00);
            acc01 = MFMA16(af[0][ku], bf[1][ku], acc01);
            acc10 = MFMA16(af[1][ku], bf[0][ku], acc10);
            acc11 = MFMA16(af[1][ku], bf[1][ku], acc11);
        }
        if (pf) { writeA(nxt, anxt); writeB(nxt, bnxt); }
        __syncthreads();
    }
    #define EPILOGP(ACCV, M2, N2) { \
        int gn = n0 + wn + (N2) * 32 + l31; \
        if (gn < EMBD) { \
            _Pragma("unroll") \
            for (int r = 0; r < 16; ++r) { \
                int gm = m0 + wm + (M2) * 32 + (r & 3) + 8 * (r >> 2) + 4 * half; \
                P[(size_t)gm * EMBD + gn] = ACCV[r]; \
            } } }
    EPILOGP(acc00, 0, 0) EPILOGP(acc01, 0, 1) EPILOGP(acc10, 1, 0) EPILOGP(acc11, 1, 1)
    #undef EPILOGP
}

// ---------------------------------------------------------------------------
// Flash attention, f16 MFMA (T12 in-register softmax path). Unchanged from R12.
// ---------------------------------------------------------------------------
__global__ __launch_bounds__(256, 2) void k_mattn(
    const _Float16* __restrict__ qkv, const _Float16* __restrict__ vT,
    _Float16* __restrict__ aob, const int* __restrict__ tcp)
{
    __shared__ __align__(16) _Float16 Kl[2][8192];   // [buf][kk*128 + chunk^ (kk&7)]
    __shared__ __align__(16) _Float16 Vl[2][6144];   // [buf][d*64 + (m^(d&7))*8]

    const int t = threadIdx.x;
    const int lane = t & 63, wid = t >> 6;
    const int half = lane >> 5, l31 = lane & 31;
    const int bid = blockIdx.x;
    const int bh = bid & 31, qt = bid >> 5;
    const int h = bh & 3, b = bh >> 2;
    const int Tc = *tcp;
    const int q0w = qt * 128 + wid * 32;
    const size_t base = (size_t)b * TBM * 1152 + 96 * h;
    const _Float16* vTb = vT + (size_t)bh * 96 * TBM;

    int skk[3], scc[3], sdd[3], smm[3];
    int koff[3], voff[3];
    #pragma unroll
    for (int i = 0; i < 3; ++i) {
        int cid = t + i * 256;
        skk[i] = cid / 12; scc[i] = cid - skk[i] * 12;
        sdd[i] = cid >> 3; smm[i] = cid & 7;
        koff[i] = skk[i] * 128 + ((scc[i] ^ (skk[i] & 7)) << 3);
        voff[i] = sdd[i] * 64 + ((smm[i] ^ (sdd[i] & 7)) << 3);
    }

    h8 qf[6];
    {
        int rl = q0w + l31; if (rl > TBM - 1) rl = TBM - 1;
        const _Float16* qrow = qkv + base + (size_t)rl * 1152;
        #pragma unroll
        for (int ku = 0; ku < 6; ++ku)
            qf[ku] = *(const h8*)(qrow + ku * 16 + half * 8);
    }

    f32x16 o0 = {}, o1 = {}, o2 = {};
    int nkt = (Tc + 63) >> 6; if (nkt > 27) nkt = 27;

    if (nkt > 0) {
        #pragma unroll
        for (int i = 0; i < 3; ++i) {
            *(h8*)&Kl[0][koff[i]] =
                *(const h8*)(qkv + base + (size_t)skk[i] * 1152 + 384 + scc[i] * 8);
            *(h8*)&Vl[0][voff[i]] =
                *(const h8*)(vTb + (size_t)sdd[i] * TBM + smm[i] * 8);
        }
    }
    __syncthreads();

    for (int kt = 0; kt < nkt; ++kt) {
        const int k0 = kt * 64;
        const int cur = kt & 1, nxt = cur ^ 1;
        h8 kpre[3], vpre[3];
        const bool pf = (kt + 1 < nkt);
        if (pf) {
            #pragma unroll
            for (int i = 0; i < 3; ++i) {
                kpre[i] = *(const h8*)(qkv + base + (size_t)(k0 + 64 + skk[i]) * 1152 + 384 + scc[i] * 8);
                vpre[i] = *(const h8*)(vTb + (size_t)sdd[i] * TBM + k0 + 64 + smm[i] * 8);
            }
        }
        // S^T = K Q (12 MFMAs)
        f32x16 sT0 = {}, sT1 = {};
        #pragma unroll
        for (int ku = 0; ku < 6; ++ku) {
            int c = ku * 2 + half;
            int cp = c ^ (l31 & 7);
            h8 kb0 = *(const h8*)&Kl[cur][l31 * 128 + cp * 8];
            h8 kb1 = *(const h8*)&Kl[cur][(32 + l31) * 128 + cp * 8];
            sT0 = MFMA16(kb0, qf[ku], sT0);
            sT1 = MFMA16(kb1, qf[ku], sT1);
        }
        // exp -> f16 pack -> permlane half-swap -> PV A-fragments (no LDS)
        h8 pa[4];
        #pragma unroll
        for (int g = 0; g < 2; ++g) {
            const f32x16& sT = g ? sT1 : sT0;
            const int kbase = k0 + g * 32;
            unsigned w0, w1, w2, w3, w4, w5, w6, w7;
            #define CVTW(W, R0, R1) { \
                int ka = kbase + ((R0) & 3) + 8 * ((R0) >> 2) + 4 * half; \
                int kb_ = kbase + ((R1) & 3) + 8 * ((R1) >> 2) + 4 * half; \
                float pva = (ka  < Tc) ? __expf(sT[R0]) : 0.0f; \
                float pvb = (kb_ < Tc) ? __expf(sT[R1]) : 0.0f; \
                W = __builtin_bit_cast(unsigned, __builtin_amdgcn_cvt_pkrtz(pva, pvb)); }
            CVTW(w0, 0, 1)  CVTW(w1, 2, 3)  CVTW(w2, 4, 5)  CVTW(w3, 6, 7)
            CVTW(w4, 8, 9)  CVTW(w5, 10, 11) CVTW(w6, 12, 13) CVTW(w7, 14, 15)
            #undef CVTW
            asm volatile("v_permlane32_swap_b32 %0, %1" : "+v"(w0), "+v"(w2));
            asm volatile("v_permlane32_swap_b32 %0, %1" : "+v"(w1), "+v"(w3));
            asm volatile("v_permlane32_swap_b32 %0, %1" : "+v"(w4), "+v"(w6));
            asm volatile("v_permlane32_swap_b32 %0, %1" : "+v"(w5), "+v"(w7));
            u32x4 lo = { w0, w1, w2, w3 };
            u32x4 hi = { w4, w5, w6, w7 };
            pa[g * 2 + 0] = __builtin_bit_cast(h8, lo);
            pa[g * 2 + 1] = __builtin_bit_cast(h8, hi);
        }
        // PV (12 MFMAs)
        #pragma unroll
        for (int n = 0; n < 3; ++n) {
            f32x16* op = n == 0 ? &o0 : (n == 1 ? &o1 : &o2);
            int d = n * 32 + l31;
            #pragma unroll
            for (int ku = 0; ku < 4; ++ku) {
                int m = ku * 2 + half;
                h8 vb = *(const h8*)&Vl[cur][d * 64 + ((m ^ (d & 7)) << 3)];
                *op = MFMA16(pa[ku], vb, *op);
            }
        }
        if (pf) {
            #pragma unroll
            for (int i = 0; i < 3; ++i) {
                *(h8*)&Kl[nxt][koff[i]] = kpre[i];
                *(h8*)&Vl[nxt][voff[i]] = vpre[i];
            }
        }
        __syncthreads();
    }

    #pragma unroll
    for (int r = 0; r < 16; ++r) {
        float den = __shfl(o2[r], (lane & 32) | 26);
        float inv = (den > 0.0f) ? 1.0f / den : 0.0f;
        int qg = q0w + (r & 3) + 8 * (r >> 2) + 4 * half;
        if (qg < Tc) {
            _Float16* orow = aob + ((size_t)b * TBM + qg) * 384 + 96 * h;
            orow[l31]      = (_Float16)(o0[r] * inv);
            orow[32 + l31] = (_Float16)(o1[r] * inv);
            orow[64 + l31] = (64 + l31 < HDD) ? (_Float16)(o2[r] * inv) : (_Float16)0.0f;
        }
    }
}

// ---------------------------------------------------------------------------
// Gather + 3^3 sum-pool + |.| mask accumulation (atomic)
// ---------------------------------------------------------------------------
__global__ __launch_bounds__(128) void k_pool(
    const float* __restrict__ F_emb, const int* __restrict__ C,
    float* __restrict__ nodes, float* __restrict__ vsum)
{
    const int tkn = blockIdx.x, b = blockIdx.y;
    const int oz = tkn % 12, oy = (tkn / 12) % 12, ox = tkn / 144;
    __shared__ int idx[27];
    const int tid = threadIdx.x;
    if (tid < 27) {
        int dx = tid / 9, dy = (tid / 3) % 3, dz = tid % 3;
        idx[tid] = C[(((b * GG) + ox * 2 + dx) * GG + oy * 2 + dy) * GG + oz * 2 + dz];
    }
    __syncthreads();
    float a0 = 0.f, a1 = 0.f, a2 = 0.f;
    for (int n = 0; n < 27; ++n) {
        int c = idx[n];
        if (c == 0) continue;
        const float* src = F_emb + (size_t)(b * NROI + (c - 1)) * EMBD;
        a0 += src[tid]; a1 += src[tid + 128];
        if (tid < 104) a2 += src[tid + 256];
    }
    float* dst = nodes + ((size_t)b * TBM + tkn) * EMBD;
    dst[tid] = a0; dst[tid + 128] = a1;
    if (tid < 104) dst[tid + 256] = a2;
    float s = fabsf(a0) + fabsf(a1) + ((tid < 104) ? fabsf(a2) : 0.0f);
    #pragma unroll
    for (int o = 32; o >= 1; o >>= 1) s += __shfl_xor(s, o);
    __shared__ float red[2];
    if ((tid & 63) == 0) red[tid >> 6] = s;
    __syncthreads();
    if (tid == 0) atomicAdd(&vsum[tkn], red[0] + red[1]);
}

__global__ __launch_bounds__(256) void k_scan(
    const float* __restrict__ vsum, int* __restrict__ cidx, int* __restrict__ tcp)
{
    __shared__ int csum[256];
    __shared__ int coff[256];
    const int t = threadIdx.x;
    const int base = t * 7;
    int loc[7]; int s = 0;
    #pragma unroll
    for (int i = 0; i < 7; ++i) {
        int g = base + i;
        int v = (g < TBM) ? (vsum[g] > 0.0f ? 1 : 0) : 0;
        loc[i] = v; s += v;
    }
    csum[t] = s;
    __syncthreads();
    if (t == 0) {
        int a = 0;
        for (int i = 0; i < 256; ++i) { coff[i] = a; a += csum[i]; }
        *tcp = a;
    }
    __syncthreads();
    int off = coff[t];
    #pragma unroll
    for (int i = 0; i < 7; ++i) {
        int g = base + i;
        if (g < TBM && loc[i]) cidx[off++] = g;
    }
}

// compact -> t360 fp32 [.][360] and xh f16 [.][384] (pads zero)
__global__ __launch_bounds__(128) void k_compact(
    const float* __restrict__ nodes, const int* __restrict__ cidx,
    const int* __restrict__ tcp, float* __restrict__ xf, _Float16* __restrict__ xh)
{
    const int j = blockIdx.x, b = blockIdx.y;
    const int Tc = *tcp;
    const size_t row = (size_t)b * TBM + j;
    const float* src = (j < Tc) ? nodes + ((size_t)b * TBM + cidx[j]) * EMBD : nullptr;
    for (int e = threadIdx.x; e < 384; e += 128) {
        float v = (e < EMBD && src) ? src[e] : 0.0f;
        if (e < EMBD) xf[row * EMBD + e] = v;
        xh[row * 384 + e] = (_Float16)v;
    }
}

// ---------------------------------------------------------------------------
// Fused split-K reduce + bias + residual + LayerNorm, one WAVE per row.
// ---------------------------------------------------------------------------
__global__ __launch_bounds__(256) void k_lnr(
    const float* __restrict__ p0, const float* __restrict__ p1,
    const float* __restrict__ bias, const float* res,
    const float* __restrict__ sc, const float* __restrict__ bc,
    float* outf, _Float16* __restrict__ outh)
{
    const int lane = threadIdx.x & 63;
    const int row = blockIdx.x * 4 + (threadIdx.x >> 6);
    const size_t ro = (size_t)row * EMBD;
    const int e0 = lane * 6;
    float x[6] = {0.f, 0.f, 0.f, 0.f, 0.f, 0.f};
    float sum = 0.f;
    if (lane < 60) {
        #pragma unroll
        for (int i = 0; i < 6; ++i) {
            float v = p0[ro + e0 + i] + p1[ro + e0 + i] + bias[e0 + i] + res[ro + e0 + i];
            x[i] = v; sum += v;
        }
    }
    #pragma unroll
    for (int o = 32; o >= 1; o >>= 1) sum += __shfl_xor(sum, o);
    const float mean = sum * (1.0f / 360.0f);
    float vs = 0.f;
    if (lane < 60) {
        #pragma unroll
        for (int i = 0; i < 6; ++i) { float d = x[i] - mean; vs += d * d; }
    }
    #pragma unroll
    for (int o = 32; o >= 1; o >>= 1) vs += __shfl_xor(vs, o);
    const float rs = rsqrtf(vs * (1.0f / 360.0f) + 1e-5f);
    _Float16* hrow = outh + (size_t)row * 384;
    if (lane < 60) {
        #pragma unroll
        for (int i = 0; i < 6; ++i) {
            float v = (x[i] - mean) * rs * sc[e0 + i] + bc[e0 + i];
            outf[ro + e0 + i] = v;
            hrow[e0 + i] = (_Float16)v;
        }
    } else {
        #pragma unroll
        for (int i = 0; i < 6; ++i)
            hrow[360 + (lane - 60) * 6 + i] = (_Float16)0.0f;
    }
}

// ---------------------------------------------------------------------------
// Mean stage 1: partial[chunk][b][e] = sum over tokens in chunk.
// ---------------------------------------------------------------------------
__global__ __launch_bounds__(128) void k_mean2(
    const float* __restrict__ x, float* __restrict__ partial,
    const int* __restrict__ tcp)
{
    const int chunk = blockIdx.x;   // 0..15, 108 tokens each
    const int b = blockIdx.y;
    const int t = threadIdx.x;
    const int Tc = *tcp;
    int j0 = chunk * 108;
    int j1 = j0 + 108; if (j1 > Tc) j1 = Tc;
    const float* xb = x + (size_t)b * TBM * EMBD;
    float a0 = 0.f, a1 = 0.f, a2 = 0.f;
    for (int j = j0; j < j1; ++j) {
        const float* r = xb + (size_t)j * EMBD;
        a0 += r[t]; a1 += r[t + 128];
        if (t < 104) a2 += r[t + 256];
    }
    float* p = partial + ((size_t)chunk * NB + b) * EMBD;
    p[t] = a0; p[t + 128] = a1;
    if (t < 104) p[t + 256] = a2;
}

// Head: one block per batch.
__global__ __launch_bounds__(256) void k_head(
    const float* __restrict__ partial, const int* __restrict__ tcp,
    const float* __restrict__ cw1, const float* __restrict__ cb1,
    const float* __restrict__ cw2, const float* __restrict__ cb2,
    const float* __restrict__ cw3, const float* __restrict__ cb3,
    float* __restrict__ outp)
{
    const int b = blockIdx.x;
    __shared__ float hs[EMBD];
    __shared__ float h1[256];
    __shared__ float h2[128];
    const int t = threadIdx.x;
    int Tc = *tcp; if (Tc < 1) Tc = 1;
    const float inv = 1.0f / (float)Tc;
    for (int e = t; e < EMBD; e += 256) {
        float s = 0.f;
        #pragma unroll
        for (int c = 0; c < 16; ++c) s += partial[(size_t)c * NB * EMBD + b * EMBD + e];
        hs[e] = s * inv;
    }
    __syncthreads();
    {
        float s = cb1[t];
        for (int k = 0; k < EMBD; ++k) s = fmaf(hs[k], cw1[k * 256 + t], s);
        h1[t] = gelu_f(s);
    }
    __syncthreads();
    if (t < 128) {
        float s = cb2[t];
        for (int k = 0; k < 256; ++k) s = fmaf(h1[k], cw2[k * 128 + t], s);
        h2[t] = fmaxf(s, 0.0f);
    }
    __syncthreads();
    if (t < 2) {
        float s = cb3[t];
        for (int k = 0; k < 128; ++k) s = fmaf(h2[k], cw3[k * 2 + t], s);
        outp[b * 2 + t] = s;
    }
}

// ---------------------------------------------------------------------------
extern "C" void kernel_launch(void* const* d_in, const int* in_sizes, int n_in,
                              void* d_out, int out_size, void* d_ws, size_t ws_size,
                              hipStream_t stream)
{
    const float* F_roi  = (const float*)d_in[0];
    const int*   C      = (const int*)d_in[1];
    const float* ffn_w1 = (const float*)d_in[2];
    const float* ffn_b1 = (const float*)d_in[3];
    const float* ffn_w2 = (const float*)d_in[4];
    const float* ffn_b2 = (const float*)d_in[5];
    const float* wqkv   = (const float*)d_in[6];
    const float* bqkv   = (const float*)d_in[7];
    const float* wo     = (const float*)d_in[8];
    const float* bo     = (const float*)d_in[9];
    const float* ln1s   = (const float*)d_in[10];
    const float* ln1b   = (const float*)d_in[11];
    const float* wf1    = (const float*)d_in[12];
    const float* bf1    = (const float*)d_in[13];
    const float* wf2    = (const float*)d_in[14];
    const float* bf2    = (const float*)d_in[15];
    const float* ln2s   = (const float*)d_in[16];
    const float* ln2b   = (const float*)d_in[17];
    const float* cw1    = (const float*)d_in[18];
    const float* cb1    = (const float*)d_in[19];
    const float* cw2    = (const float*)d_in[20];
    const float* cb2    = (const float*)d_in[21];
    const float* cw3    = (const float*)d_in[22];
    const float* cb3    = (const float*)d_in[23];
    float* out = (float*)d_out;

    float* ws = (float*)d_ws;
    _Float16* qkvh = (_Float16*)ws;                   // [13824][1152] f16
    float*    tmp450 = ws;                            // alias
    float*    F_emb  = ws + 1440000;                  // alias
    float*    midf   = ws + 7962624;
    _Float16* midb   = (_Float16*)midf;               // [13824][2048] f16
    float*    nodes  = midf;                          // alias fp32
    _Float16* aob    = (_Float16*)(ws + 22118400);    // [13824][384] f16
    float*    p0     = ws + 24772608;
    float*    p1     = ws + 29749248;
    float*    t360   = ws + 34725888;
    _Float16* xh     = (_Float16*)(ws + 39702528);    // [13824][384] f16
    _Float16* sw     = (_Float16*)(ws + 42356736);

    size_t so = 0;
    auto salloc = [&](size_t n) { _Float16* p = sw + so; so += n; return p; };
    _Float16* w1c  = salloc(262144);           // [512][512]
    _Float16* w2c  = salloc(184320);           // [384][480]
    _Float16* qkvc = salloc(2 * 442368);       // [1152][384] x2
    _Float16* woc  = salloc(2 * 147456);       // [384][384]  x2
    _Float16* f1c  = salloc(2 * 786432);       // [2048][384] x2
    _Float16* f2c  = salloc(2 * 786432);       // [384][2048] x2
    float* partial = ws + 44742656;            // 16 x 8 x 360
    int*   ints    = (int*)(partial + 46080);
    int*   cidx    = ints;                     // 1728
    int*   tcp     = ints + 1728;              // 1
    float* vsumf   = (float*)(ints + 1732);    // 1728
    float* bqp     = vsumf + 1728;             // 2 x 1152
    _Float16* vT   = (_Float16*)(ws + 44800000); // [32][96][1728] f16

    dim3 blk(256);

    // Weight conversions
    k_wconv<<<dim3(16, 16, 1), blk, 0, stream>>>(ffn_w1, 512, 450, w1c, 512, 512, 0, 0);
    k_wconv<<<dim3(15, 12, 1), blk, 0, stream>>>(ffn_w2, 450, 360, w2c, 480, 384, 0, 0);
    k_wconv<<<dim3(12, 64, 2), blk, 0, stream>>>(wf1, 360, 2048, f1c, 384, 2048, 360 * 2048, 786432);
    k_wconv<<<dim3(64, 12, 2), blk, 0, stream>>>(wf2, 2048, 360, f2c, 2048, 384, 2048 * 360, 786432);
    k_wmisc<<<dim3(4618), blk, 0, stream>>>(wqkv, wo, bqkv, qkvc, woc, bqp);

    // Node featurization
    hipError_t e0 = hipMemsetAsync(vsumf, 0, TBM * sizeof(float), stream); (void)e0;
    k_mgemm<1, false, false, false><<<dim3(4, 25), blk, 0, stream>>>(F_roi, w1c, ffn_b1, nullptr, tmp450, 3200, 450, 512, 512);
    k_mgemm<0, false, false, false><<<dim3(3, 25), blk, 0, stream>>>(tmp450, w2c, ffn_b2, nullptr, F_emb, 3200, 360, 450, 480);
    k_pool<<<dim3(1728, 8), dim3(128), 0, stream>>>(F_emb, C, nodes, vsumf);
    k_scan<<<dim3(1), blk, 0, stream>>>(vsumf, cidx, tcp);
    k_compact<<<dim3(1728, 8), dim3(128), 0, stream>>>(nodes, cidx, tcp, t360, xh);

    // Transformer layers
    for (int l = 0; l < 2; ++l) {
        k_mgemm<0, false, true, true><<<dim3(9, 108), blk, 0, stream>>>(xh, qkvc + (size_t)l * 442368, bqp + l * 1152, nullptr, qkvh, MTOK, 1152, 360, 384);
        k_vtr<<<dim3(54, 3, 32), blk, 0, stream>>>(qkvh, vT);
        k_mattn<<<dim3(448), blk, 0, stream>>>(qkvh, vT, aob, tcp);
        k_skgemm<<<dim3(3, 108, 2), blk, 0, stream>>>(aob, woc + (size_t)l * 147456, p0, 384, 192, 6);
        k_lnr<<<dim3(MTOK / 4), blk, 0, stream>>>(p0, p1, bo + l * 360, t360, ln1s + l * 360, ln1b + l * 360, t360, xh);
        k_mgemm<1, false, true, true><<<dim3(16, 108), blk, 0, stream>>>(xh, f1c + (size_t)l * 786432, bf1 + l * 2048, nullptr, midb, MTOK, 2048, 360, 384);
        k_skgemm<<<dim3(3, 108, 2), blk, 0, stream>>>(midb, f2c + (size_t)l * 786432, p0, 2048, 1024, 32);
        k_lnr<<<dim3(MTOK / 4), blk, 0, stream>>>(p0, p1, bf2 + l * 360, t360, ln2s + l * 360, ln2b + l * 360, t360, xh);
    }

    // Head
    k_mean2<<<dim3(16, 8), dim3(128), 0, stream>>>(t360, partial, tcp);
    k_head<<<dim3(8), blk, 0, stream>>>(partial, tcp, cw1, cb1, cw2, cb2, cw3, cb3, out);
}

// Round 14
// 657.710 us; speedup vs baseline: 7.6183x; 1.0122x over previous
//
#include <hip/hip_runtime.h>
#include <math.h>

#define NB   8
#define NROI 400
#define GG   25
#define EMBD 360
#define HDD  90
#define TBM  1728
#define MTOK 13824      // NB*TBM

typedef __attribute__((ext_vector_type(8)))  _Float16 h8;   // 8 f16 (4 VGPR)
typedef __attribute__((ext_vector_type(4)))  _Float16 h4;
typedef __attribute__((ext_vector_type(16))) float f32x16;
typedef __attribute__((ext_vector_type(4)))  unsigned u32x4;

#define MFMA16(a,b,c) __builtin_amdgcn_mfma_f32_32x32x16_f16(a,b,c,0,0,0)
#define QSCALE 0.105409255338945984f   /* 1/sqrt(90) */

__device__ __forceinline__ float gelu_f(float x) {
    return 0.5f * x * (1.0f + erff(x * 0.7071067811865475f));
}

// bijective XCD-aware block remap (m204): logical ids contiguous per XCD.
__device__ __forceinline__ int xcd_swz(int orig, int nwg) {
    int q = nwg >> 3, r = nwg & 7;
    int xcd = orig & 7, loc = orig >> 3;
    int base = (xcd < r) ? xcd * (q + 1) : r * (q + 1) + (xcd - r) * q;
    return base + loc;
}

// ---------------------------------------------------------------------------
// Tiled weight convert+transpose: W[K][N] fp32 -> Wt[Np][Kp] f16 (zero-pad).
// ---------------------------------------------------------------------------
__global__ __launch_bounds__(256) void k_wconv(
    const float* __restrict__ W, int K, int N,
    _Float16* __restrict__ Wt, int Kp, int Np, int Wls, int Wtls)
{
    W  += (size_t)blockIdx.z * Wls;
    Wt += (size_t)blockIdx.z * Wtls;
    __shared__ float tile[32][33];
    const int k0 = blockIdx.x * 32, n0 = blockIdx.y * 32;
    const int t = threadIdx.x;
    #pragma unroll
    for (int it = 0; it < 4; ++it) {
        int e = t + it * 256;
        int i = e >> 5, j = e & 31;
        tile[j][i] = (k0 + i < K && n0 + j < N) ? W[(size_t)(k0 + i) * N + n0 + j] : 0.0f;
    }
    __syncthreads();
    #pragma unroll
    for (int it = 0; it < 4; ++it) {
        int e = t + it * 256;
        int n = e >> 5, kk = e & 31;
        if (n0 + n < Np && k0 + kk < Kp)
            Wt[(size_t)(n0 + n) * Kp + k0 + kk] = (_Float16)tile[n][kk];
    }
}

// qkv(2x) + wo(2x) + qkv-bias(2x) conversions fused into one flat kernel.
__global__ __launch_bounds__(256) void k_wmisc(
    const float* __restrict__ wqkv, const float* __restrict__ wo,
    const float* __restrict__ bqkv,
    _Float16* __restrict__ qkvc, _Float16* __restrict__ woc,
    float* __restrict__ bqp)
{
    int id = blockIdx.x * 256 + threadIdx.x;
    if (id < 884736) {                       // qkv: Wt[1152][384], n' = sec*384+96h+d
        int l = id / 442368, r = id - l * 442368;
        int np = r / 384, kk = r - np * 384;
        int sec = np / 384, rr = np - sec * 384, h = rr / 96, d = rr - h * 96;
        float v = 0.0f;
        if (d < HDD && kk < 360) v = wqkv[(size_t)l * 388800 + (size_t)kk * 1080 + sec * 360 + h * HDD + d];
        if (sec == 0) v *= QSCALE;
        qkvc[id] = (_Float16)v;
    } else if (id < 1179648) {               // wo: Wt[384][384], k' = 96h+d
        int r2 = id - 884736;
        int l = r2 / 147456, r = r2 - l * 147456;
        int n = r / 384, kp = r - n * 384;
        int h = kp / 96, d = kp - h * 96;
        float v = 0.0f;
        if (d < HDD && n < 360) v = wo[(size_t)l * 129600 + (size_t)(h * HDD + d) * 360 + n];
        woc[r2] = (_Float16)v;
    } else if (id < 1181952) {               // padded qkv bias [1152]
        int r3 = id - 1179648;
        int l = r3 / 1152, r = r3 - l * 1152;
        int sec = r / 384, rr = r - sec * 384, h = rr / 96, d = rr - h * 96;
        float v = 0.0f;
        if (d < HDD) v = bqkv[l * 1080 + sec * 360 + h * HDD + d];
        if (sec == 0) v *= QSCALE;
        if (sec == 2 && d == HDD) v = 1.0f;  // softmax denominator column
        bqp[r3] = v;
    }
}

// ---------------------------------------------------------------------------
// V transpose: qkvh V-section [13824][96 per head] -> vT[bh][96][1728] f16.
// ---------------------------------------------------------------------------
__global__ __launch_bounds__(256) void k_vtr(
    const _Float16* __restrict__ qkvh, _Float16* __restrict__ vT)
{
    __shared__ _Float16 tile[32][33];
    const int t = threadIdx.x;
    const int tok0 = blockIdx.x * 32;
    const int d0 = blockIdx.y * 32;
    const int bh = blockIdx.z;              // b*4 + h
    const int b = bh >> 2, h = bh & 3;
    const size_t src = ((size_t)b * TBM + tok0) * 1152 + 768 + 96 * h + d0;
    #pragma unroll
    for (int it = 0; it < 4; ++it) {
        int tl = (t >> 5) + it * 8, dl = t & 31;
        tile[tl][dl] = qkvh[src + (size_t)tl * 1152 + dl];
    }
    __syncthreads();
    const size_t dst = ((size_t)bh * 96 + d0) * TBM + tok0;
    #pragma unroll
    for (int it = 0; it < 4; ++it) {
        int dl = (t >> 5) + it * 8, tl = t & 31;
        vT[dst + (size_t)dl * TBM + tl] = tile[tl][dl];
    }
}

// ---------------------------------------------------------------------------
// MFMA GEMM (f16): C = act(A@B + bias (+res)). 128x128 tile, BK=32, 4 waves.
// Single LDS buffer + T14 register prefetch (R12-proven). MW = min blocks/CU.
// XCD-swizzled block ids for A-panel L2 locality.
// ---------------------------------------------------------------------------
template <int ACT, bool RES, bool OUTH, bool AH, int MW>
__global__ __launch_bounds__(256, MW) void k_mgemm(
    const void* __restrict__ Ap, const _Float16* __restrict__ Bt,
    const float* __restrict__ bias, const float* res, void* Cp,
    int M, int N, int K, int Kp)
{
    __shared__ __align__(16) _Float16 Ah[4096], Bh[4096];
    const int t = threadIdx.x;
    const int lane = t & 63, wid = t >> 6;
    const int half = lane >> 5, l31 = lane & 31;
    const int nwg = gridDim.x * gridDim.y;
    const int logical = xcd_swz(blockIdx.y * gridDim.x + blockIdx.x, nwg);
    const int m0 = (logical / gridDim.x) * 128, n0 = (logical % gridDim.x) * 128;
    const int wm = (wid >> 1) * 64, wn = (wid & 1) * 64;

    f32x16 acc00 = {}, acc01 = {}, acc10 = {}, acc11 = {};
    const int nk = Kp >> 5;
    const bool k4 = (K & 3) == 0;

    h8 acur[2], anxt[2], bcur[2], bnxt[2];
    float4 fcur[4], fnxt[4];

    const _Float16* Af = (const _Float16*)Ap;
    const float* A = (const float*)Ap;

    auto loadA_h = [&](int k0, h8* dst) {
        #pragma unroll
        for (int i = 0; i < 2; ++i) {
            int e = t + i * 256;
            int row = e >> 2, c = e & 3;
            int gm = m0 + row; if (gm > M - 1) gm = M - 1;
            dst[i] = *(const h8*)(Af + (size_t)gm * Kp + k0 + c * 8);
        }
    };
    auto loadA_f = [&](int k0, float4* dst) {
        #pragma unroll
        for (int i = 0; i < 4; ++i) {
            int e = t + i * 256;
            int row = e >> 3, c4 = e & 7;
            int gm = m0 + row, kb = k0 + c4 * 4;
            float4 fv = {0.f, 0.f, 0.f, 0.f};
            if (gm < M) {
                const float* ap = A + (size_t)gm * K + kb;
                if (k4 && kb + 3 < K) {
                    fv = *(const float4*)ap;
                } else {
                    if (kb + 0 < K) fv.x = ap[0];
                    if (kb + 1 < K) fv.y = ap[1];
                    if (kb + 2 < K) fv.z = ap[2];
                    if (kb + 3 < K) fv.w = ap[3];
                }
            }
            dst[i] = fv;
        }
    };
    auto loadB = [&](int k0, h8* dst) {
        #pragma unroll
        for (int i = 0; i < 2; ++i) {
            int e = t + i * 256;
            int col = e >> 2, c = e & 3;
            dst[i] = *(const h8*)(Bt + (size_t)(n0 + col) * Kp + k0 + c * 8);
        }
    };

    if (AH) loadA_h(0, acur); else loadA_f(0, fcur);
    loadB(0, bcur);

    for (int ks = 0; ks < nk; ++ks) {
        const bool pf = (ks + 1 < nk);
        if (pf) {
            if (AH) loadA_h((ks + 1) << 5, anxt); else loadA_f((ks + 1) << 5, fnxt);
            loadB((ks + 1) << 5, bnxt);
        }
        __syncthreads();   // previous iteration's LDS readers done
        if (AH) {
            #pragma unroll
            for (int i = 0; i < 2; ++i) {
                int e = t + i * 256;
                int row = e >> 2, c = e & 3;
                *(h8*)&Ah[(c * 128 + row) * 8] = acur[i];
            }
        } else {
            #pragma unroll
            for (int i = 0; i < 4; ++i) {
                int e = t + i * 256;
                int row = e >> 3, c4 = e & 7;
                float4 fv = fcur[i];
                h4 hv = { (_Float16)fv.x, (_Float16)fv.y, (_Float16)fv.z, (_Float16)fv.w };
                int c = c4 >> 1, sub = c4 & 1;
                *(h4*)&Ah[(c * 128 + row) * 8 + sub * 4] = hv;
            }
        }
        #pragma unroll
        for (int i = 0; i < 2; ++i) {
            int e = t + i * 256;
            int col = e >> 2, c = e & 3;
            *(h8*)&Bh[(c * 128 + col) * 8] = bcur[i];
        }
        __syncthreads();
        h8 af[2][2], bf[2][2];
        #pragma unroll
        for (int m2 = 0; m2 < 2; ++m2)
            #pragma unroll
            for (int ku = 0; ku < 2; ++ku) {
                int c = ku * 2 + half;
                af[m2][ku] = *(const h8*)&Ah[(c * 128 + wm + m2 * 32 + l31) * 8];
                bf[m2][ku] = *(const h8*)&Bh[(c * 128 + wn + m2 * 32 + l31) * 8];
            }
        #pragma unroll
        for (int ku = 0; ku < 2; ++ku) {
            acc00 = MFMA16(af[0][ku], bf[0][ku], acc00);
            acc01 = MFMA16(af[0][ku], bf[1][ku], acc01);
            acc10 = MFMA16(af[1][ku], bf[0][ku], acc10);
            acc11 = MFMA16(af[1][ku], bf[1][ku], acc11);
        }
        if (pf) {
            if (AH) { acur[0] = anxt[0]; acur[1] = anxt[1]; }
            else    { fcur[0] = fnxt[0]; fcur[1] = fnxt[1]; fcur[2] = fnxt[2]; fcur[3] = fnxt[3]; }
            bcur[0] = bnxt[0]; bcur[1] = bnxt[1];
        }
    }
    float* Cf = (float*)Cp;
    _Float16* Ch = (_Float16*)Cp;
    #define EPILOG(ACCV, M2, N2) { \
        int gn = n0 + wn + (N2) * 32 + l31; \
        if (gn < N) { \
            float bv = bias[gn]; \
            _Pragma("unroll") \
            for (int r = 0; r < 16; ++r) { \
                int gm = m0 + wm + (M2) * 32 + (r & 3) + 8 * (r >> 2) + 4 * half; \
                if (gm < M) { \
                    float v = ACCV[r] + bv; \
                    if (RES) v += res[(size_t)gm * N + gn]; \
                    if (ACT == 1) v = gelu_f(v); \
                    if (OUTH) Ch[(size_t)gm * N + gn] = (_Float16)v; \
                    else      Cf[(size_t)gm * N + gn] = v; \
                } } } }
    EPILOG(acc00, 0, 0) EPILOG(acc01, 0, 1) EPILOG(acc10, 1, 0) EPILOG(acc11, 1, 1)
    #undef EPILOG
}

// ---------------------------------------------------------------------------
// Split-K GEMM, single buffer + T14 prefetch, XCD swizzle: partial fp32.
// ---------------------------------------------------------------------------
__global__ __launch_bounds__(256, 4) void k_skgemm(
    const _Float16* __restrict__ A, const _Float16* __restrict__ Bt,
    float* __restrict__ P, int Kp, int KCH, int nstep)
{
    __shared__ __align__(16) _Float16 Ah[4096], Bh[4096];
    const int t = threadIdx.x;
    const int lane = t & 63, wid = t >> 6;
    const int half = lane >> 5, l31 = lane & 31;
    const int nwg = gridDim.x * gridDim.y;
    const int logical = xcd_swz(blockIdx.y * gridDim.x + blockIdx.x, nwg);
    const int m0 = (logical / gridDim.x) * 128, n0 = (logical % gridDim.x) * 128;
    const int wm = (wid >> 1) * 64, wn = (wid & 1) * 64;
    const int zb = blockIdx.z * KCH;
    P += (size_t)blockIdx.z * MTOK * EMBD;

    f32x16 acc00 = {}, acc01 = {}, acc10 = {}, acc11 = {};

    h8 acur[2], anxt[2], bcur[2], bnxt[2];
    auto loadA = [&](int k0, h8* dst) {
        #pragma unroll
        for (int i = 0; i < 2; ++i) {
            int e = t + i * 256;
            int row = e >> 2, c = e & 3;
            dst[i] = *(const h8*)(A + (size_t)(m0 + row) * Kp + k0 + c * 8);
        }
    };
    auto loadB = [&](int k0, h8* dst) {
        #pragma unroll
        for (int i = 0; i < 2; ++i) {
            int e = t + i * 256;
            int col = e >> 2, c = e & 3;
            dst[i] = *(const h8*)(Bt + (size_t)(n0 + col) * Kp + k0 + c * 8);
        }
    };

    loadA(zb, acur); loadB(zb, bcur);

    for (int ks = 0; ks < nstep; ++ks) {
        const bool pf = (ks + 1 < nstep);
        if (pf) { loadA(zb + ((ks + 1) << 5), anxt); loadB(zb + ((ks + 1) << 5), bnxt); }
        __syncthreads();
        #pragma unroll
        for (int i = 0; i < 2; ++i) {
            int e = t + i * 256;
            int row = e >> 2, c = e & 3;
            *(h8*)&Ah[(c * 128 + row) * 8] = acur[i];
        }
        #pragma unroll
        for (int i = 0; i < 2; ++i) {
            int e = t + i * 256;
            int col = e >> 2, c = e & 3;
            *(h8*)&Bh[(c * 128 + col) * 8] = bcur[i];
        }
        __syncthreads();
        h8 af[2][2], bf[2][2];
        #pragma unroll
        for (int m2 = 0; m2 < 2; ++m2)
            #pragma unroll
            for (int ku = 0; ku < 2; ++ku) {
                int c = ku * 2 + half;
                af[m2][ku] = *(const h8*)&Ah[(c * 128 + wm + m2 * 32 + l31) * 8];
                bf[m2][ku] = *(const h8*)&Bh[(c * 128 + wn + m2 * 32 + l31) * 8];
            }
        #pragma unroll
        for (int ku = 0; ku < 2; ++ku) {
            acc00 = MFMA16(af[0][ku], bf[0][ku], acc00);
            acc01 = MFMA16(af[0][ku], bf[1][ku], acc01);
            acc10 = MFMA16(af[1][ku], bf[0][ku], acc10);
            acc11 = MFMA16(af[1][ku], bf[1][ku], acc11);
        }
        if (pf) { acur[0] = anxt[0]; acur[1] = anxt[1]; bcur[0] = bnxt[0]; bcur[1] = bnxt[1]; }
    }
    #define EPILOGP(ACCV, M2, N2) { \
        int gn = n0 + wn + (N2) * 32 + l31; \
        if (gn < EMBD) { \
            _Pragma("unroll") \
            for (int r = 0; r < 16; ++r) { \
                int gm = m0 + wm + (M2) * 32 + (r & 3) + 8 * (r >> 2) + 4 * half; \
                P[(size_t)gm * EMBD + gn] = ACCV[r]; \
            } } }
    EPILOGP(acc00, 0, 0) EPILOGP(acc01, 0, 1) EPILOGP(acc10, 1, 0) EPILOGP(acc11, 1, 1)
    #undef EPILOGP
}

// ---------------------------------------------------------------------------
// Flash attention, f16 MFMA (T12 in-register softmax). Unchanged from R12/R13.
// ---------------------------------------------------------------------------
__global__ __launch_bounds__(256, 2) void k_mattn(
    const _Float16* __restrict__ qkv, const _Float16* __restrict__ vT,
    _Float16* __restrict__ aob, const int* __restrict__ tcp)
{
    __shared__ __align__(16) _Float16 Kl[2][8192];   // [buf][kk*128 + chunk^ (kk&7)]
    __shared__ __align__(16) _Float16 Vl[2][6144];   // [buf][d*64 + (m^(d&7))*8]

    const int t = threadIdx.x;
    const int lane = t & 63, wid = t >> 6;
    const int half = lane >> 5, l31 = lane & 31;
    const int bid = blockIdx.x;
    const int bh = bid & 31, qt = bid >> 5;
    const int h = bh & 3, b = bh >> 2;
    const int Tc = *tcp;
    const int q0w = qt * 128 + wid * 32;
    const size_t base = (size_t)b * TBM * 1152 + 96 * h;
    const _Float16* vTb = vT + (size_t)bh * 96 * TBM;

    int skk[3], scc[3], sdd[3], smm[3];
    int koff[3], voff[3];
    #pragma unroll
    for (int i = 0; i < 3; ++i) {
        int cid = t + i * 256;
        skk[i] = cid / 12; scc[i] = cid - skk[i] * 12;
        sdd[i] = cid >> 3; smm[i] = cid & 7;
        koff[i] = skk[i] * 128 + ((scc[i] ^ (skk[i] & 7)) << 3);
        voff[i] = sdd[i] * 64 + ((smm[i] ^ (sdd[i] & 7)) << 3);
    }

    h8 qf[6];
    {
        int rl = q0w + l31; if (rl > TBM - 1) rl = TBM - 1;
        const _Float16* qrow = qkv + base + (size_t)rl * 1152;
        #pragma unroll
        for (int ku = 0; ku < 6; ++ku)
            qf[ku] = *(const h8*)(qrow + ku * 16 + half * 8);
    }

    f32x16 o0 = {}, o1 = {}, o2 = {};
    int nkt = (Tc + 63) >> 6; if (nkt > 27) nkt = 27;

    if (nkt > 0) {
        #pragma unroll
        for (int i = 0; i < 3; ++i) {
            *(h8*)&Kl[0][koff[i]] =
                *(const h8*)(qkv + base + (size_t)skk[i] * 1152 + 384 + scc[i] * 8);
            *(h8*)&Vl[0][voff[i]] =
                *(const h8*)(vTb + (size_t)sdd[i] * TBM + smm[i] * 8);
        }
    }
    __syncthreads();

    for (int kt = 0; kt < nkt; ++kt) {
        const int k0 = kt * 64;
        const int cur = kt & 1, nxt = cur ^ 1;
        h8 kpre[3], vpre[3];
        const bool pf = (kt + 1 < nkt);
        if (pf) {
            #pragma unroll
            for (int i = 0; i < 3; ++i) {
                kpre[i] = *(const h8*)(qkv + base + (size_t)(k0 + 64 + skk[i]) * 1152 + 384 + scc[i] * 8);
                vpre[i] = *(const h8*)(vTb + (size_t)sdd[i] * TBM + k0 + 64 + smm[i] * 8);
            }
        }
        // S^T = K Q (12 MFMAs)
        f32x16 sT0 = {}, sT1 = {};
        #pragma unroll
        for (int ku = 0; ku < 6; ++ku) {
            int c = ku * 2 + half;
            int cp = c ^ (l31 & 7);
            h8 kb0 = *(const h8*)&Kl[cur][l31 * 128 + cp * 8];
            h8 kb1 = *(const h8*)&Kl[cur][(32 + l31) * 128 + cp * 8];
            sT0 = MFMA16(kb0, qf[ku], sT0);
            sT1 = MFMA16(kb1, qf[ku], sT1);
        }
        // exp -> f16 pack -> permlane half-swap -> PV A-fragments (no LDS)
        h8 pa[4];
        #pragma unroll
        for (int g = 0; g < 2; ++g) {
            const f32x16& sT = g ? sT1 : sT0;
            const int kbase = k0 + g * 32;
            unsigned w0, w1, w2, w3, w4, w5, w6, w7;
            #define CVTW(W, R0, R1) { \
                int ka = kbase + ((R0) & 3) + 8 * ((R0) >> 2) + 4 * half; \
                int kb_ = kbase + ((R1) & 3) + 8 * ((R1) >> 2) + 4 * half; \
                float pva = (ka  < Tc) ? __expf(sT[R0]) : 0.0f; \
                float pvb = (kb_ < Tc) ? __expf(sT[R1]) : 0.0f; \
                W = __builtin_bit_cast(unsigned, __builtin_amdgcn_cvt_pkrtz(pva, pvb)); }
            CVTW(w0, 0, 1)  CVTW(w1, 2, 3)  CVTW(w2, 4, 5)  CVTW(w3, 6, 7)
            CVTW(w4, 8, 9)  CVTW(w5, 10, 11) CVTW(w6, 12, 13) CVTW(w7, 14, 15)
            #undef CVTW
            asm volatile("v_permlane32_swap_b32 %0, %1" : "+v"(w0), "+v"(w2));
            asm volatile("v_permlane32_swap_b32 %0, %1" : "+v"(w1), "+v"(w3));
            asm volatile("v_permlane32_swap_b32 %0, %1" : "+v"(w4), "+v"(w6));
            asm volatile("v_permlane32_swap_b32 %0, %1" : "+v"(w5), "+v"(w7));
            u32x4 lo = { w0, w1, w2, w3 };
            u32x4 hi = { w4, w5, w6, w7 };
            pa[g * 2 + 0] = __builtin_bit_cast(h8, lo);
            pa[g * 2 + 1] = __builtin_bit_cast(h8, hi);
        }
        // PV (12 MFMAs)
        #pragma unroll
        for (int n = 0; n < 3; ++n) {
            f32x16* op = n == 0 ? &o0 : (n == 1 ? &o1 : &o2);
            int d = n * 32 + l31;
            #pragma unroll
            for (int ku = 0; ku < 4; ++ku) {
                int m = ku * 2 + half;
                h8 vb = *(const h8*)&Vl[cur][d * 64 + ((m ^ (d & 7)) << 3)];
                *op = MFMA16(pa[ku], vb, *op);
            }
        }
        if (pf) {
            #pragma unroll
            for (int i = 0; i < 3; ++i) {
                *(h8*)&Kl[nxt][koff[i]] = kpre[i];
                *(h8*)&Vl[nxt][voff[i]] = vpre[i];
            }
        }
        __syncthreads();
    }

    #pragma unroll
    for (int r = 0; r < 16; ++r) {
        float den = __shfl(o2[r], (lane & 32) | 26);
        float inv = (den > 0.0f) ? 1.0f / den : 0.0f;
        int qg = q0w + (r & 3) + 8 * (r >> 2) + 4 * half;
        if (qg < Tc) {
            _Float16* orow = aob + ((size_t)b * TBM + qg) * 384 + 96 * h;
            orow[l31]      = (_Float16)(o0[r] * inv);
            orow[32 + l31] = (_Float16)(o1[r] * inv);
            orow[64 + l31] = (64 + l31 < HDD) ? (_Float16)(o2[r] * inv) : (_Float16)0.0f;
        }
    }
}

// ---------------------------------------------------------------------------
// Gather + 3^3 sum-pool + |.| mask accumulation (atomic)
// ---------------------------------------------------------------------------
__global__ __launch_bounds__(128) void k_pool(
    const float* __restrict__ F_emb, const int* __restrict__ C,
    float* __restrict__ nodes, float* __restrict__ vsum)
{
    const int tkn = blockIdx.x, b = blockIdx.y;
    const int oz = tkn % 12, oy = (tkn / 12) % 12, ox = tkn / 144;
    __shared__ int idx[27];
    const int tid = threadIdx.x;
    if (tid < 27) {
        int dx = tid / 9, dy = (tid / 3) % 3, dz = tid % 3;
        idx[tid] = C[(((b * GG) + ox * 2 + dx) * GG + oy * 2 + dy) * GG + oz * 2 + dz];
    }
    __syncthreads();
    float a0 = 0.f, a1 = 0.f, a2 = 0.f;
    for (int n = 0; n < 27; ++n) {
        int c = idx[n];
        if (c == 0) continue;
        const float* src = F_emb + (size_t)(b * NROI + (c - 1)) * EMBD;
        a0 += src[tid]; a1 += src[tid + 128];
        if (tid < 104) a2 += src[tid + 256];
    }
    float* dst = nodes + ((size_t)b * TBM + tkn) * EMBD;
    dst[tid] = a0; dst[tid + 128] = a1;
    if (tid < 104) dst[tid + 256] = a2;
    float s = fabsf(a0) + fabsf(a1) + ((tid < 104) ? fabsf(a2) : 0.0f);
    #pragma unroll
    for (int o = 32; o >= 1; o >>= 1) s += __shfl_xor(s, o);
    __shared__ float red[2];
    if ((tid & 63) == 0) red[tid >> 6] = s;
    __syncthreads();
    if (tid == 0) atomicAdd(&vsum[tkn], red[0] + red[1]);
}

__global__ __launch_bounds__(256) void k_scan(
    const float* __restrict__ vsum, int* __restrict__ cidx, int* __restrict__ tcp)
{
    __shared__ int csum[256];
    __shared__ int coff[256];
    const int t = threadIdx.x;
    const int base = t * 7;
    int loc[7]; int s = 0;
    #pragma unroll
    for (int i = 0; i < 7; ++i) {
        int g = base + i;
        int v = (g < TBM) ? (vsum[g] > 0.0f ? 1 : 0) : 0;
        loc[i] = v; s += v;
    }
    csum[t] = s;
    __syncthreads();
    if (t == 0) {
        int a = 0;
        for (int i = 0; i < 256; ++i) { coff[i] = a; a += csum[i]; }
        *tcp = a;
    }
    __syncthreads();
    int off = coff[t];
    #pragma unroll
    for (int i = 0; i < 7; ++i) {
        int g = base + i;
        if (g < TBM && loc[i]) cidx[off++] = g;
    }
}

// compact -> t360 fp32 [.][360] and xh f16 [.][384] (pads zero)
__global__ __launch_bounds__(128) void k_compact(
    const float* __restrict__ nodes, const int* __restrict__ cidx,
    const int* __restrict__ tcp, float* __restrict__ xf, _Float16* __restrict__ xh)
{
    const int j = blockIdx.x, b = blockIdx.y;
    const int Tc = *tcp;
    const size_t row = (size_t)b * TBM + j;
    const float* src = (j < Tc) ? nodes + ((size_t)b * TBM + cidx[j]) * EMBD : nullptr;
    for (int e = threadIdx.x; e < 384; e += 128) {
        float v = (e < EMBD && src) ? src[e] : 0.0f;
        if (e < EMBD) xf[row * EMBD + e] = v;
        xh[row * 384 + e] = (_Float16)v;
    }
}

// ---------------------------------------------------------------------------
// Fused split-K reduce + bias + residual + LayerNorm, one WAVE per row.
// ---------------------------------------------------------------------------
__global__ __launch_bounds__(256) void k_lnr(
    const float* __restrict__ p0, const float* __restrict__ p1,
    const float* __restrict__ bias, const float* res,
    const float* __restrict__ sc, const float* __restrict__ bc,
    float* outf, _Float16* __restrict__ outh)
{
    const int lane = threadIdx.x & 63;
    const int row = blockIdx.x * 4 + (threadIdx.x >> 6);
    const size_t ro = (size_t)row * EMBD;
    const int e0 = lane * 6;
    float x[6] = {0.f, 0.f, 0.f, 0.f, 0.f, 0.f};
    float sum = 0.f;
    if (lane < 60) {
        #pragma unroll
        for (int i = 0; i < 6; ++i) {
            float v = p0[ro + e0 + i] + p1[ro + e0 + i] + bias[e0 + i] + res[ro + e0 + i];
            x[i] = v; sum += v;
        }
    }
    #pragma unroll
    for (int o = 32; o >= 1; o >>= 1) sum += __shfl_xor(sum, o);
    const float mean = sum * (1.0f / 360.0f);
    float vs = 0.f;
    if (lane < 60) {
        #pragma unroll
        for (int i = 0; i < 6; ++i) { float d = x[i] - mean; vs += d * d; }
    }
    #pragma unroll
    for (int o = 32; o >= 1; o >>= 1) vs += __shfl_xor(vs, o);
    const float rs = rsqrtf(vs * (1.0f / 360.0f) + 1e-5f);
    _Float16* hrow = outh + (size_t)row * 384;
    if (lane < 60) {
        #pragma unroll
        for (int i = 0; i < 6; ++i) {
            float v = (x[i] - mean) * rs * sc[e0 + i] + bc[e0 + i];
            outf[ro + e0 + i] = v;
            hrow[e0 + i] = (_Float16)v;
        }
    } else {
        #pragma unroll
        for (int i = 0; i < 6; ++i)
            hrow[360 + (lane - 60) * 6 + i] = (_Float16)0.0f;
    }
}

// ---------------------------------------------------------------------------
// Mean stage 1: partial[chunk][b][e] = sum over tokens in chunk.
// ---------------------------------------------------------------------------
__global__ __launch_bounds__(128) void k_mean2(
    const float* __restrict__ x, float* __restrict__ partial,
    const int* __restrict__ tcp)
{
    const int chunk = blockIdx.x;   // 0..15, 108 tokens each
    const int b = blockIdx.y;
    const int t = threadIdx.x;
    const int Tc = *tcp;
    int j0 = chunk * 108;
    int j1 = j0 + 108; if (j1 > Tc) j1 = Tc;
    const float* xb = x + (size_t)b * TBM * EMBD;
    float a0 = 0.f, a1 = 0.f, a2 = 0.f;
    for (int j = j0; j < j1; ++j) {
        const float* r = xb + (size_t)j * EMBD;
        a0 += r[t]; a1 += r[t + 128];
        if (t < 104) a2 += r[t + 256];
    }
    float* p = partial + ((size_t)chunk * NB + b) * EMBD;
    p[t] = a0; p[t + 128] = a1;
    if (t < 104) p[t + 256] = a2;
}

// Head: one block per batch.
__global__ __launch_bounds__(256) void k_head(
    const float* __restrict__ partial, const int* __restrict__ tcp,
    const float* __restrict__ cw1, const float* __restrict__ cb1,
    const float* __restrict__ cw2, const float* __restrict__ cb2,
    const float* __restrict__ cw3, const float* __restrict__ cb3,
    float* __restrict__ outp)
{
    const int b = blockIdx.x;
    __shared__ float hs[EMBD];
    __shared__ float h1[256];
    __shared__ float h2[128];
    const int t = threadIdx.x;
    int Tc = *tcp; if (Tc < 1) Tc = 1;
    const float inv = 1.0f / (float)Tc;
    for (int e = t; e < EMBD; e += 256) {
        float s = 0.f;
        #pragma unroll
        for (int c = 0; c < 16; ++c) s += partial[(size_t)c * NB * EMBD + b * EMBD + e];
        hs[e] = s * inv;
    }
    __syncthreads();
    {
        float s = cb1[t];
        for (int k = 0; k < EMBD; ++k) s = fmaf(hs[k], cw1[k * 256 + t], s);
        h1[t] = gelu_f(s);
    }
    __syncthreads();
    if (t < 128) {
        float s = cb2[t];
        for (int k = 0; k < 256; ++k) s = fmaf(h1[k], cw2[k * 128 + t], s);
        h2[t] = fmaxf(s, 0.0f);
    }
    __syncthreads();
    if (t < 2) {
        float s = cb3[t];
        for (int k = 0; k < 128; ++k) s = fmaf(h2[k], cw3[k * 2 + t], s);
        outp[b * 2 + t] = s;
    }
}

// ---------------------------------------------------------------------------
extern "C" void kernel_launch(void* const* d_in, const int* in_sizes, int n_in,
                              void* d_out, int out_size, void* d_ws, size_t ws_size,
                              hipStream_t stream)
{
    const float* F_roi  = (const float*)d_in[0];
    const int*   C      = (const int*)d_in[1];
    const float* ffn_w1 = (const float*)d_in[2];
    const float* ffn_b1 = (const float*)d_in[3];
    const float* ffn_w2 = (const float*)d_in[4];
    const float* ffn_b2 = (const float*)d_in[5];
    const float* wqkv   = (const float*)d_in[6];
    const float* bqkv   = (const float*)d_in[7];
    const float* wo     = (const float*)d_in[8];
    const float* bo     = (const float*)d_in[9];
    const float* ln1s   = (const float*)d_in[10];
    const float* ln1b   = (const float*)d_in[11];
    const float* wf1    = (const float*)d_in[12];
    const float* bf1    = (const float*)d_in[13];
    const float* wf2    = (const float*)d_in[14];
    const float* bf2    = (const float*)d_in[15];
    const float* ln2s   = (const float*)d_in[16];
    const float* ln2b   = (const float*)d_in[17];
    const float* cw1    = (const float*)d_in[18];
    const float* cb1    = (const float*)d_in[19];
    const float* cw2    = (const float*)d_in[20];
    const float* cb2    = (const float*)d_in[21];
    const float* cw3    = (const float*)d_in[22];
    const float* cb3    = (const float*)d_in[23];
    float* out = (float*)d_out;

    float* ws = (float*)d_ws;
    _Float16* qkvh = (_Float16*)ws;                   // [13824][1152] f16
    float*    tmp450 = ws;                            // alias
    float*    F_emb  = ws + 1440000;                  // alias
    float*    midf   = ws + 7962624;
    _Float16* midb   = (_Float16*)midf;               // [13824][2048] f16
    float*    nodes  = midf;                          // alias fp32
    _Float16* aob    = (_Float16*)(ws + 22118400);    // [13824][384] f16
    float*    p0     = ws + 24772608;
    float*    p1     = ws + 29749248;
    float*    t360   = ws + 34725888;
    _Float16* xh     = (_Float16*)(ws + 39702528);    // [13824][384] f16
    _Float16* sw     = (_Float16*)(ws + 42356736);

    size_t so = 0;
    auto salloc = [&](size_t n) { _Float16* p = sw + so; so += n; return p; };
    _Float16* w1c  = salloc(262144);           // [512][512]
    _Float16* w2c  = salloc(184320);           // [384][480]
    _Float16* qkvc = salloc(2 * 442368);       // [1152][384] x2
    _Float16* woc  = salloc(2 * 147456);       // [384][384]  x2
    _Float16* f1c  = salloc(2 * 786432);       // [2048][384] x2
    _Float16* f2c  = salloc(2 * 786432);       // [384][2048] x2
    float* partial = ws + 44742656;            // 16 x 8 x 360
    int*   ints    = (int*)(partial + 46080);
    int*   cidx    = ints;                     // 1728
    int*   tcp     = ints + 1728;              // 1
    float* vsumf   = (float*)(ints + 1732);    // 1728
    float* bqp     = vsumf + 1728;             // 2 x 1152
    _Float16* vT   = (_Float16*)(ws + 44800000); // [32][96][1728] f16

    dim3 blk(256);

    // Weight conversions
    k_wconv<<<dim3(16, 16, 1), blk, 0, stream>>>(ffn_w1, 512, 450, w1c, 512, 512, 0, 0);
    k_wconv<<<dim3(15, 12, 1), blk, 0, stream>>>(ffn_w2, 450, 360, w2c, 480, 384, 0, 0);
    k_wconv<<<dim3(12, 64, 2), blk, 0, stream>>>(wf1, 360, 2048, f1c, 384, 2048, 360 * 2048, 786432);
    k_wconv<<<dim3(64, 12, 2), blk, 0, stream>>>(wf2, 2048, 360, f2c, 2048, 384, 2048 * 360, 786432);
    k_wmisc<<<dim3(4618), blk, 0, stream>>>(wqkv, wo, bqkv, qkvc, woc, bqp);

    // Node featurization
    hipError_t e0 = hipMemsetAsync(vsumf, 0, TBM * sizeof(float), stream); (void)e0;
    k_mgemm<1, false, false, false, 3><<<dim3(4, 25), blk, 0, stream>>>(F_roi, w1c, ffn_b1, nullptr, tmp450, 3200, 450, 512, 512);
    k_mgemm<0, false, false, false, 3><<<dim3(3, 25), blk, 0, stream>>>(tmp450, w2c, ffn_b2, nullptr, F_emb, 3200, 360, 450, 480);
    k_pool<<<dim3(1728, 8), dim3(128), 0, stream>>>(F_emb, C, nodes, vsumf);
    k_scan<<<dim3(1), blk, 0, stream>>>(vsumf, cidx, tcp);
    k_compact<<<dim3(1728, 8), dim3(128), 0, stream>>>(nodes, cidx, tcp, t360, xh);

    // Transformer layers
    for (int l = 0; l < 2; ++l) {
        k_mgemm<0, false, true, true, 4><<<dim3(9, 108), blk, 0, stream>>>(xh, qkvc + (size_t)l * 442368, bqp + l * 1152, nullptr, qkvh, MTOK, 1152, 360, 384);
        k_vtr<<<dim3(54, 3, 32), blk, 0, stream>>>(qkvh, vT);
        k_mattn<<<dim3(448), blk, 0, stream>>>(qkvh, vT, aob, tcp);
        k_skgemm<<<dim3(3, 108, 2), blk, 0, stream>>>(aob, woc + (size_t)l * 147456, p0, 384, 192, 6);
        k_lnr<<<dim3(MTOK / 4), blk, 0, stream>>>(p0, p1, bo + l * 360, t360, ln1s + l * 360, ln1b + l * 360, t360, xh);
        k_mgemm<1, false, true, true, 4><<<dim3(16, 108), blk, 0, stream>>>(xh, f1c + (size_t)l * 786432, bf1 + l * 2048, nullptr, midb, MTOK, 2048, 360, 384);
        k_skgemm<<<dim3(3, 108, 2), blk, 0, stream>>>(midb, f2c + (size_t)l * 786432, p0, 2048, 1024, 32);
        k_lnr<<<dim3(MTOK / 4), blk, 0, stream>>>(p0, p1, bf2 + l * 360, t360, ln2s + l * 360, ln2b + l * 360, t360, xh);
    }

    // Head
    k_mean2<<<dim3(16, 8), dim3(128), 0, stream>>>(t360, partial, tcp);
    k_head<<<dim3(8), blk, 0, stream>>>(partial, tcp, cw1, cb1, cw2, cb2, cw3, cb3, out);
}